// Round 4
// baseline (944.758 us; speedup 1.0000x reference)
//
#include <hip/hip_runtime.h>
#include <cstdio>
#include <cmath>

#define NUM_WORDS 2048
#define NUM_CAND 8192
#define HIDDEN 768
#define FEAT 20
#define FFNN_DIM 1000
#define SPAN_DIM 2324
#define TOP_NUM 819
#define MSW 30
#define KP2 1024   // FFNN padded to x32
#define NP 1024    // padded N
#define PNP 3072   // P matrix padded N (3 segments of 1024)

// d_out layout (floats): [scores 8192][top_idx 819][top_starts 819][top_ends 819]
//                        [top_span_emb 819*2324][top_scores 819]
#define OUT_TOPIDX   (NUM_CAND)
#define OUT_TSTART   (NUM_CAND + TOP_NUM)
#define OUT_TEND     (NUM_CAND + 2*TOP_NUM)
#define OUT_TEMB     (NUM_CAND + 3*TOP_NUM)
#define OUT_TSCORE   (NUM_CAND + 3*TOP_NUM + TOP_NUM*SPAN_DIM)

typedef short short8 __attribute__((ext_vector_type(8)));
typedef float f32x4 __attribute__((ext_vector_type(4)));
typedef unsigned short u16x4 __attribute__((ext_vector_type(4)));

__device__ __forceinline__ unsigned short bf16_rne(float x) {
    unsigned int u = __float_as_uint(x);
    unsigned int r = u + 0x7FFFu + ((u >> 16) & 1u);
    return (unsigned short)(r >> 16);
}
__device__ __forceinline__ float bf16_to_f(unsigned short h) {
    return __uint_as_float(((unsigned int)h) << 16);
}
// 3-way split: v = s0 + s1 + s2 + r, |r| <= 2^-27 |v|
__device__ __forceinline__ void store_split3(unsigned short* p0, unsigned short* p1,
                                             unsigned short* p2, size_t off, float v) {
    unsigned short h0 = bf16_rne(v);
    float r1 = v - bf16_to_f(h0);
    unsigned short h1 = bf16_rne(r1);
    float r2 = r1 - bf16_to_f(h1);
    p0[off] = h0;
    p1[off] = h1;
    p2[off] = bf16_rne(r2);
}

// async 16B global->LDS (gfx950 global_load_lds_dwordx4). LDS dest must be
// wave-uniform base + lane*16 -> staging tiles are UNPADDED (128x32 bf16, 64B rows),
// bank conflicts handled by XOR swizzle: kblk stored at kblk^(row&3).
__device__ __forceinline__ void gl_lds16(const unsigned short* g, unsigned short* l) {
    __builtin_amdgcn_global_load_lds(
        (const __attribute__((address_space(1))) unsigned short*)g,
        (__attribute__((address_space(3))) unsigned short*)l, 16, 0, 0);
}

// ---------------- head scores: doc @ head_w + head_b  -> [2048] ----------------
__global__ void head_kernel(const float* __restrict__ doc, const float* __restrict__ hw,
                            const float* __restrict__ hb, float* __restrict__ out) {
    int wave = threadIdx.x >> 6, lane = threadIdx.x & 63;
    int row = blockIdx.x * 4 + wave;
    if (row >= NUM_WORDS) return;
    float acc = 0.f;
    for (int h = lane; h < HIDDEN; h += 64) acc += doc[row * HIDDEN + h] * hw[h];
    for (int off = 32; off > 0; off >>= 1) acc += __shfl_down(acc, off);
    if (lane == 0) out[row] = acc + hb[0];
}

// ---------------- width prior ffnn: [30,20] -> [30] ----------------
__global__ void width_kernel(const float* __restrict__ x, const float* __restrict__ w1,
                             const float* __restrict__ b1, const float* __restrict__ w2,
                             const float* __restrict__ b2, const float* __restrict__ w3,
                             const float* __restrict__ b3, float* __restrict__ out) {
    __shared__ float xs[FEAT];
    __shared__ float h1s[FFNN_DIM];
    __shared__ float red[256];
    int r = blockIdx.x, t = threadIdx.x;
    if (t < FEAT) xs[t] = x[r * FEAT + t];
    __syncthreads();
    for (int j = t; j < FFNN_DIM; j += 256) {
        float acc = b1[j];
        for (int k = 0; k < FEAT; ++k) acc += xs[k] * w1[k * FFNN_DIM + j];
        h1s[j] = fmaxf(acc, 0.f);
    }
    __syncthreads();
    float partial = 0.f;
    for (int j = t; j < FFNN_DIM; j += 256) {
        float acc = b2[j];
        for (int k = 0; k < FFNN_DIM; ++k) acc += h1s[k] * w2[k * FFNN_DIM + j];
        partial += fmaxf(acc, 0.f) * w3[j];
    }
    red[t] = partial;
    __syncthreads();
    for (int s = 128; s > 0; s >>= 1) { if (t < s) red[t] += red[t + s]; __syncthreads(); }
    if (t == 0) out[r] = red[0] + b3[0];
}

// ---------------- attention weights per span: attn_g [8192][32] ----------------
__global__ void attn_kernel(const float* __restrict__ head_s, const int* __restrict__ starts,
                            const int* __restrict__ ends, float* __restrict__ attn_g) {
    int wave = threadIdx.x >> 6, w = threadIdx.x & 63;
    int c = blockIdx.x * 4 + wave;
    if (c >= NUM_CAND) return;
    int s = starts[c], e = ends[c];
    int wid = e - s;
    float hsv = -INFINITY;
    if (w < MSW && w <= wid) hsv = head_s[s + w];
    float m = hsv;
    for (int off = 32; off > 0; off >>= 1) m = fmaxf(m, __shfl_down(m, off));
    m = __shfl(m, 0);
    float ex = (w < MSW && w <= wid) ? expf(hsv - m) : 0.f;
    float ssum = ex;
    for (int off = 32; off > 0; off >>= 1) ssum += __shfl_down(ssum, off);
    ssum = __shfl(ssum, 0);
    if (w < 32) attn_g[c * 32 + w] = (w < MSW) ? (ex / ssum) : 0.f;
}

// ---------------- doc fp32 -> 3-split bf16 [2048*768] ----------------
__global__ void doc_convert(const float* __restrict__ doc, unsigned short* __restrict__ d0,
                            unsigned short* __restrict__ d1, unsigned short* __restrict__ d2) {
    int i = blockIdx.x * 256 + threadIdx.x;
    if (i < NUM_WORDS * HIDDEN) store_split3(d0, d1, d2, i, doc[i]);
}

// ---------------- weight convert+transpose: w[K][N] -> 3-split [gridDim.y][Kp] ------------
__global__ void convert_wt(const float* __restrict__ w, int K, int N, int Kp,
                           unsigned short* __restrict__ q0, unsigned short* __restrict__ q1,
                           unsigned short* __restrict__ q2) {
    int n = blockIdx.y;
    int k = blockIdx.x * blockDim.x + threadIdx.x;
    if (k >= Kp) return;
    float v = (k < K && n < N) ? w[(size_t)k * N + n] : 0.f;
    store_split3(q0, q1, q2, (size_t)n * Kp + k, v);
}

// ---------------- fused Wc convert: 3 segments of m_w1 -> 3-split [3072][768] ------------
// r18: replaces three convert_wt launches (bit-identical arithmetic). seg row bases:
// 0 -> rows 0..767 (start), 1 -> rows 768..1535 (end), 2 -> rows 1556..2323 (attended).
__global__ void convert_wc(const float* __restrict__ w1,
                           unsigned short* __restrict__ q0, unsigned short* __restrict__ q1,
                           unsigned short* __restrict__ q2) {
    int n2 = blockIdx.y;                    // 0..3071 output row
    int seg = n2 >> 10;
    int n = n2 & 1023;                      // col within segment
    int k = blockIdx.x * 256 + threadIdx.x; // 0..767
    int row0 = (seg == 0) ? 0 : ((seg == 1) ? HIDDEN : 1556);
    float v = (n < FFNN_DIM) ? w1[(size_t)(row0 + k) * FFNN_DIM + n] : 0.f;
    store_split3(q0, q1, q2, (size_t)n2 * HIDDEN + k, v);
}

// ---------------- T_w[wid][1024] = span_width_emb[wid] @ m_w1[1536:1556] ----------------
__global__ void tw_kernel(const float* __restrict__ swe, const float* __restrict__ w1,
                          float* __restrict__ tw) {
    int wid = blockIdx.x, t = threadIdx.x;
    for (int n = t; n < NP; n += 256) {
        float acc = 0.f;
        if (n < FFNN_DIM) {
            for (int f = 0; f < FEAT; ++f)
                acc += swe[wid * FEAT + f] * w1[(size_t)(1536 + f) * FFNN_DIM + n];
        }
        tw[wid * NP + n] = acc;
    }
}

// Stage one 128x32-bf16 tile (8KB) async into LDS with XOR swizzle.
__device__ __forceinline__ void stage_tile(const unsigned short* __restrict__ src,
                                           unsigned short* lds, int base_row, int Kp, int k0,
                                           int t) {
#pragma unroll
    for (int qi = 0; qi < 2; ++qi) {
        int u = qi * 256 + t;
        int l = u & 63;
        int row = ((u >> 6) << 4) + (l >> 2);
        int cblk = (l & 3) ^ (row & 3);
        const unsigned short* g = src + (size_t)(base_row + row) * Kp + k0 + cblk * 8;
        gl_lds16(g, lds + u * 8);
    }
}

// ---------------- 3-split 6-product MFMA GEMM, fp32 out: P = doc @ [W_s|W_e|W_a] ---------
__global__ __launch_bounds__(256, 2) void gemm6p(
    const unsigned short* __restrict__ A0, const unsigned short* __restrict__ A1,
    const unsigned short* __restrict__ A2,
    const unsigned short* __restrict__ B0, const unsigned short* __restrict__ B1,
    const unsigned short* __restrict__ B2,
    float* __restrict__ C) {
    __shared__ unsigned short As0[128 * 32], As1[128 * 32], As2[128 * 32];
    __shared__ unsigned short Bs0[128 * 32], Bs1[128 * 32], Bs2[128 * 32];
    int t = threadIdx.x;
    int bid = blockIdx.x;
    int bm = (bid & 15) << 7;
    int bn = (bid >> 4) << 7;
    int lane = t & 63, wv = t >> 6;
    int wm = (wv >> 1) * 64, wn = (wv & 1) * 64;
    int lr = lane & 15, qq = lane >> 4;
    int sw = (qq ^ (lr & 3)) * 8;

    f32x4 acc[4][4] = {};

    for (int k0 = 0; k0 < HIDDEN; k0 += 32) {
        stage_tile(A0, As0, bm, HIDDEN, k0, t);
        stage_tile(A1, As1, bm, HIDDEN, k0, t);
        stage_tile(A2, As2, bm, HIDDEN, k0, t);
        stage_tile(B0, Bs0, bn, HIDDEN, k0, t);
        stage_tile(B1, Bs1, bn, HIDDEN, k0, t);
        stage_tile(B2, Bs2, bn, HIDDEN, k0, t);
        __syncthreads();
        short8 a0[4], a1[4], a2[4];
#pragma unroll
        for (int i = 0; i < 4; ++i) {
            int ra = (wm + i * 16 + lr) * 32 + sw;
            a0[i] = *(const short8*)&As0[ra];
            a1[i] = *(const short8*)&As1[ra];
            a2[i] = *(const short8*)&As2[ra];
        }
#pragma unroll
        for (int j = 0; j < 4; ++j) {
            int rb = (wn + j * 16 + lr) * 32 + sw;
            short8 b0 = *(const short8*)&Bs0[rb];
            short8 b1 = *(const short8*)&Bs1[rb];
            short8 b2 = *(const short8*)&Bs2[rb];
#pragma unroll
            for (int i = 0; i < 4; ++i) {
                acc[i][j] = __builtin_amdgcn_mfma_f32_16x16x32_bf16(a2[i], b0, acc[i][j], 0, 0, 0);
                acc[i][j] = __builtin_amdgcn_mfma_f32_16x16x32_bf16(a0[i], b2, acc[i][j], 0, 0, 0);
                acc[i][j] = __builtin_amdgcn_mfma_f32_16x16x32_bf16(a1[i], b1, acc[i][j], 0, 0, 0);
                acc[i][j] = __builtin_amdgcn_mfma_f32_16x16x32_bf16(a1[i], b0, acc[i][j], 0, 0, 0);
                acc[i][j] = __builtin_amdgcn_mfma_f32_16x16x32_bf16(a0[i], b1, acc[i][j], 0, 0, 0);
                acc[i][j] = __builtin_amdgcn_mfma_f32_16x16x32_bf16(a0[i], b0, acc[i][j], 0, 0, 0);
            }
        }
        __syncthreads();
    }
#pragma unroll
    for (int i = 0; i < 4; ++i)
#pragma unroll
        for (int j = 0; j < 4; ++j)
#pragma unroll
            for (int r = 0; r < 4; ++r) {
                int m = bm + wm + i * 16 + qq * 4 + r;
                int n = bn + wn + j * 16 + lr;
                C[(size_t)m * PNP + n] = acc[i][j][r];
            }
}

// ---------------- combine: h1[c] = relu(P_s[s] + P_e[e] + sum attn*P_a[s+w] + Tw + b1) ----
// r16: float4 loads (all P/tw/b1 offsets 16B-aligned) + ushort4 split stores. Bit-exact.
__global__ void combine_kernel(const float* __restrict__ P, const float* __restrict__ tw,
                               const float* __restrict__ attn_g, const float* __restrict__ b1,
                               const int* __restrict__ starts, const int* __restrict__ ends,
                               unsigned short* __restrict__ h0, unsigned short* __restrict__ h1,
                               unsigned short* __restrict__ h2) {
    int c = blockIdx.x, t = threadIdx.x;
    int s = starts[c], e = ends[c];
    int wid = e - s;
    __shared__ float at[MSW];
    if (t < MSW) at[t] = attn_g[c * 32 + t];
    __syncthreads();
    int n0 = t * 4;
    size_t ho = (size_t)c * NP + n0;
    if (t < 250) {
        f32x4 acc = *(const f32x4*)&P[(size_t)s * PNP + n0];
        acc += *(const f32x4*)&P[(size_t)e * PNP + 1024 + n0];
        acc += *(const f32x4*)&tw[(size_t)wid * NP + n0];
        acc += *(const f32x4*)&b1[n0];
        const float* Pa = P + (size_t)s * PNP + 2048 + n0;
        for (int w = 0; w <= wid; ++w)
            acc += at[w] * *(const f32x4*)&Pa[(size_t)w * PNP];
        u16x4 q0, q1, q2;
#pragma unroll
        for (int k = 0; k < 4; ++k) {
            float v = fmaxf(acc[k], 0.f);
            unsigned short x0 = bf16_rne(v);
            float r1 = v - bf16_to_f(x0);
            unsigned short x1 = bf16_rne(r1);
            float r2 = r1 - bf16_to_f(x1);
            q0[k] = x0; q1[k] = x1; q2[k] = bf16_rne(r2);
        }
        *(u16x4*)&h0[ho] = q0;
        *(u16x4*)&h1[ho] = q1;
        *(u16x4*)&h2[ho] = q2;
    } else {
        u16x4 z = {0, 0, 0, 0};
        *(u16x4*)&h0[ho] = z;
        *(u16x4*)&h1[ho] = z;
        *(u16x4*)&h2[ho] = z;
    }
}

// ---------------- 3-split 6-product MFMA GEMM (score fusion) ------------
__global__ __launch_bounds__(256, 2) void gemm6(
    const unsigned short* __restrict__ A0, const unsigned short* __restrict__ A1,
    const unsigned short* __restrict__ A2,
    const unsigned short* __restrict__ B0, const unsigned short* __restrict__ B1,
    const unsigned short* __restrict__ B2,
    const float* __restrict__ bias, int nreal, int Kp,
    const float* __restrict__ w3, float* __restrict__ partials) {
    __shared__ unsigned short As0[128 * 32], As1[128 * 32], As2[128 * 32];
    __shared__ unsigned short Bs0[128 * 32], Bs1[128 * 32], Bs2[128 * 32];
    int t = threadIdx.x;
    int bid = blockIdx.x;
    int sm = bid >> 6, idx = bid & 63;
    int bm = ((sm << 3) + (idx & 7)) << 7;
    int bn = (idx >> 3) << 7;
    int lane = t & 63, wv = t >> 6;
    int wm = (wv >> 1) * 64, wn = (wv & 1) * 64;
    int lr = lane & 15, qq = lane >> 4;
    int sw = (qq ^ (lr & 3)) * 8;

    f32x4 acc[4][4] = {};

    for (int k0 = 0; k0 < Kp; k0 += 32) {
        stage_tile(A0, As0, bm, Kp, k0, t);
        stage_tile(A1, As1, bm, Kp, k0, t);
        stage_tile(A2, As2, bm, Kp, k0, t);
        stage_tile(B0, Bs0, bn, Kp, k0, t);
        stage_tile(B1, Bs1, bn, Kp, k0, t);
        stage_tile(B2, Bs2, bn, Kp, k0, t);
        __syncthreads();
        short8 a0[4], a1[4], a2[4];
#pragma unroll
        for (int i = 0; i < 4; ++i) {
            int ra = (wm + i * 16 + lr) * 32 + sw;
            a0[i] = *(const short8*)&As0[ra];
            a1[i] = *(const short8*)&As1[ra];
            a2[i] = *(const short8*)&As2[ra];
        }
#pragma unroll
        for (int j = 0; j < 4; ++j) {
            int rb = (wn + j * 16 + lr) * 32 + sw;
            short8 b0 = *(const short8*)&Bs0[rb];
            short8 b1 = *(const short8*)&Bs1[rb];
            short8 b2 = *(const short8*)&Bs2[rb];
#pragma unroll
            for (int i = 0; i < 4; ++i) {
                acc[i][j] = __builtin_amdgcn_mfma_f32_16x16x32_bf16(a2[i], b0, acc[i][j], 0, 0, 0);
                acc[i][j] = __builtin_amdgcn_mfma_f32_16x16x32_bf16(a0[i], b2, acc[i][j], 0, 0, 0);
                acc[i][j] = __builtin_amdgcn_mfma_f32_16x16x32_bf16(a1[i], b1, acc[i][j], 0, 0, 0);
                acc[i][j] = __builtin_amdgcn_mfma_f32_16x16x32_bf16(a1[i], b0, acc[i][j], 0, 0, 0);
                acc[i][j] = __builtin_amdgcn_mfma_f32_16x16x32_bf16(a0[i], b1, acc[i][j], 0, 0, 0);
                acc[i][j] = __builtin_amdgcn_mfma_f32_16x16x32_bf16(a0[i], b0, acc[i][j], 0, 0, 0);
            }
        }
        __syncthreads();
    }

    int pid = ((bn >> 7) << 1) | (wn >> 6);  // 0..15
#pragma unroll
    for (int i = 0; i < 4; ++i)
#pragma unroll
        for (int r = 0; r < 4; ++r) {
            float p = 0.f;
#pragma unroll
            for (int j = 0; j < 4; ++j) {
                int n = bn + wn + j * 16 + lr;
                float v = acc[i][j][r] + (n < nreal ? bias[n] : 0.f);
                v = fmaxf(v, 0.f);
                p += v * (n < nreal ? w3[n] : 0.f);
            }
            p += __shfl_xor(p, 1);
            p += __shfl_xor(p, 2);
            p += __shfl_xor(p, 4);
            p += __shfl_xor(p, 8);
            if (lr == 0) {
                int m = bm + wm + i * 16 + qq * 4 + r;
                partials[(size_t)m * 16 + pid] = p;
            }
        }
}

// ---------------- deterministic score finalize ----------------
__global__ void score_final(const float* __restrict__ partials, const float* __restrict__ b3,
                            const float* __restrict__ width_s, const int* __restrict__ starts,
                            const int* __restrict__ ends, float* __restrict__ out) {
    int c = blockIdx.x * 256 + threadIdx.x;
    if (c >= NUM_CAND) return;
    float s = b3[0] + width_s[ends[c] - starts[c]];
#pragma unroll
    for (int p = 0; p < 16; ++p) s += partials[(size_t)c * 16 + p];
    out[c] = s;
}

// ---------------- exact counting rank-sort: 256 blocks ----------------
__global__ __launch_bounds__(256) void rank_kernel(const float* __restrict__ scores,
                                                   const int* __restrict__ starts,
                                                   const int* __restrict__ ends,
                                                   unsigned short* __restrict__ ord_g,
                                                   unsigned int* __restrict__ se_g) {
    __shared__ unsigned long long kk[NUM_CAND];  // 64 KB
    int t = threadIdx.x;
    for (int i = t; i < NUM_CAND; i += 256) {
        unsigned int b = __float_as_uint(scores[i]);
        unsigned int u = b ^ ((b & 0x80000000u) ? 0xFFFFFFFFu : 0x80000000u);
        unsigned int hi = ~u;
        kk[i] = ((unsigned long long)hi << 32) | (unsigned int)i;
    }
    __syncthreads();
    int c = blockIdx.x * 32 + (t >> 3);
    int seg = (t & 7) * 1024;
    unsigned long long mykey = kk[c];
    int cnt = 0;
    for (int i = seg; i < seg + 1024; ++i) cnt += (kk[i] < mykey) ? 1 : 0;
    cnt += __shfl_xor(cnt, 1);
    cnt += __shfl_xor(cnt, 2);
    cnt += __shfl_xor(cnt, 4);
    if ((t & 7) == 0) {
        int idx = (int)(mykey & 0xFFFFFFFFull);
        int rank = cnt;
        ord_g[rank] = (unsigned short)idx;
        se_g[rank] = ((unsigned int)starts[idx] << 16) | (unsigned int)ends[idx];
    }
}

// ---------------- single-wave pipelined greedy crossing-NMS ----------------
// r18: software-pipeline the r17 single-wave loop. Per chunk, the next chunk's 30-word st
// snapshot is ISSUED BEFORE the serial resolve (the resolve is pure SALU/VALU, so the LDS
// reads complete underneath it). Those reads miss only the CURRENT chunk's accepts, which
// the r13-verified fix-up formulas repair afterwards (readlane loop over the lcnt accepted
// (s,e) pairs). The accept-apply ds_atomics after the resolve pin the prefetched reads
// above them (may-alias), so the compiler cannot sink the loads and lose the overlap.
// Resolve decision loop byte-identical to the r2..r17-verified form.
__global__ __launch_bounds__(64, 1)
void select_nms(const unsigned int* __restrict__ se_g,
                unsigned short* __restrict__ sel_g,
                int* __restrict__ count_g) {
    __shared__ unsigned int se_arr[NUM_CAND];   // 32 KB
    __shared__ unsigned int st[2 * NUM_WORDS];  // 16 KB
    int lane = threadIdx.x;

    {
        const uint4* src4 = (const uint4*)se_g;
        uint4* dst4 = (uint4*)se_arr;
        for (int i = lane; i < NUM_CAND / 4; i += 64) dst4[i] = src4[i];
    }
    for (int i = lane; i < 2 * NUM_WORDS; i += 64)
        st[i] = (i & 1) ? (unsigned int)NUM_WORDS : 0u;  // max_end+1=0, min_start=2048
    __syncthreads();

    const unsigned long long* stp = (const unsigned long long*)st;

    // ---- prologue: chunk 0 snapshot + predicate (pristine st) ----
    unsigned int sev = se_arr[lane];
    int s = (int)(sev >> 16), e = (int)(sev & 0xFFFFu);
    int me;
    bool crossed;
    {
        const unsigned long long* bp = stp + s;
        unsigned long long v[MSW];
#pragma unroll
        for (int w = 0; w < MSW; ++w) v[w] = bp[w];
        me = (int)(unsigned int)v[0] - 1;
        bool cA = (s < e) && ((int)(unsigned int)(v[0] >> 32) < s);
        bool cB = false;
#pragma unroll
        for (int w = 1; w < MSW; ++w) {
            int j = s + w;
            bool in = (j <= e);
            int mej = (int)(unsigned int)v[w] - 1;
            int msj = (int)(unsigned int)(v[w] >> 32);
            bool hit = in && ((mej > e) || ((j < e) && (msj < s)));
            if (w & 1) cA = cA || hit; else cB = cB || hit;
        }
        crossed = cA || cB;
    }
    bool spec = !crossed && (me != e);

    int count = 0;
    for (int c = 0; c < NUM_CAND / 64; ++c) {
        int ib = c * 64;
        bool have_next = (c + 1 < NUM_CAND / 64);
        // ---- prefetch next chunk's spans + stale snapshot (completes under resolve) ----
        unsigned int sev_n = 0;
        int s_n = 0, e_n = 0;
        unsigned long long vn[MSW];
        if (have_next) {
            sev_n = se_arr[ib + 64 + lane];
            s_n = (int)(sev_n >> 16);
            e_n = (int)(sev_n & 0xFFFFu);
            const unsigned long long* bp = stp + s_n;
#pragma unroll
            for (int w = 0; w < MSW; ++w) vn[w] = bp[w];
        }

        // ---- serial resolve — decision loop identical to the verified form ----
        int cbefore = count;
        unsigned long long window = ~0ull;
        unsigned int pend = 0u;
        int rk = 0, lcnt = 0;
        while (true) {
            unsigned long long b = __ballot(spec) & window;
            if (b == 0ull) break;
            int f = __ffsll((unsigned long long)b) - 1;
            unsigned int sef = __builtin_amdgcn_readlane(sev, (unsigned int)f);
            int sf = (int)(sef >> 16), ef = (int)(sef & 0xFFFFu);
            bool mine = (lane == lcnt);
            pend = mine ? sef : pend;
            rk = mine ? (ib + f) : rk;
            lcnt++;
            count++;
            if (count >= TOP_NUM) break;
            window &= (f >= 63) ? 0ull : (~0ull << (f + 1));
            if (lane > f) {
                if (s == sf) me = max(me, ef);
                crossed = crossed || ((s < sf) && (sf <= e) && (ef > e))
                                  || ((sf < s) && (s <= ef) && (ef < e));
                spec = !crossed && (me != e);
            }
        }
        if (lane < lcnt) {
            int sf = (int)(pend >> 16), ef = (int)(pend & 0xFFFFu);
            sel_g[cbefore + lane] = (unsigned short)rk;
            atomicMax(&st[2 * sf], (unsigned int)(ef + 1));
            atomicMin(&st[2 * ef + 1], (unsigned int)sf);
        }
        if (count >= TOP_NUM || !have_next) break;

        // ---- build next predicate from the stale snapshot ----
        int me_n = (int)(unsigned int)vn[0] - 1;
        bool cA = (s_n < e_n) && ((int)(unsigned int)(vn[0] >> 32) < s_n);
        bool cB = false;
#pragma unroll
        for (int w = 1; w < MSW; ++w) {
            int j = s_n + w;
            bool in = (j <= e_n);
            int mej = (int)(unsigned int)vn[w] - 1;
            int msj = (int)(unsigned int)(vn[w] >> 32);
            bool hit = in && ((mej > e_n) || ((j < e_n) && (msj < s_n)));
            if (w & 1) cA = cA || hit; else cB = cB || hit;
        }
        bool crossed_n = cA || cB;
        // ---- fix-ups: apply this chunk's accepts (r13-verified formulas) ----
        for (int k = 0; k < lcnt; ++k) {
            unsigned int sef = __builtin_amdgcn_readlane(pend, (unsigned int)k);
            int sf = (int)(sef >> 16), ef = (int)(sef & 0xFFFFu);
            if (s_n == sf) me_n = max(me_n, ef);
            crossed_n = crossed_n || ((s_n < sf) && (sf <= e_n) && (ef > e_n))
                                  || ((sf < s_n) && (s_n <= ef) && (ef < e_n));
        }
        // ---- rotate ----
        sev = sev_n; s = s_n; e = e_n; me = me_n; crossed = crossed_n;
        spec = !crossed && (me != e);
    }
    if (lane == 0) *count_g = count;
}

// ---------------- post: final span-order sort + emit ----------------
__global__ __launch_bounds__(256) void select_post(const float* __restrict__ scores,
                                                   const int* __restrict__ starts,
                                                   const int* __restrict__ ends,
                                                   const unsigned short* __restrict__ ord_g,
                                                   const unsigned short* __restrict__ sel_g,
                                                   const int* __restrict__ count_g,
                                                   float* out, int* top_idx_ws) {
    __shared__ unsigned long long fkeys[1024];
    int t = threadIdx.x;
    int count = *count_g;
    for (int i = t; i < 1024; i += 256) {
        unsigned long long k = 0xFFFFFFFFFFFFFFFFull;
        if (i < count) {
            int idx = (int)ord_g[sel_g[i]];
            unsigned int key32 = (unsigned int)(starts[idx] * NUM_WORDS + ends[idx]);
            k = ((unsigned long long)key32 << 32) | (unsigned int)idx;
        }
        fkeys[i] = k;
    }
    __syncthreads();
    for (int size = 2; size <= 1024; size <<= 1) {
        for (int stride = size >> 1; stride > 0; stride >>= 1) {
            for (int i = t; i < 1024; i += 256) {
                int ixj = i ^ stride;
                if (ixj > i) {
                    bool up = ((i & size) == 0);
                    unsigned long long a = fkeys[i], b = fkeys[ixj];
                    if ((a > b) == up) { fkeys[i] = b; fkeys[ixj] = a; }
                }
            }
            __syncthreads();
        }
    }
    for (int i = t; i < TOP_NUM; i += 256) {
        int fi = (i < count) ? (int)(fkeys[i] & 0xFFFFFFFFull)
                             : (int)(fkeys[0] & 0xFFFFFFFFull);
        out[OUT_TOPIDX + i] = (float)fi;
        out[OUT_TSTART + i] = (float)starts[fi];
        out[OUT_TEND + i] = (float)ends[fi];
        out[OUT_TSCORE + i] = scores[fi];
        top_idx_ws[i] = fi;
    }
}

// ---------------- gather top_span_emb rows directly from doc (exact fp32) ----------------
__global__ void gather_emb(const float* __restrict__ doc, const float* __restrict__ swe,
                           const float* __restrict__ attn_g, const int* __restrict__ starts,
                           const int* __restrict__ ends, const int* __restrict__ top_idx_ws,
                           float* __restrict__ out) {
    int r = blockIdx.x, t = threadIdx.x;
    int idx = top_idx_ws[r];
    int s = starts[idx], e = ends[idx];
    int wid = e - s;
    __shared__ float at[MSW];
    if (t < MSW) at[t] = attn_g[(size_t)idx * 32 + t];
    __syncthreads();
    float* dst = out + OUT_TEMB + (size_t)r * SPAN_DIM;
    if (t < 192) {
        int h4 = t * 4;
        f32x4 vs = *(const f32x4*)&doc[(size_t)s * HIDDEN + h4];
        f32x4 ve = *(const f32x4*)&doc[(size_t)e * HIDDEN + h4];
        f32x4 acc = {0.f, 0.f, 0.f, 0.f};
        for (int w = 0; w <= wid; ++w)
            acc += at[w] * *(const f32x4*)&doc[(size_t)(s + w) * HIDDEN + h4];
#pragma unroll
        for (int k = 0; k < 4; ++k) {
            dst[h4 + k] = vs[k];
            dst[HIDDEN + h4 + k] = ve[k];
            dst[2 * HIDDEN + FEAT + h4 + k] = acc[k];
        }
    }
    if (t < FEAT) dst[2 * HIDDEN + t] = swe[wid * FEAT + t];
}

extern "C" void kernel_launch(void* const* d_in, const int* in_sizes, int n_in,
                              void* d_out, int out_size, void* d_ws, size_t ws_size,
                              hipStream_t stream) {
    const float* mention_doc = (const float*)d_in[0];
    const float* span_width_emb = (const float*)d_in[1];
    const float* head_w = (const float*)d_in[2];
    const float* head_b = (const float*)d_in[3];
    const float* m_w1 = (const float*)d_in[4];
    const float* m_b1 = (const float*)d_in[5];
    const float* m_w2 = (const float*)d_in[6];
    const float* m_b2 = (const float*)d_in[7];
    const float* m_w3 = (const float*)d_in[8];
    const float* m_b3 = (const float*)d_in[9];
    const float* width_prior_emb = (const float*)d_in[10];
    const float* w_w1 = (const float*)d_in[11];
    const float* w_b1 = (const float*)d_in[12];
    const float* w_w2 = (const float*)d_in[13];
    const float* w_b2 = (const float*)d_in[14];
    const float* w_w3 = (const float*)d_in[15];
    const float* w_b3 = (const float*)d_in[16];
    const int* cand_starts = (const int*)d_in[17];
    const int* cand_ends = (const int*)d_in[18];

    char* w = (char*)d_ws;
    const size_t szH = (size_t)NUM_CAND * NP * 2;
    const size_t szW2 = (size_t)NP * KP2 * 2;
    const size_t szWc = (size_t)PNP * HIDDEN * 2;
    const size_t szD = (size_t)NUM_WORDS * HIDDEN * 2;
    char* p = w;
    unsigned short* h0 = (unsigned short*)p; p += szH;
    unsigned short* h1 = (unsigned short*)p; p += szH;
    unsigned short* h2 = (unsigned short*)p; p += szH;
    unsigned short* w2t0 = (unsigned short*)p; p += szW2;
    unsigned short* w2t1 = (unsigned short*)p; p += szW2;
    unsigned short* w2t2 = (unsigned short*)p; p += szW2;
    unsigned short* Wc0 = (unsigned short*)p; p += szWc;
    unsigned short* Wc1 = (unsigned short*)p; p += szWc;
    unsigned short* Wc2 = (unsigned short*)p; p += szWc;
    unsigned short* d0 = (unsigned short*)p; p += szD;
    unsigned short* d1 = (unsigned short*)p; p += szD;
    unsigned short* d2 = (unsigned short*)p; p += szD;
    float* P = (float*)p; p += (size_t)NUM_WORDS * PNP * 4;
    float* tw = (float*)p; p += (size_t)MSW * NP * 4;
    float* attn_g = (float*)p; p += (size_t)NUM_CAND * 32 * 4;
    float* partials = (float*)p; p += (size_t)NUM_CAND * 16 * 4;
    unsigned short* ord_g = (unsigned short*)p; p += (size_t)NUM_CAND * 2;
    unsigned int* se_g = (unsigned int*)p; p += (size_t)NUM_CAND * 4;
    unsigned short* sel_g = (unsigned short*)p; p += 2048;
    int* count_g = (int*)p; p += 128;
    float* head_s = (float*)p; p += NUM_WORDS * 4;
    float* width_s = (float*)p; p += 128;
    int* top_idx_ws = (int*)p; p += 4096;

    size_t need = (size_t)(p - w);
    if (ws_size < need) {
        fprintf(stderr, "kernel_launch: ws too small (%zu < %zu)\n", ws_size, need);
    }

    float* out = (float*)d_out;

    head_kernel<<<NUM_WORDS / 4, 256, 0, stream>>>(mention_doc, head_w, head_b, head_s);
    width_kernel<<<MSW, 256, 0, stream>>>(width_prior_emb, w_w1, w_b1, w_w2, w_b2, w_w3, w_b3,
                                          width_s);
    attn_kernel<<<NUM_CAND / 4, 256, 0, stream>>>(head_s, cand_starts, cand_ends, attn_g);
    doc_convert<<<(NUM_WORDS * HIDDEN + 255) / 256, 256, 0, stream>>>(mention_doc, d0, d1, d2);
    convert_wc<<<dim3(3, 3072), 256, 0, stream>>>(m_w1, Wc0, Wc1, Wc2);
    convert_wt<<<dim3(4, 1024), 256, 0, stream>>>(m_w2, FFNN_DIM, FFNN_DIM, KP2,
                                                  w2t0, w2t1, w2t2);
    tw_kernel<<<MSW, 256, 0, stream>>>(span_width_emb, m_w1, tw);
    gemm6p<<<16 * 24, 256, 0, stream>>>(d0, d1, d2, Wc0, Wc1, Wc2, P);
    combine_kernel<<<NUM_CAND, 256, 0, stream>>>(P, tw, attn_g, m_b1, cand_starts, cand_ends,
                                                 h0, h1, h2);
    gemm6<<<512, 256, 0, stream>>>(h0, h1, h2, w2t0, w2t1, w2t2, m_b2, FFNN_DIM, KP2,
                                   m_w3, partials);
    score_final<<<NUM_CAND / 256, 256, 0, stream>>>(partials, m_b3, width_s, cand_starts,
                                                    cand_ends, out);
    rank_kernel<<<NUM_CAND / 32, 256, 0, stream>>>(out, cand_starts, cand_ends, ord_g, se_g);
    select_nms<<<1, 64, 0, stream>>>(se_g, sel_g, count_g);
    select_post<<<1, 256, 0, stream>>>(out, cand_starts, cand_ends, ord_g, sel_g, count_g,
                                       out, top_idx_ws);
    gather_emb<<<TOP_NUM, 256, 0, stream>>>(mention_doc, span_width_emb, attn_g, cand_starts,
                                            cand_ends, top_idx_ws, out);
}

// Round 5
// 920.035 us; speedup vs baseline: 1.0269x; 1.0269x over previous
//
#include <hip/hip_runtime.h>
#include <cstdio>
#include <cmath>

#define NUM_WORDS 2048
#define NUM_CAND 8192
#define HIDDEN 768
#define FEAT 20
#define FFNN_DIM 1000
#define SPAN_DIM 2324
#define TOP_NUM 819
#define MSW 30
#define KP2 1024   // FFNN padded to x32
#define NP 1024    // padded N
#define PNP 3072   // P matrix padded N (3 segments of 1024)

// d_out layout (floats): [scores 8192][top_idx 819][top_starts 819][top_ends 819]
//                        [top_span_emb 819*2324][top_scores 819]
#define OUT_TOPIDX   (NUM_CAND)
#define OUT_TSTART   (NUM_CAND + TOP_NUM)
#define OUT_TEND     (NUM_CAND + 2*TOP_NUM)
#define OUT_TEMB     (NUM_CAND + 3*TOP_NUM)
#define OUT_TSCORE   (NUM_CAND + 3*TOP_NUM + TOP_NUM*SPAN_DIM)

typedef short short8 __attribute__((ext_vector_type(8)));
typedef float f32x4 __attribute__((ext_vector_type(4)));
typedef unsigned short u16x4 __attribute__((ext_vector_type(4)));

__device__ __forceinline__ unsigned short bf16_rne(float x) {
    unsigned int u = __float_as_uint(x);
    unsigned int r = u + 0x7FFFu + ((u >> 16) & 1u);
    return (unsigned short)(r >> 16);
}
__device__ __forceinline__ float bf16_to_f(unsigned short h) {
    return __uint_as_float(((unsigned int)h) << 16);
}
// 3-way split: v = s0 + s1 + s2 + r, |r| <= 2^-27 |v|
__device__ __forceinline__ void store_split3(unsigned short* p0, unsigned short* p1,
                                             unsigned short* p2, size_t off, float v) {
    unsigned short h0 = bf16_rne(v);
    float r1 = v - bf16_to_f(h0);
    unsigned short h1 = bf16_rne(r1);
    float r2 = r1 - bf16_to_f(h1);
    p0[off] = h0;
    p1[off] = h1;
    p2[off] = bf16_rne(r2);
}

// async 16B global->LDS (gfx950 global_load_lds_dwordx4). LDS dest must be
// wave-uniform base + lane*16 -> staging tiles are UNPADDED (128x32 bf16, 64B rows),
// bank conflicts handled by XOR swizzle: kblk stored at kblk^(row&3).
__device__ __forceinline__ void gl_lds16(const unsigned short* g, unsigned short* l) {
    __builtin_amdgcn_global_load_lds(
        (const __attribute__((address_space(1))) unsigned short*)g,
        (__attribute__((address_space(3))) unsigned short*)l, 16, 0, 0);
}

// ---------------- head scores: doc @ head_w + head_b  -> [2048] ----------------
__global__ void head_kernel(const float* __restrict__ doc, const float* __restrict__ hw,
                            const float* __restrict__ hb, float* __restrict__ out) {
    int wave = threadIdx.x >> 6, lane = threadIdx.x & 63;
    int row = blockIdx.x * 4 + wave;
    if (row >= NUM_WORDS) return;
    float acc = 0.f;
    for (int h = lane; h < HIDDEN; h += 64) acc += doc[row * HIDDEN + h] * hw[h];
    for (int off = 32; off > 0; off >>= 1) acc += __shfl_down(acc, off);
    if (lane == 0) out[row] = acc + hb[0];
}

// ---------------- width prior ffnn: [30,20] -> [30] ----------------
__global__ void width_kernel(const float* __restrict__ x, const float* __restrict__ w1,
                             const float* __restrict__ b1, const float* __restrict__ w2,
                             const float* __restrict__ b2, const float* __restrict__ w3,
                             const float* __restrict__ b3, float* __restrict__ out) {
    __shared__ float xs[FEAT];
    __shared__ float h1s[FFNN_DIM];
    __shared__ float red[256];
    int r = blockIdx.x, t = threadIdx.x;
    if (t < FEAT) xs[t] = x[r * FEAT + t];
    __syncthreads();
    for (int j = t; j < FFNN_DIM; j += 256) {
        float acc = b1[j];
        for (int k = 0; k < FEAT; ++k) acc += xs[k] * w1[k * FFNN_DIM + j];
        h1s[j] = fmaxf(acc, 0.f);
    }
    __syncthreads();
    float partial = 0.f;
    for (int j = t; j < FFNN_DIM; j += 256) {
        float acc = b2[j];
        for (int k = 0; k < FFNN_DIM; ++k) acc += h1s[k] * w2[k * FFNN_DIM + j];
        partial += fmaxf(acc, 0.f) * w3[j];
    }
    red[t] = partial;
    __syncthreads();
    for (int s = 128; s > 0; s >>= 1) { if (t < s) red[t] += red[t + s]; __syncthreads(); }
    if (t == 0) out[r] = red[0] + b3[0];
}

// ---------------- attention weights per span: attn_g [8192][32] ----------------
__global__ void attn_kernel(const float* __restrict__ head_s, const int* __restrict__ starts,
                            const int* __restrict__ ends, float* __restrict__ attn_g) {
    int wave = threadIdx.x >> 6, w = threadIdx.x & 63;
    int c = blockIdx.x * 4 + wave;
    if (c >= NUM_CAND) return;
    int s = starts[c], e = ends[c];
    int wid = e - s;
    float hsv = -INFINITY;
    if (w < MSW && w <= wid) hsv = head_s[s + w];
    float m = hsv;
    for (int off = 32; off > 0; off >>= 1) m = fmaxf(m, __shfl_down(m, off));
    m = __shfl(m, 0);
    float ex = (w < MSW && w <= wid) ? expf(hsv - m) : 0.f;
    float ssum = ex;
    for (int off = 32; off > 0; off >>= 1) ssum += __shfl_down(ssum, off);
    ssum = __shfl(ssum, 0);
    if (w < 32) attn_g[c * 32 + w] = (w < MSW) ? (ex / ssum) : 0.f;
}

// ---------------- doc fp32 -> 3-split bf16 [2048*768] ----------------
__global__ void doc_convert(const float* __restrict__ doc, unsigned short* __restrict__ d0,
                            unsigned short* __restrict__ d1, unsigned short* __restrict__ d2) {
    int i = blockIdx.x * 256 + threadIdx.x;
    if (i < NUM_WORDS * HIDDEN) store_split3(d0, d1, d2, i, doc[i]);
}

// ---------------- weight convert+transpose: w[K][N] -> 3-split [gridDim.y][Kp] ------------
__global__ void convert_wt(const float* __restrict__ w, int K, int N, int Kp,
                           unsigned short* __restrict__ q0, unsigned short* __restrict__ q1,
                           unsigned short* __restrict__ q2) {
    int n = blockIdx.y;
    int k = blockIdx.x * blockDim.x + threadIdx.x;
    if (k >= Kp) return;
    float v = (k < K && n < N) ? w[(size_t)k * N + n] : 0.f;
    store_split3(q0, q1, q2, (size_t)n * Kp + k, v);
}

// ---------------- fused Wc convert: 3 segments of m_w1 -> 3-split [3072][768] ------------
// r18: replaces three convert_wt launches (bit-identical arithmetic). seg row bases:
// 0 -> rows 0..767 (start), 1 -> rows 768..1535 (end), 2 -> rows 1556..2323 (attended).
__global__ void convert_wc(const float* __restrict__ w1,
                           unsigned short* __restrict__ q0, unsigned short* __restrict__ q1,
                           unsigned short* __restrict__ q2) {
    int n2 = blockIdx.y;                    // 0..3071 output row
    int seg = n2 >> 10;
    int n = n2 & 1023;                      // col within segment
    int k = blockIdx.x * 256 + threadIdx.x; // 0..767
    int row0 = (seg == 0) ? 0 : ((seg == 1) ? HIDDEN : 1556);
    float v = (n < FFNN_DIM) ? w1[(size_t)(row0 + k) * FFNN_DIM + n] : 0.f;
    store_split3(q0, q1, q2, (size_t)n2 * HIDDEN + k, v);
}

// ---------------- T_w[wid][1024] = span_width_emb[wid] @ m_w1[1536:1556] ----------------
__global__ void tw_kernel(const float* __restrict__ swe, const float* __restrict__ w1,
                          float* __restrict__ tw) {
    int wid = blockIdx.x, t = threadIdx.x;
    for (int n = t; n < NP; n += 256) {
        float acc = 0.f;
        if (n < FFNN_DIM) {
            for (int f = 0; f < FEAT; ++f)
                acc += swe[wid * FEAT + f] * w1[(size_t)(1536 + f) * FFNN_DIM + n];
        }
        tw[wid * NP + n] = acc;
    }
}

// Stage one 128x32-bf16 tile (8KB) async into LDS with XOR swizzle.
__device__ __forceinline__ void stage_tile(const unsigned short* __restrict__ src,
                                           unsigned short* lds, int base_row, int Kp, int k0,
                                           int t) {
#pragma unroll
    for (int qi = 0; qi < 2; ++qi) {
        int u = qi * 256 + t;
        int l = u & 63;
        int row = ((u >> 6) << 4) + (l >> 2);
        int cblk = (l & 3) ^ (row & 3);
        const unsigned short* g = src + (size_t)(base_row + row) * Kp + k0 + cblk * 8;
        gl_lds16(g, lds + u * 8);
    }
}

// ---------------- 3-split 6-product MFMA GEMM, fp32 out: P = doc @ [W_s|W_e|W_a] ---------
__global__ __launch_bounds__(256, 2) void gemm6p(
    const unsigned short* __restrict__ A0, const unsigned short* __restrict__ A1,
    const unsigned short* __restrict__ A2,
    const unsigned short* __restrict__ B0, const unsigned short* __restrict__ B1,
    const unsigned short* __restrict__ B2,
    float* __restrict__ C) {
    __shared__ unsigned short As0[128 * 32], As1[128 * 32], As2[128 * 32];
    __shared__ unsigned short Bs0[128 * 32], Bs1[128 * 32], Bs2[128 * 32];
    int t = threadIdx.x;
    int bid = blockIdx.x;
    int bm = (bid & 15) << 7;
    int bn = (bid >> 4) << 7;
    int lane = t & 63, wv = t >> 6;
    int wm = (wv >> 1) * 64, wn = (wv & 1) * 64;
    int lr = lane & 15, qq = lane >> 4;
    int sw = (qq ^ (lr & 3)) * 8;

    f32x4 acc[4][4] = {};

    for (int k0 = 0; k0 < HIDDEN; k0 += 32) {
        stage_tile(A0, As0, bm, HIDDEN, k0, t);
        stage_tile(A1, As1, bm, HIDDEN, k0, t);
        stage_tile(A2, As2, bm, HIDDEN, k0, t);
        stage_tile(B0, Bs0, bn, HIDDEN, k0, t);
        stage_tile(B1, Bs1, bn, HIDDEN, k0, t);
        stage_tile(B2, Bs2, bn, HIDDEN, k0, t);
        __syncthreads();
        short8 a0[4], a1[4], a2[4];
#pragma unroll
        for (int i = 0; i < 4; ++i) {
            int ra = (wm + i * 16 + lr) * 32 + sw;
            a0[i] = *(const short8*)&As0[ra];
            a1[i] = *(const short8*)&As1[ra];
            a2[i] = *(const short8*)&As2[ra];
        }
#pragma unroll
        for (int j = 0; j < 4; ++j) {
            int rb = (wn + j * 16 + lr) * 32 + sw;
            short8 b0 = *(const short8*)&Bs0[rb];
            short8 b1 = *(const short8*)&Bs1[rb];
            short8 b2 = *(const short8*)&Bs2[rb];
#pragma unroll
            for (int i = 0; i < 4; ++i) {
                acc[i][j] = __builtin_amdgcn_mfma_f32_16x16x32_bf16(a2[i], b0, acc[i][j], 0, 0, 0);
                acc[i][j] = __builtin_amdgcn_mfma_f32_16x16x32_bf16(a0[i], b2, acc[i][j], 0, 0, 0);
                acc[i][j] = __builtin_amdgcn_mfma_f32_16x16x32_bf16(a1[i], b1, acc[i][j], 0, 0, 0);
                acc[i][j] = __builtin_amdgcn_mfma_f32_16x16x32_bf16(a1[i], b0, acc[i][j], 0, 0, 0);
                acc[i][j] = __builtin_amdgcn_mfma_f32_16x16x32_bf16(a0[i], b1, acc[i][j], 0, 0, 0);
                acc[i][j] = __builtin_amdgcn_mfma_f32_16x16x32_bf16(a0[i], b0, acc[i][j], 0, 0, 0);
            }
        }
        __syncthreads();
    }
#pragma unroll
    for (int i = 0; i < 4; ++i)
#pragma unroll
        for (int j = 0; j < 4; ++j)
#pragma unroll
            for (int r = 0; r < 4; ++r) {
                int m = bm + wm + i * 16 + qq * 4 + r;
                int n = bn + wn + j * 16 + lr;
                C[(size_t)m * PNP + n] = acc[i][j][r];
            }
}

// ---------------- combine: h1[c] = relu(P_s[s] + P_e[e] + sum attn*P_a[s+w] + Tw + b1) ----
// r16: float4 loads (all P/tw/b1 offsets 16B-aligned) + ushort4 split stores. Bit-exact.
__global__ void combine_kernel(const float* __restrict__ P, const float* __restrict__ tw,
                               const float* __restrict__ attn_g, const float* __restrict__ b1,
                               const int* __restrict__ starts, const int* __restrict__ ends,
                               unsigned short* __restrict__ h0, unsigned short* __restrict__ h1,
                               unsigned short* __restrict__ h2) {
    int c = blockIdx.x, t = threadIdx.x;
    int s = starts[c], e = ends[c];
    int wid = e - s;
    __shared__ float at[MSW];
    if (t < MSW) at[t] = attn_g[c * 32 + t];
    __syncthreads();
    int n0 = t * 4;
    size_t ho = (size_t)c * NP + n0;
    if (t < 250) {
        f32x4 acc = *(const f32x4*)&P[(size_t)s * PNP + n0];
        acc += *(const f32x4*)&P[(size_t)e * PNP + 1024 + n0];
        acc += *(const f32x4*)&tw[(size_t)wid * NP + n0];
        acc += *(const f32x4*)&b1[n0];
        const float* Pa = P + (size_t)s * PNP + 2048 + n0;
        for (int w = 0; w <= wid; ++w)
            acc += at[w] * *(const f32x4*)&Pa[(size_t)w * PNP];
        u16x4 q0, q1, q2;
#pragma unroll
        for (int k = 0; k < 4; ++k) {
            float v = fmaxf(acc[k], 0.f);
            unsigned short x0 = bf16_rne(v);
            float r1 = v - bf16_to_f(x0);
            unsigned short x1 = bf16_rne(r1);
            float r2 = r1 - bf16_to_f(x1);
            q0[k] = x0; q1[k] = x1; q2[k] = bf16_rne(r2);
        }
        *(u16x4*)&h0[ho] = q0;
        *(u16x4*)&h1[ho] = q1;
        *(u16x4*)&h2[ho] = q2;
    } else {
        u16x4 z = {0, 0, 0, 0};
        *(u16x4*)&h0[ho] = z;
        *(u16x4*)&h1[ho] = z;
        *(u16x4*)&h2[ho] = z;
    }
}

// ---------------- 3-split 6-product MFMA GEMM (score fusion) ------------
__global__ __launch_bounds__(256, 2) void gemm6(
    const unsigned short* __restrict__ A0, const unsigned short* __restrict__ A1,
    const unsigned short* __restrict__ A2,
    const unsigned short* __restrict__ B0, const unsigned short* __restrict__ B1,
    const unsigned short* __restrict__ B2,
    const float* __restrict__ bias, int nreal, int Kp,
    const float* __restrict__ w3, float* __restrict__ partials) {
    __shared__ unsigned short As0[128 * 32], As1[128 * 32], As2[128 * 32];
    __shared__ unsigned short Bs0[128 * 32], Bs1[128 * 32], Bs2[128 * 32];
    int t = threadIdx.x;
    int bid = blockIdx.x;
    int sm = bid >> 6, idx = bid & 63;
    int bm = ((sm << 3) + (idx & 7)) << 7;
    int bn = (idx >> 3) << 7;
    int lane = t & 63, wv = t >> 6;
    int wm = (wv >> 1) * 64, wn = (wv & 1) * 64;
    int lr = lane & 15, qq = lane >> 4;
    int sw = (qq ^ (lr & 3)) * 8;

    f32x4 acc[4][4] = {};

    for (int k0 = 0; k0 < Kp; k0 += 32) {
        stage_tile(A0, As0, bm, Kp, k0, t);
        stage_tile(A1, As1, bm, Kp, k0, t);
        stage_tile(A2, As2, bm, Kp, k0, t);
        stage_tile(B0, Bs0, bn, Kp, k0, t);
        stage_tile(B1, Bs1, bn, Kp, k0, t);
        stage_tile(B2, Bs2, bn, Kp, k0, t);
        __syncthreads();
        short8 a0[4], a1[4], a2[4];
#pragma unroll
        for (int i = 0; i < 4; ++i) {
            int ra = (wm + i * 16 + lr) * 32 + sw;
            a0[i] = *(const short8*)&As0[ra];
            a1[i] = *(const short8*)&As1[ra];
            a2[i] = *(const short8*)&As2[ra];
        }
#pragma unroll
        for (int j = 0; j < 4; ++j) {
            int rb = (wn + j * 16 + lr) * 32 + sw;
            short8 b0 = *(const short8*)&Bs0[rb];
            short8 b1 = *(const short8*)&Bs1[rb];
            short8 b2 = *(const short8*)&Bs2[rb];
#pragma unroll
            for (int i = 0; i < 4; ++i) {
                acc[i][j] = __builtin_amdgcn_mfma_f32_16x16x32_bf16(a2[i], b0, acc[i][j], 0, 0, 0);
                acc[i][j] = __builtin_amdgcn_mfma_f32_16x16x32_bf16(a0[i], b2, acc[i][j], 0, 0, 0);
                acc[i][j] = __builtin_amdgcn_mfma_f32_16x16x32_bf16(a1[i], b1, acc[i][j], 0, 0, 0);
                acc[i][j] = __builtin_amdgcn_mfma_f32_16x16x32_bf16(a1[i], b0, acc[i][j], 0, 0, 0);
                acc[i][j] = __builtin_amdgcn_mfma_f32_16x16x32_bf16(a0[i], b1, acc[i][j], 0, 0, 0);
                acc[i][j] = __builtin_amdgcn_mfma_f32_16x16x32_bf16(a0[i], b0, acc[i][j], 0, 0, 0);
            }
        }
        __syncthreads();
    }

    int pid = ((bn >> 7) << 1) | (wn >> 6);  // 0..15
#pragma unroll
    for (int i = 0; i < 4; ++i)
#pragma unroll
        for (int r = 0; r < 4; ++r) {
            float p = 0.f;
#pragma unroll
            for (int j = 0; j < 4; ++j) {
                int n = bn + wn + j * 16 + lr;
                float v = acc[i][j][r] + (n < nreal ? bias[n] : 0.f);
                v = fmaxf(v, 0.f);
                p += v * (n < nreal ? w3[n] : 0.f);
            }
            p += __shfl_xor(p, 1);
            p += __shfl_xor(p, 2);
            p += __shfl_xor(p, 4);
            p += __shfl_xor(p, 8);
            if (lr == 0) {
                int m = bm + wm + i * 16 + qq * 4 + r;
                partials[(size_t)m * 16 + pid] = p;
            }
        }
}

// ---------------- deterministic score finalize ----------------
__global__ void score_final(const float* __restrict__ partials, const float* __restrict__ b3,
                            const float* __restrict__ width_s, const int* __restrict__ starts,
                            const int* __restrict__ ends, float* __restrict__ out) {
    int c = blockIdx.x * 256 + threadIdx.x;
    if (c >= NUM_CAND) return;
    float s = b3[0] + width_s[ends[c] - starts[c]];
#pragma unroll
    for (int p = 0; p < 16; ++p) s += partials[(size_t)c * 16 + p];
    out[c] = s;
}

// ---------------- exact counting rank-sort: 256 blocks ----------------
__global__ __launch_bounds__(256) void rank_kernel(const float* __restrict__ scores,
                                                   const int* __restrict__ starts,
                                                   const int* __restrict__ ends,
                                                   unsigned short* __restrict__ ord_g,
                                                   unsigned int* __restrict__ se_g) {
    __shared__ unsigned long long kk[NUM_CAND];  // 64 KB
    int t = threadIdx.x;
    for (int i = t; i < NUM_CAND; i += 256) {
        unsigned int b = __float_as_uint(scores[i]);
        unsigned int u = b ^ ((b & 0x80000000u) ? 0xFFFFFFFFu : 0x80000000u);
        unsigned int hi = ~u;
        kk[i] = ((unsigned long long)hi << 32) | (unsigned int)i;
    }
    __syncthreads();
    int c = blockIdx.x * 32 + (t >> 3);
    int seg = (t & 7) * 1024;
    unsigned long long mykey = kk[c];
    int cnt = 0;
    for (int i = seg; i < seg + 1024; ++i) cnt += (kk[i] < mykey) ? 1 : 0;
    cnt += __shfl_xor(cnt, 1);
    cnt += __shfl_xor(cnt, 2);
    cnt += __shfl_xor(cnt, 4);
    if ((t & 7) == 0) {
        int idx = (int)(mykey & 0xFFFFFFFFull);
        int rank = cnt;
        ord_g[rank] = (unsigned short)idx;
        se_g[rank] = ((unsigned int)starts[idx] << 16) | (unsigned int)ends[idx];
    }
}

// ---------------- single-wave batch-accept greedy crossing-NMS ----------------
// r19: r17 structure (single wave, sequential chunks of 64, no sync) but the serial
// one-accept-per-ballot resolve (~819 iterations x ~22 dependent ops) is replaced by a
// wave-parallel fixpoint:
//   1. pblock_l = mask of earlier NON-CROSSED lanes b whose ACCEPTANCE could affect lane l:
//      s_b == s_l (me update; may set OR CLEAR dup) or crossing pattern (monotone reject).
//      Snapshot-crossed lanes are definitively rejected (crossed is monotone) -> never block.
//   2. rounds: lanes with all blockers decided decide NOW (accept iff !crossed && me!=e);
//      then the new accepts' effects (the r13-verified me-max / crossed-OR formulas) are
//      applied to later lanes. Same-round accepts can't block each other (a ready lane has
//      no undecided blocker). Progress: lowest undecided lane is always ready.
//   3. TOP_NUM cap: keep first (TOP_NUM-count) accepts in lane (=rank) order — decisions
//      never depend on count, so truncation == sequential stop. sel_g rank = ib+lane.
// All loops are independent-iteration (readlane broadcast), unlike the old dependent chain.
__global__ __launch_bounds__(64, 1)
void select_nms(const unsigned int* __restrict__ se_g,
                unsigned short* __restrict__ sel_g,
                int* __restrict__ count_g) {
    __shared__ unsigned int se_arr[NUM_CAND];   // 32 KB
    __shared__ unsigned int st[2 * NUM_WORDS];  // 16 KB
    int lane = threadIdx.x;

    {
        const uint4* src4 = (const uint4*)se_g;
        uint4* dst4 = (uint4*)se_arr;
        for (int i = lane; i < NUM_CAND / 4; i += 64) dst4[i] = src4[i];
    }
    for (int i = lane; i < 2 * NUM_WORDS; i += 64)
        st[i] = (i & 1) ? (unsigned int)NUM_WORDS : 0u;  // max_end+1=0, min_start=2048
    __syncthreads();

    const unsigned long long* stp = (const unsigned long long*)st;
    unsigned long long lane_below = (lane == 0) ? 0ull : (~0ull >> (64 - lane));
    int count = 0;
    for (int c = 0; c < NUM_CAND / 64; ++c) {
        int ib = c * 64;
        unsigned int sev = se_arr[ib + lane];
        int s = (int)(sev >> 16), e = (int)(sev & 0xFFFFu);
        // ---- snapshot + base predicate (identical to the r17-verified form) ----
        const unsigned long long* bp = stp + s;
        unsigned long long v[MSW];
#pragma unroll
        for (int w = 0; w < MSW; ++w) v[w] = bp[w];
        int me = (int)(unsigned int)v[0] - 1;
        bool crossedA = (s < e) && ((int)(unsigned int)(v[0] >> 32) < s);
        bool crossedB = false;
#pragma unroll
        for (int w = 1; w < MSW; ++w) {
            int j = s + w;
            bool in = (j <= e);
            int mej = (int)(unsigned int)v[w] - 1;
            int msj = (int)(unsigned int)(v[w] >> 32);
            bool hit = in && ((mej > e) || ((j < e) && (msj < s)));
            if (w & 1) crossedA = crossedA || hit;
            else       crossedB = crossedB || hit;
        }
        bool crossed = crossedA || crossedB;
        bool undec = !crossed;  // snapshot-crossed lanes are definitively rejected

        // ---- build potential-blocker mask over earlier undecided lanes ----
        unsigned long long undec_mask = __ballot(undec);
        unsigned long long pb = 0ull;
        unsigned long long mm = undec_mask & lane_below;
        while (mm) {
            int b = __ffsll((unsigned long long)mm) - 1;
            mm &= mm - 1;
            unsigned int sef = __builtin_amdgcn_readlane(sev, (unsigned int)b);
            int sf = (int)(sef >> 16), ef = (int)(sef & 0xFFFFu);
            bool rel = (sf == s)
                    || ((s < sf) && (sf <= e) && (ef > e))
                    || ((sf < s) && (s <= ef) && (ef < e));
            if (rel) pb |= (1ull << b);
        }

        // ---- fixpoint rounds ----
        unsigned long long undecided = undec_mask;
        unsigned long long accm = 0ull;
        while (undecided) {
            bool ready = undec && ((pb & undecided) == 0ull);
            unsigned long long dec = __ballot(ready);
            bool spec = !crossed && (me != e);
            unsigned long long newacc = __ballot(ready && spec);
            // apply effects of this round's accepts to later lanes (r13-verified formulas)
            unsigned long long m2 = newacc;
            while (m2) {
                int b = __ffsll((unsigned long long)m2) - 1;
                m2 &= m2 - 1;
                unsigned int sef = __builtin_amdgcn_readlane(sev, (unsigned int)b);
                int sf = (int)(sef >> 16), ef = (int)(sef & 0xFFFFu);
                if (lane > b) {
                    if (s == sf) me = max(me, ef);
                    crossed = crossed || ((s < sf) && (sf <= e) && (ef > e))
                                      || ((sf < s) && (s <= ef) && (ef < e));
                }
            }
            undec = undec && !ready;
            undecided &= ~dec;
            accm |= newacc;
        }

        // ---- cap + rank-order emit ----
        int navail = TOP_NUM - count;           // > 0 (we break at >=)
        int nacc = __popcll(accm);
        int ntake = (nacc < navail) ? nacc : navail;
        bool acc_l = ((accm >> lane) & 1ull) != 0ull;
        int myord = __popcll(accm & lane_below);
        if (acc_l && myord < ntake) {
            sel_g[count + myord] = (unsigned short)(ib + lane);
            atomicMax(&st[2 * s], (unsigned int)(e + 1));
            atomicMin(&st[2 * e + 1], (unsigned int)s);
        }
        count += ntake;
        if (count >= TOP_NUM) break;
    }
    if (lane == 0) *count_g = count;
}

// ---------------- post: final span-order sort + emit ----------------
__global__ __launch_bounds__(256) void select_post(const float* __restrict__ scores,
                                                   const int* __restrict__ starts,
                                                   const int* __restrict__ ends,
                                                   const unsigned short* __restrict__ ord_g,
                                                   const unsigned short* __restrict__ sel_g,
                                                   const int* __restrict__ count_g,
                                                   float* out, int* top_idx_ws) {
    __shared__ unsigned long long fkeys[1024];
    int t = threadIdx.x;
    int count = *count_g;
    for (int i = t; i < 1024; i += 256) {
        unsigned long long k = 0xFFFFFFFFFFFFFFFFull;
        if (i < count) {
            int idx = (int)ord_g[sel_g[i]];
            unsigned int key32 = (unsigned int)(starts[idx] * NUM_WORDS + ends[idx]);
            k = ((unsigned long long)key32 << 32) | (unsigned int)idx;
        }
        fkeys[i] = k;
    }
    __syncthreads();
    for (int size = 2; size <= 1024; size <<= 1) {
        for (int stride = size >> 1; stride > 0; stride >>= 1) {
            for (int i = t; i < 1024; i += 256) {
                int ixj = i ^ stride;
                if (ixj > i) {
                    bool up = ((i & size) == 0);
                    unsigned long long a = fkeys[i], b = fkeys[ixj];
                    if ((a > b) == up) { fkeys[i] = b; fkeys[ixj] = a; }
                }
            }
            __syncthreads();
        }
    }
    for (int i = t; i < TOP_NUM; i += 256) {
        int fi = (i < count) ? (int)(fkeys[i] & 0xFFFFFFFFull)
                             : (int)(fkeys[0] & 0xFFFFFFFFull);
        out[OUT_TOPIDX + i] = (float)fi;
        out[OUT_TSTART + i] = (float)starts[fi];
        out[OUT_TEND + i] = (float)ends[fi];
        out[OUT_TSCORE + i] = scores[fi];
        top_idx_ws[i] = fi;
    }
}

// ---------------- gather top_span_emb rows directly from doc (exact fp32) ----------------
__global__ void gather_emb(const float* __restrict__ doc, const float* __restrict__ swe,
                           const float* __restrict__ attn_g, const int* __restrict__ starts,
                           const int* __restrict__ ends, const int* __restrict__ top_idx_ws,
                           float* __restrict__ out) {
    int r = blockIdx.x, t = threadIdx.x;
    int idx = top_idx_ws[r];
    int s = starts[idx], e = ends[idx];
    int wid = e - s;
    __shared__ float at[MSW];
    if (t < MSW) at[t] = attn_g[(size_t)idx * 32 + t];
    __syncthreads();
    float* dst = out + OUT_TEMB + (size_t)r * SPAN_DIM;
    if (t < 192) {
        int h4 = t * 4;
        f32x4 vs = *(const f32x4*)&doc[(size_t)s * HIDDEN + h4];
        f32x4 ve = *(const f32x4*)&doc[(size_t)e * HIDDEN + h4];
        f32x4 acc = {0.f, 0.f, 0.f, 0.f};
        for (int w = 0; w <= wid; ++w)
            acc += at[w] * *(const f32x4*)&doc[(size_t)(s + w) * HIDDEN + h4];
#pragma unroll
        for (int k = 0; k < 4; ++k) {
            dst[h4 + k] = vs[k];
            dst[HIDDEN + h4 + k] = ve[k];
            dst[2 * HIDDEN + FEAT + h4 + k] = acc[k];
        }
    }
    if (t < FEAT) dst[2 * HIDDEN + t] = swe[wid * FEAT + t];
}

extern "C" void kernel_launch(void* const* d_in, const int* in_sizes, int n_in,
                              void* d_out, int out_size, void* d_ws, size_t ws_size,
                              hipStream_t stream) {
    const float* mention_doc = (const float*)d_in[0];
    const float* span_width_emb = (const float*)d_in[1];
    const float* head_w = (const float*)d_in[2];
    const float* head_b = (const float*)d_in[3];
    const float* m_w1 = (const float*)d_in[4];
    const float* m_b1 = (const float*)d_in[5];
    const float* m_w2 = (const float*)d_in[6];
    const float* m_b2 = (const float*)d_in[7];
    const float* m_w3 = (const float*)d_in[8];
    const float* m_b3 = (const float*)d_in[9];
    const float* width_prior_emb = (const float*)d_in[10];
    const float* w_w1 = (const float*)d_in[11];
    const float* w_b1 = (const float*)d_in[12];
    const float* w_w2 = (const float*)d_in[13];
    const float* w_b2 = (const float*)d_in[14];
    const float* w_w3 = (const float*)d_in[15];
    const float* w_b3 = (const float*)d_in[16];
    const int* cand_starts = (const int*)d_in[17];
    const int* cand_ends = (const int*)d_in[18];

    char* w = (char*)d_ws;
    const size_t szH = (size_t)NUM_CAND * NP * 2;
    const size_t szW2 = (size_t)NP * KP2 * 2;
    const size_t szWc = (size_t)PNP * HIDDEN * 2;
    const size_t szD = (size_t)NUM_WORDS * HIDDEN * 2;
    char* p = w;
    unsigned short* h0 = (unsigned short*)p; p += szH;
    unsigned short* h1 = (unsigned short*)p; p += szH;
    unsigned short* h2 = (unsigned short*)p; p += szH;
    unsigned short* w2t0 = (unsigned short*)p; p += szW2;
    unsigned short* w2t1 = (unsigned short*)p; p += szW2;
    unsigned short* w2t2 = (unsigned short*)p; p += szW2;
    unsigned short* Wc0 = (unsigned short*)p; p += szWc;
    unsigned short* Wc1 = (unsigned short*)p; p += szWc;
    unsigned short* Wc2 = (unsigned short*)p; p += szWc;
    unsigned short* d0 = (unsigned short*)p; p += szD;
    unsigned short* d1 = (unsigned short*)p; p += szD;
    unsigned short* d2 = (unsigned short*)p; p += szD;
    float* P = (float*)p; p += (size_t)NUM_WORDS * PNP * 4;
    float* tw = (float*)p; p += (size_t)MSW * NP * 4;
    float* attn_g = (float*)p; p += (size_t)NUM_CAND * 32 * 4;
    float* partials = (float*)p; p += (size_t)NUM_CAND * 16 * 4;
    unsigned short* ord_g = (unsigned short*)p; p += (size_t)NUM_CAND * 2;
    unsigned int* se_g = (unsigned int*)p; p += (size_t)NUM_CAND * 4;
    unsigned short* sel_g = (unsigned short*)p; p += 2048;
    int* count_g = (int*)p; p += 128;
    float* head_s = (float*)p; p += NUM_WORDS * 4;
    float* width_s = (float*)p; p += 128;
    int* top_idx_ws = (int*)p; p += 4096;

    size_t need = (size_t)(p - w);
    if (ws_size < need) {
        fprintf(stderr, "kernel_launch: ws too small (%zu < %zu)\n", ws_size, need);
    }

    float* out = (float*)d_out;

    head_kernel<<<NUM_WORDS / 4, 256, 0, stream>>>(mention_doc, head_w, head_b, head_s);
    width_kernel<<<MSW, 256, 0, stream>>>(width_prior_emb, w_w1, w_b1, w_w2, w_b2, w_w3, w_b3,
                                          width_s);
    attn_kernel<<<NUM_CAND / 4, 256, 0, stream>>>(head_s, cand_starts, cand_ends, attn_g);
    doc_convert<<<(NUM_WORDS * HIDDEN + 255) / 256, 256, 0, stream>>>(mention_doc, d0, d1, d2);
    convert_wc<<<dim3(3, 3072), 256, 0, stream>>>(m_w1, Wc0, Wc1, Wc2);
    convert_wt<<<dim3(4, 1024), 256, 0, stream>>>(m_w2, FFNN_DIM, FFNN_DIM, KP2,
                                                  w2t0, w2t1, w2t2);
    tw_kernel<<<MSW, 256, 0, stream>>>(span_width_emb, m_w1, tw);
    gemm6p<<<16 * 24, 256, 0, stream>>>(d0, d1, d2, Wc0, Wc1, Wc2, P);
    combine_kernel<<<NUM_CAND, 256, 0, stream>>>(P, tw, attn_g, m_b1, cand_starts, cand_ends,
                                                 h0, h1, h2);
    gemm6<<<512, 256, 0, stream>>>(h0, h1, h2, w2t0, w2t1, w2t2, m_b2, FFNN_DIM, KP2,
                                   m_w3, partials);
    score_final<<<NUM_CAND / 256, 256, 0, stream>>>(partials, m_b3, width_s, cand_starts,
                                                    cand_ends, out);
    rank_kernel<<<NUM_CAND / 32, 256, 0, stream>>>(out, cand_starts, cand_ends, ord_g, se_g);
    select_nms<<<1, 64, 0, stream>>>(se_g, sel_g, count_g);
    select_post<<<1, 256, 0, stream>>>(out, cand_starts, cand_ends, ord_g, sel_g, count_g,
                                       out, top_idx_ws);
    gather_emb<<<TOP_NUM, 256, 0, stream>>>(mention_doc, span_width_emb, attn_g, cand_starts,
                                            cand_ends, top_idx_ws, out);
}

// Round 6
// 902.291 us; speedup vs baseline: 1.0471x; 1.0197x over previous
//
#include <hip/hip_runtime.h>
#include <cstdio>
#include <cmath>

#define NUM_WORDS 2048
#define NUM_CAND 8192
#define HIDDEN 768
#define FEAT 20
#define FFNN_DIM 1000
#define SPAN_DIM 2324
#define TOP_NUM 819
#define MSW 30
#define KP2 1024   // FFNN padded to x32
#define NP 1024    // padded N
#define PNP 3072   // P matrix padded N (3 segments of 1024)

// d_out layout (floats): [scores 8192][top_idx 819][top_starts 819][top_ends 819]
//                        [top_span_emb 819*2324][top_scores 819]
#define OUT_TOPIDX   (NUM_CAND)
#define OUT_TSTART   (NUM_CAND + TOP_NUM)
#define OUT_TEND     (NUM_CAND + 2*TOP_NUM)
#define OUT_TEMB     (NUM_CAND + 3*TOP_NUM)
#define OUT_TSCORE   (NUM_CAND + 3*TOP_NUM + TOP_NUM*SPAN_DIM)

typedef short short8 __attribute__((ext_vector_type(8)));
typedef float f32x4 __attribute__((ext_vector_type(4)));
typedef unsigned short u16x4 __attribute__((ext_vector_type(4)));

__device__ __forceinline__ unsigned short bf16_rne(float x) {
    unsigned int u = __float_as_uint(x);
    unsigned int r = u + 0x7FFFu + ((u >> 16) & 1u);
    return (unsigned short)(r >> 16);
}
__device__ __forceinline__ float bf16_to_f(unsigned short h) {
    return __uint_as_float(((unsigned int)h) << 16);
}
// 3-way split: v = s0 + s1 + s2 + r, |r| <= 2^-27 |v|
__device__ __forceinline__ void store_split3(unsigned short* p0, unsigned short* p1,
                                             unsigned short* p2, size_t off, float v) {
    unsigned short h0 = bf16_rne(v);
    float r1 = v - bf16_to_f(h0);
    unsigned short h1 = bf16_rne(r1);
    float r2 = r1 - bf16_to_f(h1);
    p0[off] = h0;
    p1[off] = h1;
    p2[off] = bf16_rne(r2);
}

// async 16B global->LDS (gfx950 global_load_lds_dwordx4). LDS dest must be
// wave-uniform base + lane*16 -> staging tiles are UNPADDED (128x32 bf16, 64B rows),
// bank conflicts handled by XOR swizzle: kblk stored at kblk^(row&3).
__device__ __forceinline__ void gl_lds16(const unsigned short* g, unsigned short* l) {
    __builtin_amdgcn_global_load_lds(
        (const __attribute__((address_space(1))) unsigned short*)g,
        (__attribute__((address_space(3))) unsigned short*)l, 16, 0, 0);
}

// ---------------- head scores: doc @ head_w + head_b  -> [2048] ----------------
__global__ void head_kernel(const float* __restrict__ doc, const float* __restrict__ hw,
                            const float* __restrict__ hb, float* __restrict__ out) {
    int wave = threadIdx.x >> 6, lane = threadIdx.x & 63;
    int row = blockIdx.x * 4 + wave;
    if (row >= NUM_WORDS) return;
    float acc = 0.f;
    for (int h = lane; h < HIDDEN; h += 64) acc += doc[row * HIDDEN + h] * hw[h];
    for (int off = 32; off > 0; off >>= 1) acc += __shfl_down(acc, off);
    if (lane == 0) out[row] = acc + hb[0];
}

// ---------------- width prior ffnn: [30,20] -> [30] ----------------
__global__ void width_kernel(const float* __restrict__ x, const float* __restrict__ w1,
                             const float* __restrict__ b1, const float* __restrict__ w2,
                             const float* __restrict__ b2, const float* __restrict__ w3,
                             const float* __restrict__ b3, float* __restrict__ out) {
    __shared__ float xs[FEAT];
    __shared__ float h1s[FFNN_DIM];
    __shared__ float red[256];
    int r = blockIdx.x, t = threadIdx.x;
    if (t < FEAT) xs[t] = x[r * FEAT + t];
    __syncthreads();
    for (int j = t; j < FFNN_DIM; j += 256) {
        float acc = b1[j];
        for (int k = 0; k < FEAT; ++k) acc += xs[k] * w1[k * FFNN_DIM + j];
        h1s[j] = fmaxf(acc, 0.f);
    }
    __syncthreads();
    float partial = 0.f;
    for (int j = t; j < FFNN_DIM; j += 256) {
        float acc = b2[j];
        for (int k = 0; k < FFNN_DIM; ++k) acc += h1s[k] * w2[k * FFNN_DIM + j];
        partial += fmaxf(acc, 0.f) * w3[j];
    }
    red[t] = partial;
    __syncthreads();
    for (int s = 128; s > 0; s >>= 1) { if (t < s) red[t] += red[t + s]; __syncthreads(); }
    if (t == 0) out[r] = red[0] + b3[0];
}

// ---------------- attention weights per span: attn_g [8192][32] ----------------
__global__ void attn_kernel(const float* __restrict__ head_s, const int* __restrict__ starts,
                            const int* __restrict__ ends, float* __restrict__ attn_g) {
    int wave = threadIdx.x >> 6, w = threadIdx.x & 63;
    int c = blockIdx.x * 4 + wave;
    if (c >= NUM_CAND) return;
    int s = starts[c], e = ends[c];
    int wid = e - s;
    float hsv = -INFINITY;
    if (w < MSW && w <= wid) hsv = head_s[s + w];
    float m = hsv;
    for (int off = 32; off > 0; off >>= 1) m = fmaxf(m, __shfl_down(m, off));
    m = __shfl(m, 0);
    float ex = (w < MSW && w <= wid) ? expf(hsv - m) : 0.f;
    float ssum = ex;
    for (int off = 32; off > 0; off >>= 1) ssum += __shfl_down(ssum, off);
    ssum = __shfl(ssum, 0);
    if (w < 32) attn_g[c * 32 + w] = (w < MSW) ? (ex / ssum) : 0.f;
}

// ---------------- doc fp32 -> 3-split bf16 [2048*768] ----------------
__global__ void doc_convert(const float* __restrict__ doc, unsigned short* __restrict__ d0,
                            unsigned short* __restrict__ d1, unsigned short* __restrict__ d2) {
    int i = blockIdx.x * 256 + threadIdx.x;
    if (i < NUM_WORDS * HIDDEN) store_split3(d0, d1, d2, i, doc[i]);
}

// ---------------- weight convert+transpose: w[K][N] -> 3-split [gridDim.y][Kp] ------------
__global__ void convert_wt(const float* __restrict__ w, int K, int N, int Kp,
                           unsigned short* __restrict__ q0, unsigned short* __restrict__ q1,
                           unsigned short* __restrict__ q2) {
    int n = blockIdx.y;
    int k = blockIdx.x * blockDim.x + threadIdx.x;
    if (k >= Kp) return;
    float v = (k < K && n < N) ? w[(size_t)k * N + n] : 0.f;
    store_split3(q0, q1, q2, (size_t)n * Kp + k, v);
}

// ---------------- fused Wc convert: 3 segments of m_w1 -> 3-split [3072][768] ------------
// r18: replaces three convert_wt launches (bit-identical arithmetic). seg row bases:
// 0 -> rows 0..767 (start), 1 -> rows 768..1535 (end), 2 -> rows 1556..2323 (attended).
__global__ void convert_wc(const float* __restrict__ w1,
                           unsigned short* __restrict__ q0, unsigned short* __restrict__ q1,
                           unsigned short* __restrict__ q2) {
    int n2 = blockIdx.y;                    // 0..3071 output row
    int seg = n2 >> 10;
    int n = n2 & 1023;                      // col within segment
    int k = blockIdx.x * 256 + threadIdx.x; // 0..767
    int row0 = (seg == 0) ? 0 : ((seg == 1) ? HIDDEN : 1556);
    float v = (n < FFNN_DIM) ? w1[(size_t)(row0 + k) * FFNN_DIM + n] : 0.f;
    store_split3(q0, q1, q2, (size_t)n2 * HIDDEN + k, v);
}

// ---------------- T_w[wid][1024] = span_width_emb[wid] @ m_w1[1536:1556] ----------------
__global__ void tw_kernel(const float* __restrict__ swe, const float* __restrict__ w1,
                          float* __restrict__ tw) {
    int wid = blockIdx.x, t = threadIdx.x;
    for (int n = t; n < NP; n += 256) {
        float acc = 0.f;
        if (n < FFNN_DIM) {
            for (int f = 0; f < FEAT; ++f)
                acc += swe[wid * FEAT + f] * w1[(size_t)(1536 + f) * FFNN_DIM + n];
        }
        tw[wid * NP + n] = acc;
    }
}

// Stage one 128x32-bf16 tile (8KB) async into LDS with XOR swizzle.
__device__ __forceinline__ void stage_tile(const unsigned short* __restrict__ src,
                                           unsigned short* lds, int base_row, int Kp, int k0,
                                           int t) {
#pragma unroll
    for (int qi = 0; qi < 2; ++qi) {
        int u = qi * 256 + t;
        int l = u & 63;
        int row = ((u >> 6) << 4) + (l >> 2);
        int cblk = (l & 3) ^ (row & 3);
        const unsigned short* g = src + (size_t)(base_row + row) * Kp + k0 + cblk * 8;
        gl_lds16(g, lds + u * 8);
    }
}

// ---------------- 3-split 6-product MFMA GEMM, fp32 out: P = doc @ [W_s|W_e|W_a] ---------
__global__ __launch_bounds__(256, 2) void gemm6p(
    const unsigned short* __restrict__ A0, const unsigned short* __restrict__ A1,
    const unsigned short* __restrict__ A2,
    const unsigned short* __restrict__ B0, const unsigned short* __restrict__ B1,
    const unsigned short* __restrict__ B2,
    float* __restrict__ C) {
    __shared__ unsigned short As0[128 * 32], As1[128 * 32], As2[128 * 32];
    __shared__ unsigned short Bs0[128 * 32], Bs1[128 * 32], Bs2[128 * 32];
    int t = threadIdx.x;
    int bid = blockIdx.x;
    int bm = (bid & 15) << 7;
    int bn = (bid >> 4) << 7;
    int lane = t & 63, wv = t >> 6;
    int wm = (wv >> 1) * 64, wn = (wv & 1) * 64;
    int lr = lane & 15, qq = lane >> 4;
    int sw = (qq ^ (lr & 3)) * 8;

    f32x4 acc[4][4] = {};

    for (int k0 = 0; k0 < HIDDEN; k0 += 32) {
        stage_tile(A0, As0, bm, HIDDEN, k0, t);
        stage_tile(A1, As1, bm, HIDDEN, k0, t);
        stage_tile(A2, As2, bm, HIDDEN, k0, t);
        stage_tile(B0, Bs0, bn, HIDDEN, k0, t);
        stage_tile(B1, Bs1, bn, HIDDEN, k0, t);
        stage_tile(B2, Bs2, bn, HIDDEN, k0, t);
        __syncthreads();
        short8 a0[4], a1[4], a2[4];
#pragma unroll
        for (int i = 0; i < 4; ++i) {
            int ra = (wm + i * 16 + lr) * 32 + sw;
            a0[i] = *(const short8*)&As0[ra];
            a1[i] = *(const short8*)&As1[ra];
            a2[i] = *(const short8*)&As2[ra];
        }
#pragma unroll
        for (int j = 0; j < 4; ++j) {
            int rb = (wn + j * 16 + lr) * 32 + sw;
            short8 b0 = *(const short8*)&Bs0[rb];
            short8 b1 = *(const short8*)&Bs1[rb];
            short8 b2 = *(const short8*)&Bs2[rb];
#pragma unroll
            for (int i = 0; i < 4; ++i) {
                acc[i][j] = __builtin_amdgcn_mfma_f32_16x16x32_bf16(a2[i], b0, acc[i][j], 0, 0, 0);
                acc[i][j] = __builtin_amdgcn_mfma_f32_16x16x32_bf16(a0[i], b2, acc[i][j], 0, 0, 0);
                acc[i][j] = __builtin_amdgcn_mfma_f32_16x16x32_bf16(a1[i], b1, acc[i][j], 0, 0, 0);
                acc[i][j] = __builtin_amdgcn_mfma_f32_16x16x32_bf16(a1[i], b0, acc[i][j], 0, 0, 0);
                acc[i][j] = __builtin_amdgcn_mfma_f32_16x16x32_bf16(a0[i], b1, acc[i][j], 0, 0, 0);
                acc[i][j] = __builtin_amdgcn_mfma_f32_16x16x32_bf16(a0[i], b0, acc[i][j], 0, 0, 0);
            }
        }
        __syncthreads();
    }
#pragma unroll
    for (int i = 0; i < 4; ++i)
#pragma unroll
        for (int j = 0; j < 4; ++j)
#pragma unroll
            for (int r = 0; r < 4; ++r) {
                int m = bm + wm + i * 16 + qq * 4 + r;
                int n = bn + wn + j * 16 + lr;
                C[(size_t)m * PNP + n] = acc[i][j][r];
            }
}

// ---------------- combine: h1[c] = relu(P_s[s] + P_e[e] + sum attn*P_a[s+w] + Tw + b1) ----
// r16: float4 loads (all P/tw/b1 offsets 16B-aligned) + ushort4 split stores. Bit-exact.
__global__ void combine_kernel(const float* __restrict__ P, const float* __restrict__ tw,
                               const float* __restrict__ attn_g, const float* __restrict__ b1,
                               const int* __restrict__ starts, const int* __restrict__ ends,
                               unsigned short* __restrict__ h0, unsigned short* __restrict__ h1,
                               unsigned short* __restrict__ h2) {
    int c = blockIdx.x, t = threadIdx.x;
    int s = starts[c], e = ends[c];
    int wid = e - s;
    __shared__ float at[MSW];
    if (t < MSW) at[t] = attn_g[c * 32 + t];
    __syncthreads();
    int n0 = t * 4;
    size_t ho = (size_t)c * NP + n0;
    if (t < 250) {
        f32x4 acc = *(const f32x4*)&P[(size_t)s * PNP + n0];
        acc += *(const f32x4*)&P[(size_t)e * PNP + 1024 + n0];
        acc += *(const f32x4*)&tw[(size_t)wid * NP + n0];
        acc += *(const f32x4*)&b1[n0];
        const float* Pa = P + (size_t)s * PNP + 2048 + n0;
        for (int w = 0; w <= wid; ++w)
            acc += at[w] * *(const f32x4*)&Pa[(size_t)w * PNP];
        u16x4 q0, q1, q2;
#pragma unroll
        for (int k = 0; k < 4; ++k) {
            float v = fmaxf(acc[k], 0.f);
            unsigned short x0 = bf16_rne(v);
            float r1 = v - bf16_to_f(x0);
            unsigned short x1 = bf16_rne(r1);
            float r2 = r1 - bf16_to_f(x1);
            q0[k] = x0; q1[k] = x1; q2[k] = bf16_rne(r2);
        }
        *(u16x4*)&h0[ho] = q0;
        *(u16x4*)&h1[ho] = q1;
        *(u16x4*)&h2[ho] = q2;
    } else {
        u16x4 z = {0, 0, 0, 0};
        *(u16x4*)&h0[ho] = z;
        *(u16x4*)&h1[ho] = z;
        *(u16x4*)&h2[ho] = z;
    }
}

// ---------------- 3-split 6-product MFMA GEMM (score fusion) ------------
__global__ __launch_bounds__(256, 2) void gemm6(
    const unsigned short* __restrict__ A0, const unsigned short* __restrict__ A1,
    const unsigned short* __restrict__ A2,
    const unsigned short* __restrict__ B0, const unsigned short* __restrict__ B1,
    const unsigned short* __restrict__ B2,
    const float* __restrict__ bias, int nreal, int Kp,
    const float* __restrict__ w3, float* __restrict__ partials) {
    __shared__ unsigned short As0[128 * 32], As1[128 * 32], As2[128 * 32];
    __shared__ unsigned short Bs0[128 * 32], Bs1[128 * 32], Bs2[128 * 32];
    int t = threadIdx.x;
    int bid = blockIdx.x;
    int sm = bid >> 6, idx = bid & 63;
    int bm = ((sm << 3) + (idx & 7)) << 7;
    int bn = (idx >> 3) << 7;
    int lane = t & 63, wv = t >> 6;
    int wm = (wv >> 1) * 64, wn = (wv & 1) * 64;
    int lr = lane & 15, qq = lane >> 4;
    int sw = (qq ^ (lr & 3)) * 8;

    f32x4 acc[4][4] = {};

    for (int k0 = 0; k0 < Kp; k0 += 32) {
        stage_tile(A0, As0, bm, Kp, k0, t);
        stage_tile(A1, As1, bm, Kp, k0, t);
        stage_tile(A2, As2, bm, Kp, k0, t);
        stage_tile(B0, Bs0, bn, Kp, k0, t);
        stage_tile(B1, Bs1, bn, Kp, k0, t);
        stage_tile(B2, Bs2, bn, Kp, k0, t);
        __syncthreads();
        short8 a0[4], a1[4], a2[4];
#pragma unroll
        for (int i = 0; i < 4; ++i) {
            int ra = (wm + i * 16 + lr) * 32 + sw;
            a0[i] = *(const short8*)&As0[ra];
            a1[i] = *(const short8*)&As1[ra];
            a2[i] = *(const short8*)&As2[ra];
        }
#pragma unroll
        for (int j = 0; j < 4; ++j) {
            int rb = (wn + j * 16 + lr) * 32 + sw;
            short8 b0 = *(const short8*)&Bs0[rb];
            short8 b1 = *(const short8*)&Bs1[rb];
            short8 b2 = *(const short8*)&Bs2[rb];
#pragma unroll
            for (int i = 0; i < 4; ++i) {
                acc[i][j] = __builtin_amdgcn_mfma_f32_16x16x32_bf16(a2[i], b0, acc[i][j], 0, 0, 0);
                acc[i][j] = __builtin_amdgcn_mfma_f32_16x16x32_bf16(a0[i], b2, acc[i][j], 0, 0, 0);
                acc[i][j] = __builtin_amdgcn_mfma_f32_16x16x32_bf16(a1[i], b1, acc[i][j], 0, 0, 0);
                acc[i][j] = __builtin_amdgcn_mfma_f32_16x16x32_bf16(a1[i], b0, acc[i][j], 0, 0, 0);
                acc[i][j] = __builtin_amdgcn_mfma_f32_16x16x32_bf16(a0[i], b1, acc[i][j], 0, 0, 0);
                acc[i][j] = __builtin_amdgcn_mfma_f32_16x16x32_bf16(a0[i], b0, acc[i][j], 0, 0, 0);
            }
        }
        __syncthreads();
    }

    int pid = ((bn >> 7) << 1) | (wn >> 6);  // 0..15
#pragma unroll
    for (int i = 0; i < 4; ++i)
#pragma unroll
        for (int r = 0; r < 4; ++r) {
            float p = 0.f;
#pragma unroll
            for (int j = 0; j < 4; ++j) {
                int n = bn + wn + j * 16 + lr;
                float v = acc[i][j][r] + (n < nreal ? bias[n] : 0.f);
                v = fmaxf(v, 0.f);
                p += v * (n < nreal ? w3[n] : 0.f);
            }
            p += __shfl_xor(p, 1);
            p += __shfl_xor(p, 2);
            p += __shfl_xor(p, 4);
            p += __shfl_xor(p, 8);
            if (lr == 0) {
                int m = bm + wm + i * 16 + qq * 4 + r;
                partials[(size_t)m * 16 + pid] = p;
            }
        }
}

// ---------------- deterministic score finalize (+ zero the NMS done-flag) ----------------
__global__ void score_final(const float* __restrict__ partials, const float* __restrict__ b3,
                            const float* __restrict__ width_s, const int* __restrict__ starts,
                            const int* __restrict__ ends, float* __restrict__ out,
                            int* __restrict__ done_flag) {
    int c = blockIdx.x * 256 + threadIdx.x;
    if (c == 0) *done_flag = 0;  // reset before select_nms (stream-ordered)
    if (c >= NUM_CAND) return;
    float s = b3[0] + width_s[ends[c] - starts[c]];
#pragma unroll
    for (int p = 0; p < 16; ++p) s += partials[(size_t)c * 16 + p];
    out[c] = s;
}

// ---------------- exact counting rank-sort: 256 blocks ----------------
__global__ __launch_bounds__(256) void rank_kernel(const float* __restrict__ scores,
                                                   const int* __restrict__ starts,
                                                   const int* __restrict__ ends,
                                                   unsigned short* __restrict__ ord_g,
                                                   unsigned int* __restrict__ se_g) {
    __shared__ unsigned long long kk[NUM_CAND];  // 64 KB
    int t = threadIdx.x;
    for (int i = t; i < NUM_CAND; i += 256) {
        unsigned int b = __float_as_uint(scores[i]);
        unsigned int u = b ^ ((b & 0x80000000u) ? 0xFFFFFFFFu : 0x80000000u);
        unsigned int hi = ~u;
        kk[i] = ((unsigned long long)hi << 32) | (unsigned int)i;
    }
    __syncthreads();
    int c = blockIdx.x * 32 + (t >> 3);
    int seg = (t & 7) * 1024;
    unsigned long long mykey = kk[c];
    int cnt = 0;
    for (int i = seg; i < seg + 1024; ++i) cnt += (kk[i] < mykey) ? 1 : 0;
    cnt += __shfl_xor(cnt, 1);
    cnt += __shfl_xor(cnt, 2);
    cnt += __shfl_xor(cnt, 4);
    if ((t & 7) == 0) {
        int idx = (int)(mykey & 0xFFFFFFFFull);
        int rank = cnt;
        ord_g[rank] = (unsigned short)idx;
        se_g[rank] = ((unsigned int)starts[idx] << 16) | (unsigned int)ends[idx];
    }
}

// ---------------- single-wave greedy crossing-NMS + clock-hold spinners ----------------
// r20: decision path reverted byte-for-byte to the r17-verified 292us form (r18/r19
// redesigns both regressed: dur tracks total instruction count, latency-hiding buys
// nothing). Static cycle count (~85K) vs 292us wall implies ~300MHz effective rate —
// DVFS candidate: 255/256 CUs idle during this dispatch. Embedded A/B: blocks 1..256 run
// a dependent-FMA spin (1 wave on each other CU) to hold the clock up, exiting when
// block 0 release-stores done_flag (agent-scope, coherent across XCDs; 4096-iter hard cap
// bounds any visibility failure to ~1.5ms). Spinners write nothing; NMS block unchanged.
// If DVFS theory holds: ~110-160us. If structural-stall theory: ~292us (spin is free).
__global__ __launch_bounds__(64, 1)
void select_nms(const unsigned int* __restrict__ se_g,
                unsigned short* __restrict__ sel_g,
                int* __restrict__ count_g,
                int* __restrict__ done_flag) {
    if (blockIdx.x != 0) {
        float a = 1.0f + (float)threadIdx.x * 0.001f;
        const float b = 1.0000001f, cc = 0.0000001f;
        for (int it = 0; it < 4096; ++it) {
#pragma unroll
            for (int u = 0; u < 64; ++u) a = __builtin_fmaf(a, b, cc);
            if (__hip_atomic_load(done_flag, __ATOMIC_RELAXED,
                                  __HIP_MEMORY_SCOPE_AGENT) != 0)
                break;
        }
        asm volatile("" :: "v"(a));  // keep the FMA chain live (no DCE)
        return;
    }

    __shared__ unsigned int se_arr[NUM_CAND];   // 32 KB
    __shared__ unsigned int st[2 * NUM_WORDS];  // 16 KB
    int lane = threadIdx.x;

    {
        const uint4* src4 = (const uint4*)se_g;
        uint4* dst4 = (uint4*)se_arr;
        for (int i = lane; i < NUM_CAND / 4; i += 64) dst4[i] = src4[i];
    }
    for (int i = lane; i < 2 * NUM_WORDS; i += 64)
        st[i] = (i & 1) ? (unsigned int)NUM_WORDS : 0u;  // max_end+1=0, min_start=2048
    __syncthreads();

    const unsigned long long* stp = (const unsigned long long*)st;
    int count = 0;
    for (int c = 0; c < NUM_CAND / 64; ++c) {
        int ib = c * 64;
        unsigned int sev = se_arr[ib + lane];
        int s = (int)(sev >> 16), e = (int)(sev & 0xFFFFu);
        // snapshot: by program order this wave's own st atomics from all previous chunks
        // are visible (per-wave DS ops are in-order).
        const unsigned long long* bp = stp + s;
        unsigned long long v[MSW];
#pragma unroll
        for (int w = 0; w < MSW; ++w) v[w] = bp[w];
        int me = (int)(unsigned int)v[0] - 1;
        bool crossedA = (s < e) && ((int)(unsigned int)(v[0] >> 32) < s);
        bool crossedB = false;
#pragma unroll
        for (int w = 1; w < MSW; ++w) {
            int j = s + w;
            bool in = (j <= e);
            int mej = (int)(unsigned int)v[w] - 1;
            int msj = (int)(unsigned int)(v[w] >> 32);
            bool hit = in && ((mej > e) || ((j < e) && (msj < s)));
            if (w & 1) crossedA = crossedA || hit;
            else       crossedB = crossedB || hit;
        }
        bool crossed = crossedA || crossedB;
        bool spec = !crossed && (me != e);

        // serial resolve — decision loop identical to the r2..r17-verified form
        int cbefore = count;
        unsigned long long window = ~0ull;
        unsigned int pend = 0u;
        int rk = 0, lcnt = 0;
        while (true) {
            unsigned long long b = __ballot(spec) & window;
            if (b == 0ull) break;
            int f = __ffsll((unsigned long long)b) - 1;
            unsigned int sef = __builtin_amdgcn_readlane(sev, (unsigned int)f);
            int sf = (int)(sef >> 16), ef = (int)(sef & 0xFFFFu);
            bool mine = (lane == lcnt);
            pend = mine ? sef : pend;
            rk = mine ? (ib + f) : rk;
            lcnt++;
            count++;
            if (count >= TOP_NUM) break;
            window &= (f >= 63) ? 0ull : (~0ull << (f + 1));
            if (lane > f) {
                if (s == sf) me = max(me, ef);
                crossed = crossed || ((s < sf) && (sf <= e) && (ef > e))
                                  || ((sf < s) && (s <= ef) && (ef < e));
                spec = !crossed && (me != e);
            }
        }
        if (lane < lcnt) {
            int sf = (int)(pend >> 16), ef = (int)(pend & 0xFFFFu);
            sel_g[cbefore + lane] = (unsigned short)rk;
            atomicMax(&st[2 * sf], (unsigned int)(ef + 1));
            atomicMin(&st[2 * ef + 1], (unsigned int)sf);
        }
        if (count >= TOP_NUM) break;
    }
    if (lane == 0) {
        *count_g = count;
        __hip_atomic_store(done_flag, 1, __ATOMIC_RELEASE, __HIP_MEMORY_SCOPE_AGENT);
    }
}

// ---------------- post: final span-order sort + emit ----------------
__global__ __launch_bounds__(256) void select_post(const float* __restrict__ scores,
                                                   const int* __restrict__ starts,
                                                   const int* __restrict__ ends,
                                                   const unsigned short* __restrict__ ord_g,
                                                   const unsigned short* __restrict__ sel_g,
                                                   const int* __restrict__ count_g,
                                                   float* out, int* top_idx_ws) {
    __shared__ unsigned long long fkeys[1024];
    int t = threadIdx.x;
    int count = *count_g;
    for (int i = t; i < 1024; i += 256) {
        unsigned long long k = 0xFFFFFFFFFFFFFFFFull;
        if (i < count) {
            int idx = (int)ord_g[sel_g[i]];
            unsigned int key32 = (unsigned int)(starts[idx] * NUM_WORDS + ends[idx]);
            k = ((unsigned long long)key32 << 32) | (unsigned int)idx;
        }
        fkeys[i] = k;
    }
    __syncthreads();
    for (int size = 2; size <= 1024; size <<= 1) {
        for (int stride = size >> 1; stride > 0; stride >>= 1) {
            for (int i = t; i < 1024; i += 256) {
                int ixj = i ^ stride;
                if (ixj > i) {
                    bool up = ((i & size) == 0);
                    unsigned long long a = fkeys[i], b = fkeys[ixj];
                    if ((a > b) == up) { fkeys[i] = b; fkeys[ixj] = a; }
                }
            }
            __syncthreads();
        }
    }
    for (int i = t; i < TOP_NUM; i += 256) {
        int fi = (i < count) ? (int)(fkeys[i] & 0xFFFFFFFFull)
                             : (int)(fkeys[0] & 0xFFFFFFFFull);
        out[OUT_TOPIDX + i] = (float)fi;
        out[OUT_TSTART + i] = (float)starts[fi];
        out[OUT_TEND + i] = (float)ends[fi];
        out[OUT_TSCORE + i] = scores[fi];
        top_idx_ws[i] = fi;
    }
}

// ---------------- gather top_span_emb rows directly from doc (exact fp32) ----------------
__global__ void gather_emb(const float* __restrict__ doc, const float* __restrict__ swe,
                           const float* __restrict__ attn_g, const int* __restrict__ starts,
                           const int* __restrict__ ends, const int* __restrict__ top_idx_ws,
                           float* __restrict__ out) {
    int r = blockIdx.x, t = threadIdx.x;
    int idx = top_idx_ws[r];
    int s = starts[idx], e = ends[idx];
    int wid = e - s;
    __shared__ float at[MSW];
    if (t < MSW) at[t] = attn_g[(size_t)idx * 32 + t];
    __syncthreads();
    float* dst = out + OUT_TEMB + (size_t)r * SPAN_DIM;
    if (t < 192) {
        int h4 = t * 4;
        f32x4 vs = *(const f32x4*)&doc[(size_t)s * HIDDEN + h4];
        f32x4 ve = *(const f32x4*)&doc[(size_t)e * HIDDEN + h4];
        f32x4 acc = {0.f, 0.f, 0.f, 0.f};
        for (int w = 0; w <= wid; ++w)
            acc += at[w] * *(const f32x4*)&doc[(size_t)(s + w) * HIDDEN + h4];
#pragma unroll
        for (int k = 0; k < 4; ++k) {
            dst[h4 + k] = vs[k];
            dst[HIDDEN + h4 + k] = ve[k];
            dst[2 * HIDDEN + FEAT + h4 + k] = acc[k];
        }
    }
    if (t < FEAT) dst[2 * HIDDEN + t] = swe[wid * FEAT + t];
}

extern "C" void kernel_launch(void* const* d_in, const int* in_sizes, int n_in,
                              void* d_out, int out_size, void* d_ws, size_t ws_size,
                              hipStream_t stream) {
    const float* mention_doc = (const float*)d_in[0];
    const float* span_width_emb = (const float*)d_in[1];
    const float* head_w = (const float*)d_in[2];
    const float* head_b = (const float*)d_in[3];
    const float* m_w1 = (const float*)d_in[4];
    const float* m_b1 = (const float*)d_in[5];
    const float* m_w2 = (const float*)d_in[6];
    const float* m_b2 = (const float*)d_in[7];
    const float* m_w3 = (const float*)d_in[8];
    const float* m_b3 = (const float*)d_in[9];
    const float* width_prior_emb = (const float*)d_in[10];
    const float* w_w1 = (const float*)d_in[11];
    const float* w_b1 = (const float*)d_in[12];
    const float* w_w2 = (const float*)d_in[13];
    const float* w_b2 = (const float*)d_in[14];
    const float* w_w3 = (const float*)d_in[15];
    const float* w_b3 = (const float*)d_in[16];
    const int* cand_starts = (const int*)d_in[17];
    const int* cand_ends = (const int*)d_in[18];

    char* w = (char*)d_ws;
    const size_t szH = (size_t)NUM_CAND * NP * 2;
    const size_t szW2 = (size_t)NP * KP2 * 2;
    const size_t szWc = (size_t)PNP * HIDDEN * 2;
    const size_t szD = (size_t)NUM_WORDS * HIDDEN * 2;
    char* p = w;
    unsigned short* h0 = (unsigned short*)p; p += szH;
    unsigned short* h1 = (unsigned short*)p; p += szH;
    unsigned short* h2 = (unsigned short*)p; p += szH;
    unsigned short* w2t0 = (unsigned short*)p; p += szW2;
    unsigned short* w2t1 = (unsigned short*)p; p += szW2;
    unsigned short* w2t2 = (unsigned short*)p; p += szW2;
    unsigned short* Wc0 = (unsigned short*)p; p += szWc;
    unsigned short* Wc1 = (unsigned short*)p; p += szWc;
    unsigned short* Wc2 = (unsigned short*)p; p += szWc;
    unsigned short* d0 = (unsigned short*)p; p += szD;
    unsigned short* d1 = (unsigned short*)p; p += szD;
    unsigned short* d2 = (unsigned short*)p; p += szD;
    float* P = (float*)p; p += (size_t)NUM_WORDS * PNP * 4;
    float* tw = (float*)p; p += (size_t)MSW * NP * 4;
    float* attn_g = (float*)p; p += (size_t)NUM_CAND * 32 * 4;
    float* partials = (float*)p; p += (size_t)NUM_CAND * 16 * 4;
    unsigned short* ord_g = (unsigned short*)p; p += (size_t)NUM_CAND * 2;
    unsigned int* se_g = (unsigned int*)p; p += (size_t)NUM_CAND * 4;
    unsigned short* sel_g = (unsigned short*)p; p += 2048;
    int* count_g = (int*)p; p += 128;
    float* head_s = (float*)p; p += NUM_WORDS * 4;
    float* width_s = (float*)p; p += 128;
    int* top_idx_ws = (int*)p; p += 4096;

    size_t need = (size_t)(p - w);
    if (ws_size < need) {
        fprintf(stderr, "kernel_launch: ws too small (%zu < %zu)\n", ws_size, need);
    }

    int* done_flag = count_g + 16;  // 64B past count_g, within the 128B count region

    float* out = (float*)d_out;

    head_kernel<<<NUM_WORDS / 4, 256, 0, stream>>>(mention_doc, head_w, head_b, head_s);
    width_kernel<<<MSW, 256, 0, stream>>>(width_prior_emb, w_w1, w_b1, w_w2, w_b2, w_w3, w_b3,
                                          width_s);
    attn_kernel<<<NUM_CAND / 4, 256, 0, stream>>>(head_s, cand_starts, cand_ends, attn_g);
    doc_convert<<<(NUM_WORDS * HIDDEN + 255) / 256, 256, 0, stream>>>(mention_doc, d0, d1, d2);
    convert_wc<<<dim3(3, 3072), 256, 0, stream>>>(m_w1, Wc0, Wc1, Wc2);
    convert_wt<<<dim3(4, 1024), 256, 0, stream>>>(m_w2, FFNN_DIM, FFNN_DIM, KP2,
                                                  w2t0, w2t1, w2t2);
    tw_kernel<<<MSW, 256, 0, stream>>>(span_width_emb, m_w1, tw);
    gemm6p<<<16 * 24, 256, 0, stream>>>(d0, d1, d2, Wc0, Wc1, Wc2, P);
    combine_kernel<<<NUM_CAND, 256, 0, stream>>>(P, tw, attn_g, m_b1, cand_starts, cand_ends,
                                                 h0, h1, h2);
    gemm6<<<512, 256, 0, stream>>>(h0, h1, h2, w2t0, w2t1, w2t2, m_b2, FFNN_DIM, KP2,
                                   m_w3, partials);
    score_final<<<NUM_CAND / 256, 256, 0, stream>>>(partials, m_b3, width_s, cand_starts,
                                                    cand_ends, out, done_flag);
    rank_kernel<<<NUM_CAND / 32, 256, 0, stream>>>(out, cand_starts, cand_ends, ord_g, se_g);
    select_nms<<<257, 64, 0, stream>>>(se_g, sel_g, count_g, done_flag);
    select_post<<<1, 256, 0, stream>>>(out, cand_starts, cand_ends, ord_g, sel_g, count_g,
                                       out, top_idx_ws);
    gather_emb<<<TOP_NUM, 256, 0, stream>>>(mention_doc, span_width_emb, attn_g, cand_starts,
                                            cand_ends, top_idx_ws, out);
}

// Round 7
// 820.212 us; speedup vs baseline: 1.1518x; 1.1001x over previous
//
#include <hip/hip_runtime.h>
#include <cstdio>
#include <cmath>

#define NUM_WORDS 2048
#define NUM_CAND 8192
#define HIDDEN 768
#define FEAT 20
#define FFNN_DIM 1000
#define SPAN_DIM 2324
#define TOP_NUM 819
#define MSW 30
#define KP2 1024   // FFNN padded to x32
#define NP 1024    // padded N
#define PNP 3072   // P matrix padded N (3 segments of 1024)

// d_out layout (floats): [scores 8192][top_idx 819][top_starts 819][top_ends 819]
//                        [top_span_emb 819*2324][top_scores 819]
#define OUT_TOPIDX   (NUM_CAND)
#define OUT_TSTART   (NUM_CAND + TOP_NUM)
#define OUT_TEND     (NUM_CAND + 2*TOP_NUM)
#define OUT_TEMB     (NUM_CAND + 3*TOP_NUM)
#define OUT_TSCORE   (NUM_CAND + 3*TOP_NUM + TOP_NUM*SPAN_DIM)

typedef short short8 __attribute__((ext_vector_type(8)));
typedef float f32x4 __attribute__((ext_vector_type(4)));
typedef unsigned short u16x4 __attribute__((ext_vector_type(4)));

__device__ __forceinline__ unsigned short bf16_rne(float x) {
    unsigned int u = __float_as_uint(x);
    unsigned int r = u + 0x7FFFu + ((u >> 16) & 1u);
    return (unsigned short)(r >> 16);
}
__device__ __forceinline__ float bf16_to_f(unsigned short h) {
    return __uint_as_float(((unsigned int)h) << 16);
}
// 2-way split: v = s0 + s1 + r, |r| <= 2^-16 |v|.
// r21: replaces the 3-way split. GEMMs use 3 products (a0b0+a0b1+a1b0) -> ~2^-16 rel
// error vs 2^-24 before; measured absmax (0.0039) is dominated elsewhere, so this holds.
__device__ __forceinline__ void store_split2(unsigned short* p0, unsigned short* p1,
                                             size_t off, float v) {
    unsigned short h0 = bf16_rne(v);
    float r1 = v - bf16_to_f(h0);
    p0[off] = h0;
    p1[off] = bf16_rne(r1);
}

// async 16B global->LDS (gfx950 global_load_lds_dwordx4). LDS dest must be
// wave-uniform base + lane*16 -> staging tiles are UNPADDED (128x32 bf16, 64B rows),
// bank conflicts handled by XOR swizzle: kblk stored at kblk^(row&3).
__device__ __forceinline__ void gl_lds16(const unsigned short* g, unsigned short* l) {
    __builtin_amdgcn_global_load_lds(
        (const __attribute__((address_space(1))) unsigned short*)g,
        (__attribute__((address_space(3))) unsigned short*)l, 16, 0, 0);
}

// ---------------- head scores: doc @ head_w + head_b  -> [2048] ----------------
__global__ void head_kernel(const float* __restrict__ doc, const float* __restrict__ hw,
                            const float* __restrict__ hb, float* __restrict__ out) {
    int wave = threadIdx.x >> 6, lane = threadIdx.x & 63;
    int row = blockIdx.x * 4 + wave;
    if (row >= NUM_WORDS) return;
    float acc = 0.f;
    for (int h = lane; h < HIDDEN; h += 64) acc += doc[row * HIDDEN + h] * hw[h];
    for (int off = 32; off > 0; off >>= 1) acc += __shfl_down(acc, off);
    if (lane == 0) out[row] = acc + hb[0];
}

// ---------------- width prior ffnn: [30,20] -> [30] ----------------
__global__ void width_kernel(const float* __restrict__ x, const float* __restrict__ w1,
                             const float* __restrict__ b1, const float* __restrict__ w2,
                             const float* __restrict__ b2, const float* __restrict__ w3,
                             const float* __restrict__ b3, float* __restrict__ out) {
    __shared__ float xs[FEAT];
    __shared__ float h1s[FFNN_DIM];
    __shared__ float red[256];
    int r = blockIdx.x, t = threadIdx.x;
    if (t < FEAT) xs[t] = x[r * FEAT + t];
    __syncthreads();
    for (int j = t; j < FFNN_DIM; j += 256) {
        float acc = b1[j];
        for (int k = 0; k < FEAT; ++k) acc += xs[k] * w1[k * FFNN_DIM + j];
        h1s[j] = fmaxf(acc, 0.f);
    }
    __syncthreads();
    float partial = 0.f;
    for (int j = t; j < FFNN_DIM; j += 256) {
        float acc = b2[j];
        for (int k = 0; k < FFNN_DIM; ++k) acc += h1s[k] * w2[k * FFNN_DIM + j];
        partial += fmaxf(acc, 0.f) * w3[j];
    }
    red[t] = partial;
    __syncthreads();
    for (int s = 128; s > 0; s >>= 1) { if (t < s) red[t] += red[t + s]; __syncthreads(); }
    if (t == 0) out[r] = red[0] + b3[0];
}

// ---------------- attention weights per span: attn_g [8192][32] ----------------
__global__ void attn_kernel(const float* __restrict__ head_s, const int* __restrict__ starts,
                            const int* __restrict__ ends, float* __restrict__ attn_g) {
    int wave = threadIdx.x >> 6, w = threadIdx.x & 63;
    int c = blockIdx.x * 4 + wave;
    if (c >= NUM_CAND) return;
    int s = starts[c], e = ends[c];
    int wid = e - s;
    float hsv = -INFINITY;
    if (w < MSW && w <= wid) hsv = head_s[s + w];
    float m = hsv;
    for (int off = 32; off > 0; off >>= 1) m = fmaxf(m, __shfl_down(m, off));
    m = __shfl(m, 0);
    float ex = (w < MSW && w <= wid) ? expf(hsv - m) : 0.f;
    float ssum = ex;
    for (int off = 32; off > 0; off >>= 1) ssum += __shfl_down(ssum, off);
    ssum = __shfl(ssum, 0);
    if (w < 32) attn_g[c * 32 + w] = (w < MSW) ? (ex / ssum) : 0.f;
}

// ---------------- doc fp32 -> 2-split bf16 [2048*768] ----------------
__global__ void doc_convert(const float* __restrict__ doc, unsigned short* __restrict__ d0,
                            unsigned short* __restrict__ d1) {
    int i = blockIdx.x * 256 + threadIdx.x;
    if (i < NUM_WORDS * HIDDEN) store_split2(d0, d1, i, doc[i]);
}

// ---------------- weight convert+transpose: w[K][N] -> 2-split [gridDim.y][Kp] ------------
__global__ void convert_wt(const float* __restrict__ w, int K, int N, int Kp,
                           unsigned short* __restrict__ q0, unsigned short* __restrict__ q1) {
    int n = blockIdx.y;
    int k = blockIdx.x * blockDim.x + threadIdx.x;
    if (k >= Kp) return;
    float v = (k < K && n < N) ? w[(size_t)k * N + n] : 0.f;
    store_split2(q0, q1, (size_t)n * Kp + k, v);
}

// ---------------- fused Wc convert: 3 segments of m_w1 -> 2-split [3072][768] ------------
// seg row bases: 0 -> rows 0..767 (start), 1 -> 768..1535 (end), 2 -> 1556..2323 (attended)
__global__ void convert_wc(const float* __restrict__ w1,
                           unsigned short* __restrict__ q0, unsigned short* __restrict__ q1) {
    int n2 = blockIdx.y;                    // 0..3071 output row
    int seg = n2 >> 10;
    int n = n2 & 1023;                      // col within segment
    int k = blockIdx.x * 256 + threadIdx.x; // 0..767
    int row0 = (seg == 0) ? 0 : ((seg == 1) ? HIDDEN : 1556);
    float v = (n < FFNN_DIM) ? w1[(size_t)(row0 + k) * FFNN_DIM + n] : 0.f;
    store_split2(q0, q1, (size_t)n2 * HIDDEN + k, v);
}

// ---------------- T_w[wid][1024] = span_width_emb[wid] @ m_w1[1536:1556] ----------------
__global__ void tw_kernel(const float* __restrict__ swe, const float* __restrict__ w1,
                          float* __restrict__ tw) {
    int wid = blockIdx.x, t = threadIdx.x;
    for (int n = t; n < NP; n += 256) {
        float acc = 0.f;
        if (n < FFNN_DIM) {
            for (int f = 0; f < FEAT; ++f)
                acc += swe[wid * FEAT + f] * w1[(size_t)(1536 + f) * FFNN_DIM + n];
        }
        tw[wid * NP + n] = acc;
    }
}

// Stage one 128x32-bf16 tile (8KB) async into LDS with XOR swizzle.
__device__ __forceinline__ void stage_tile(const unsigned short* __restrict__ src,
                                           unsigned short* lds, int base_row, int Kp, int k0,
                                           int t) {
#pragma unroll
    for (int qi = 0; qi < 2; ++qi) {
        int u = qi * 256 + t;
        int l = u & 63;
        int row = ((u >> 6) << 4) + (l >> 2);
        int cblk = (l & 3) ^ (row & 3);
        const unsigned short* g = src + (size_t)(base_row + row) * Kp + k0 + cblk * 8;
        gl_lds16(g, lds + u * 8);
    }
}

// ---------------- 2-split 3-product MFMA GEMM, fp32 out: P = doc @ [W_s|W_e|W_a] ---------
__global__ __launch_bounds__(256, 2) void gemm3p(
    const unsigned short* __restrict__ A0, const unsigned short* __restrict__ A1,
    const unsigned short* __restrict__ B0, const unsigned short* __restrict__ B1,
    float* __restrict__ C) {
    __shared__ unsigned short As0[128 * 32], As1[128 * 32];
    __shared__ unsigned short Bs0[128 * 32], Bs1[128 * 32];
    int t = threadIdx.x;
    int bid = blockIdx.x;
    int bm = (bid & 15) << 7;
    int bn = (bid >> 4) << 7;
    int lane = t & 63, wv = t >> 6;
    int wm = (wv >> 1) * 64, wn = (wv & 1) * 64;
    int lr = lane & 15, qq = lane >> 4;
    int sw = (qq ^ (lr & 3)) * 8;

    f32x4 acc[4][4] = {};

    for (int k0 = 0; k0 < HIDDEN; k0 += 32) {
        stage_tile(A0, As0, bm, HIDDEN, k0, t);
        stage_tile(A1, As1, bm, HIDDEN, k0, t);
        stage_tile(B0, Bs0, bn, HIDDEN, k0, t);
        stage_tile(B1, Bs1, bn, HIDDEN, k0, t);
        __syncthreads();
        short8 a0[4], a1[4];
#pragma unroll
        for (int i = 0; i < 4; ++i) {
            int ra = (wm + i * 16 + lr) * 32 + sw;
            a0[i] = *(const short8*)&As0[ra];
            a1[i] = *(const short8*)&As1[ra];
        }
#pragma unroll
        for (int j = 0; j < 4; ++j) {
            int rb = (wn + j * 16 + lr) * 32 + sw;
            short8 b0 = *(const short8*)&Bs0[rb];
            short8 b1 = *(const short8*)&Bs1[rb];
#pragma unroll
            for (int i = 0; i < 4; ++i) {
                acc[i][j] = __builtin_amdgcn_mfma_f32_16x16x32_bf16(a1[i], b0, acc[i][j], 0, 0, 0);
                acc[i][j] = __builtin_amdgcn_mfma_f32_16x16x32_bf16(a0[i], b1, acc[i][j], 0, 0, 0);
                acc[i][j] = __builtin_amdgcn_mfma_f32_16x16x32_bf16(a0[i], b0, acc[i][j], 0, 0, 0);
            }
        }
        __syncthreads();
    }
#pragma unroll
    for (int i = 0; i < 4; ++i)
#pragma unroll
        for (int j = 0; j < 4; ++j)
#pragma unroll
            for (int r = 0; r < 4; ++r) {
                int m = bm + wm + i * 16 + qq * 4 + r;
                int n = bn + wn + j * 16 + lr;
                C[(size_t)m * PNP + n] = acc[i][j][r];
            }
}

// ---------------- combine: h1[c] = relu(P_s[s] + P_e[e] + sum attn*P_a[s+w] + Tw + b1) ----
// float4 loads + 2-split ushort4 stores. Per-element FP order unchanged.
__global__ void combine_kernel(const float* __restrict__ P, const float* __restrict__ tw,
                               const float* __restrict__ attn_g, const float* __restrict__ b1,
                               const int* __restrict__ starts, const int* __restrict__ ends,
                               unsigned short* __restrict__ h0, unsigned short* __restrict__ h1) {
    int c = blockIdx.x, t = threadIdx.x;
    int s = starts[c], e = ends[c];
    int wid = e - s;
    __shared__ float at[MSW];
    if (t < MSW) at[t] = attn_g[c * 32 + t];
    __syncthreads();
    int n0 = t * 4;
    size_t ho = (size_t)c * NP + n0;
    if (t < 250) {
        f32x4 acc = *(const f32x4*)&P[(size_t)s * PNP + n0];
        acc += *(const f32x4*)&P[(size_t)e * PNP + 1024 + n0];
        acc += *(const f32x4*)&tw[(size_t)wid * NP + n0];
        acc += *(const f32x4*)&b1[n0];
        const float* Pa = P + (size_t)s * PNP + 2048 + n0;
        for (int w = 0; w <= wid; ++w)
            acc += at[w] * *(const f32x4*)&Pa[(size_t)w * PNP];
        u16x4 q0, q1;
#pragma unroll
        for (int k = 0; k < 4; ++k) {
            float v = fmaxf(acc[k], 0.f);
            unsigned short x0 = bf16_rne(v);
            float r1 = v - bf16_to_f(x0);
            q0[k] = x0; q1[k] = bf16_rne(r1);
        }
        *(u16x4*)&h0[ho] = q0;
        *(u16x4*)&h1[ho] = q1;
    } else {
        u16x4 z = {0, 0, 0, 0};
        *(u16x4*)&h0[ho] = z;
        *(u16x4*)&h1[ho] = z;
    }
}

// ---------------- 2-split 3-product MFMA GEMM (score fusion) ------------
__global__ __launch_bounds__(256, 2) void gemm3(
    const unsigned short* __restrict__ A0, const unsigned short* __restrict__ A1,
    const unsigned short* __restrict__ B0, const unsigned short* __restrict__ B1,
    const float* __restrict__ bias, int nreal, int Kp,
    const float* __restrict__ w3, float* __restrict__ partials) {
    __shared__ unsigned short As0[128 * 32], As1[128 * 32];
    __shared__ unsigned short Bs0[128 * 32], Bs1[128 * 32];
    int t = threadIdx.x;
    int bid = blockIdx.x;
    int sm = bid >> 6, idx = bid & 63;
    int bm = ((sm << 3) + (idx & 7)) << 7;
    int bn = (idx >> 3) << 7;
    int lane = t & 63, wv = t >> 6;
    int wm = (wv >> 1) * 64, wn = (wv & 1) * 64;
    int lr = lane & 15, qq = lane >> 4;
    int sw = (qq ^ (lr & 3)) * 8;

    f32x4 acc[4][4] = {};

    for (int k0 = 0; k0 < Kp; k0 += 32) {
        stage_tile(A0, As0, bm, Kp, k0, t);
        stage_tile(A1, As1, bm, Kp, k0, t);
        stage_tile(B0, Bs0, bn, Kp, k0, t);
        stage_tile(B1, Bs1, bn, Kp, k0, t);
        __syncthreads();
        short8 a0[4], a1[4];
#pragma unroll
        for (int i = 0; i < 4; ++i) {
            int ra = (wm + i * 16 + lr) * 32 + sw;
            a0[i] = *(const short8*)&As0[ra];
            a1[i] = *(const short8*)&As1[ra];
        }
#pragma unroll
        for (int j = 0; j < 4; ++j) {
            int rb = (wn + j * 16 + lr) * 32 + sw;
            short8 b0 = *(const short8*)&Bs0[rb];
            short8 b1 = *(const short8*)&Bs1[rb];
#pragma unroll
            for (int i = 0; i < 4; ++i) {
                acc[i][j] = __builtin_amdgcn_mfma_f32_16x16x32_bf16(a1[i], b0, acc[i][j], 0, 0, 0);
                acc[i][j] = __builtin_amdgcn_mfma_f32_16x16x32_bf16(a0[i], b1, acc[i][j], 0, 0, 0);
                acc[i][j] = __builtin_amdgcn_mfma_f32_16x16x32_bf16(a0[i], b0, acc[i][j], 0, 0, 0);
            }
        }
        __syncthreads();
    }

    int pid = ((bn >> 7) << 1) | (wn >> 6);  // 0..15
#pragma unroll
    for (int i = 0; i < 4; ++i)
#pragma unroll
        for (int r = 0; r < 4; ++r) {
            float p = 0.f;
#pragma unroll
            for (int j = 0; j < 4; ++j) {
                int n = bn + wn + j * 16 + lr;
                float v = acc[i][j][r] + (n < nreal ? bias[n] : 0.f);
                v = fmaxf(v, 0.f);
                p += v * (n < nreal ? w3[n] : 0.f);
            }
            p += __shfl_xor(p, 1);
            p += __shfl_xor(p, 2);
            p += __shfl_xor(p, 4);
            p += __shfl_xor(p, 8);
            if (lr == 0) {
                int m = bm + wm + i * 16 + qq * 4 + r;
                partials[(size_t)m * 16 + pid] = p;
            }
        }
}

// ---------------- deterministic score finalize ----------------
__global__ void score_final(const float* __restrict__ partials, const float* __restrict__ b3,
                            const float* __restrict__ width_s, const int* __restrict__ starts,
                            const int* __restrict__ ends, float* __restrict__ out) {
    int c = blockIdx.x * 256 + threadIdx.x;
    if (c >= NUM_CAND) return;
    float s = b3[0] + width_s[ends[c] - starts[c]];
#pragma unroll
    for (int p = 0; p < 16; ++p) s += partials[(size_t)c * 16 + p];
    out[c] = s;
}

// ---------------- exact counting rank-sort: 256 blocks ----------------
__global__ __launch_bounds__(256) void rank_kernel(const float* __restrict__ scores,
                                                   const int* __restrict__ starts,
                                                   const int* __restrict__ ends,
                                                   unsigned short* __restrict__ ord_g,
                                                   unsigned int* __restrict__ se_g) {
    __shared__ unsigned long long kk[NUM_CAND];  // 64 KB
    int t = threadIdx.x;
    for (int i = t; i < NUM_CAND; i += 256) {
        unsigned int b = __float_as_uint(scores[i]);
        unsigned int u = b ^ ((b & 0x80000000u) ? 0xFFFFFFFFu : 0x80000000u);
        unsigned int hi = ~u;
        kk[i] = ((unsigned long long)hi << 32) | (unsigned int)i;
    }
    __syncthreads();
    int c = blockIdx.x * 32 + (t >> 3);
    int seg = (t & 7) * 1024;
    unsigned long long mykey = kk[c];
    int cnt = 0;
    for (int i = seg; i < seg + 1024; ++i) cnt += (kk[i] < mykey) ? 1 : 0;
    cnt += __shfl_xor(cnt, 1);
    cnt += __shfl_xor(cnt, 2);
    cnt += __shfl_xor(cnt, 4);
    if ((t & 7) == 0) {
        int idx = (int)(mykey & 0xFFFFFFFFull);
        int rank = cnt;
        ord_g[rank] = (unsigned short)idx;
        se_g[rank] = ((unsigned int)starts[idx] << 16) | (unsigned int)ends[idx];
    }
}

// ---------------- single-wave greedy crossing-NMS ----------------
// r21: LOCKED at the r17-verified form (292us). Evidence: r13 8-wave=313, r15 flag=401,
// r18 pipelined=374, r19 fixpoint=356, r20 clock-hold spinners=350 (DVFS falsified —
// busy CUs didn't speed the wave; the cost is dependent-chain latency, structural).
// Every added instruction costs ~8 cycles wall; only LESS work helps, and this is the
// least-work form found. Do not restructure further.
__global__ __launch_bounds__(64, 1)
void select_nms(const unsigned int* __restrict__ se_g,
                unsigned short* __restrict__ sel_g,
                int* __restrict__ count_g) {
    __shared__ unsigned int se_arr[NUM_CAND];   // 32 KB
    __shared__ unsigned int st[2 * NUM_WORDS];  // 16 KB
    int lane = threadIdx.x;

    {
        const uint4* src4 = (const uint4*)se_g;
        uint4* dst4 = (uint4*)se_arr;
        for (int i = lane; i < NUM_CAND / 4; i += 64) dst4[i] = src4[i];
    }
    for (int i = lane; i < 2 * NUM_WORDS; i += 64)
        st[i] = (i & 1) ? (unsigned int)NUM_WORDS : 0u;  // max_end+1=0, min_start=2048
    __syncthreads();

    const unsigned long long* stp = (const unsigned long long*)st;
    int count = 0;
    for (int c = 0; c < NUM_CAND / 64; ++c) {
        int ib = c * 64;
        unsigned int sev = se_arr[ib + lane];
        int s = (int)(sev >> 16), e = (int)(sev & 0xFFFFu);
        // snapshot: by program order this wave's own st atomics from all previous chunks
        // are visible (per-wave DS ops are in-order).
        const unsigned long long* bp = stp + s;
        unsigned long long v[MSW];
#pragma unroll
        for (int w = 0; w < MSW; ++w) v[w] = bp[w];
        int me = (int)(unsigned int)v[0] - 1;
        bool crossedA = (s < e) && ((int)(unsigned int)(v[0] >> 32) < s);
        bool crossedB = false;
#pragma unroll
        for (int w = 1; w < MSW; ++w) {
            int j = s + w;
            bool in = (j <= e);
            int mej = (int)(unsigned int)v[w] - 1;
            int msj = (int)(unsigned int)(v[w] >> 32);
            bool hit = in && ((mej > e) || ((j < e) && (msj < s)));
            if (w & 1) crossedA = crossedA || hit;
            else       crossedB = crossedB || hit;
        }
        bool crossed = crossedA || crossedB;
        bool spec = !crossed && (me != e);

        // serial resolve — decision loop identical to the r2..r17-verified form
        int cbefore = count;
        unsigned long long window = ~0ull;
        unsigned int pend = 0u;
        int rk = 0, lcnt = 0;
        while (true) {
            unsigned long long b = __ballot(spec) & window;
            if (b == 0ull) break;
            int f = __ffsll((unsigned long long)b) - 1;
            unsigned int sef = __builtin_amdgcn_readlane(sev, (unsigned int)f);
            int sf = (int)(sef >> 16), ef = (int)(sef & 0xFFFFu);
            bool mine = (lane == lcnt);
            pend = mine ? sef : pend;
            rk = mine ? (ib + f) : rk;
            lcnt++;
            count++;
            if (count >= TOP_NUM) break;
            window &= (f >= 63) ? 0ull : (~0ull << (f + 1));
            if (lane > f) {
                if (s == sf) me = max(me, ef);
                crossed = crossed || ((s < sf) && (sf <= e) && (ef > e))
                                  || ((sf < s) && (s <= ef) && (ef < e));
                spec = !crossed && (me != e);
            }
        }
        if (lane < lcnt) {
            int sf = (int)(pend >> 16), ef = (int)(pend & 0xFFFFu);
            sel_g[cbefore + lane] = (unsigned short)rk;
            atomicMax(&st[2 * sf], (unsigned int)(ef + 1));
            atomicMin(&st[2 * ef + 1], (unsigned int)sf);
        }
        if (count >= TOP_NUM) break;
    }
    if (lane == 0) *count_g = count;
}

// ---------------- post: final span-order sort + emit ----------------
__global__ __launch_bounds__(256) void select_post(const float* __restrict__ scores,
                                                   const int* __restrict__ starts,
                                                   const int* __restrict__ ends,
                                                   const unsigned short* __restrict__ ord_g,
                                                   const unsigned short* __restrict__ sel_g,
                                                   const int* __restrict__ count_g,
                                                   float* out, int* top_idx_ws) {
    __shared__ unsigned long long fkeys[1024];
    int t = threadIdx.x;
    int count = *count_g;
    for (int i = t; i < 1024; i += 256) {
        unsigned long long k = 0xFFFFFFFFFFFFFFFFull;
        if (i < count) {
            int idx = (int)ord_g[sel_g[i]];
            unsigned int key32 = (unsigned int)(starts[idx] * NUM_WORDS + ends[idx]);
            k = ((unsigned long long)key32 << 32) | (unsigned int)idx;
        }
        fkeys[i] = k;
    }
    __syncthreads();
    for (int size = 2; size <= 1024; size <<= 1) {
        for (int stride = size >> 1; stride > 0; stride >>= 1) {
            for (int i = t; i < 1024; i += 256) {
                int ixj = i ^ stride;
                if (ixj > i) {
                    bool up = ((i & size) == 0);
                    unsigned long long a = fkeys[i], b = fkeys[ixj];
                    if ((a > b) == up) { fkeys[i] = b; fkeys[ixj] = a; }
                }
            }
            __syncthreads();
        }
    }
    for (int i = t; i < TOP_NUM; i += 256) {
        int fi = (i < count) ? (int)(fkeys[i] & 0xFFFFFFFFull)
                             : (int)(fkeys[0] & 0xFFFFFFFFull);
        out[OUT_TOPIDX + i] = (float)fi;
        out[OUT_TSTART + i] = (float)starts[fi];
        out[OUT_TEND + i] = (float)ends[fi];
        out[OUT_TSCORE + i] = scores[fi];
        top_idx_ws[i] = fi;
    }
}

// ---------------- gather top_span_emb rows directly from doc (exact fp32) ----------------
__global__ void gather_emb(const float* __restrict__ doc, const float* __restrict__ swe,
                           const float* __restrict__ attn_g, const int* __restrict__ starts,
                           const int* __restrict__ ends, const int* __restrict__ top_idx_ws,
                           float* __restrict__ out) {
    int r = blockIdx.x, t = threadIdx.x;
    int idx = top_idx_ws[r];
    int s = starts[idx], e = ends[idx];
    int wid = e - s;
    __shared__ float at[MSW];
    if (t < MSW) at[t] = attn_g[(size_t)idx * 32 + t];
    __syncthreads();
    float* dst = out + OUT_TEMB + (size_t)r * SPAN_DIM;
    if (t < 192) {
        int h4 = t * 4;
        f32x4 vs = *(const f32x4*)&doc[(size_t)s * HIDDEN + h4];
        f32x4 ve = *(const f32x4*)&doc[(size_t)e * HIDDEN + h4];
        f32x4 acc = {0.f, 0.f, 0.f, 0.f};
        for (int w = 0; w <= wid; ++w)
            acc += at[w] * *(const f32x4*)&doc[(size_t)(s + w) * HIDDEN + h4];
#pragma unroll
        for (int k = 0; k < 4; ++k) {
            dst[h4 + k] = vs[k];
            dst[HIDDEN + h4 + k] = ve[k];
            dst[2 * HIDDEN + FEAT + h4 + k] = acc[k];
        }
    }
    if (t < FEAT) dst[2 * HIDDEN + t] = swe[wid * FEAT + t];
}

extern "C" void kernel_launch(void* const* d_in, const int* in_sizes, int n_in,
                              void* d_out, int out_size, void* d_ws, size_t ws_size,
                              hipStream_t stream) {
    const float* mention_doc = (const float*)d_in[0];
    const float* span_width_emb = (const float*)d_in[1];
    const float* head_w = (const float*)d_in[2];
    const float* head_b = (const float*)d_in[3];
    const float* m_w1 = (const float*)d_in[4];
    const float* m_b1 = (const float*)d_in[5];
    const float* m_w2 = (const float*)d_in[6];
    const float* m_b2 = (const float*)d_in[7];
    const float* m_w3 = (const float*)d_in[8];
    const float* m_b3 = (const float*)d_in[9];
    const float* width_prior_emb = (const float*)d_in[10];
    const float* w_w1 = (const float*)d_in[11];
    const float* w_b1 = (const float*)d_in[12];
    const float* w_w2 = (const float*)d_in[13];
    const float* w_b2 = (const float*)d_in[14];
    const float* w_w3 = (const float*)d_in[15];
    const float* w_b3 = (const float*)d_in[16];
    const int* cand_starts = (const int*)d_in[17];
    const int* cand_ends = (const int*)d_in[18];

    char* w = (char*)d_ws;
    const size_t szH = (size_t)NUM_CAND * NP * 2;
    const size_t szW2 = (size_t)NP * KP2 * 2;
    const size_t szWc = (size_t)PNP * HIDDEN * 2;
    const size_t szD = (size_t)NUM_WORDS * HIDDEN * 2;
    char* p = w;
    unsigned short* h0 = (unsigned short*)p; p += szH;
    unsigned short* h1 = (unsigned short*)p; p += szH;
    unsigned short* w2t0 = (unsigned short*)p; p += szW2;
    unsigned short* w2t1 = (unsigned short*)p; p += szW2;
    unsigned short* Wc0 = (unsigned short*)p; p += szWc;
    unsigned short* Wc1 = (unsigned short*)p; p += szWc;
    unsigned short* d0 = (unsigned short*)p; p += szD;
    unsigned short* d1 = (unsigned short*)p; p += szD;
    float* P = (float*)p; p += (size_t)NUM_WORDS * PNP * 4;
    float* tw = (float*)p; p += (size_t)MSW * NP * 4;
    float* attn_g = (float*)p; p += (size_t)NUM_CAND * 32 * 4;
    float* partials = (float*)p; p += (size_t)NUM_CAND * 16 * 4;
    unsigned short* ord_g = (unsigned short*)p; p += (size_t)NUM_CAND * 2;
    unsigned int* se_g = (unsigned int*)p; p += (size_t)NUM_CAND * 4;
    unsigned short* sel_g = (unsigned short*)p; p += 2048;
    int* count_g = (int*)p; p += 128;
    float* head_s = (float*)p; p += NUM_WORDS * 4;
    float* width_s = (float*)p; p += 128;
    int* top_idx_ws = (int*)p; p += 4096;

    size_t need = (size_t)(p - w);
    if (ws_size < need) {
        fprintf(stderr, "kernel_launch: ws too small (%zu < %zu)\n", ws_size, need);
    }

    float* out = (float*)d_out;

    head_kernel<<<NUM_WORDS / 4, 256, 0, stream>>>(mention_doc, head_w, head_b, head_s);
    width_kernel<<<MSW, 256, 0, stream>>>(width_prior_emb, w_w1, w_b1, w_w2, w_b2, w_w3, w_b3,
                                          width_s);
    attn_kernel<<<NUM_CAND / 4, 256, 0, stream>>>(head_s, cand_starts, cand_ends, attn_g);
    doc_convert<<<(NUM_WORDS * HIDDEN + 255) / 256, 256, 0, stream>>>(mention_doc, d0, d1);
    convert_wc<<<dim3(3, 3072), 256, 0, stream>>>(m_w1, Wc0, Wc1);
    convert_wt<<<dim3(4, 1024), 256, 0, stream>>>(m_w2, FFNN_DIM, FFNN_DIM, KP2,
                                                  w2t0, w2t1);
    tw_kernel<<<MSW, 256, 0, stream>>>(span_width_emb, m_w1, tw);
    gemm3p<<<16 * 24, 256, 0, stream>>>(d0, d1, Wc0, Wc1, P);
    combine_kernel<<<NUM_CAND, 256, 0, stream>>>(P, tw, attn_g, m_b1, cand_starts, cand_ends,
                                                 h0, h1);
    gemm3<<<512, 256, 0, stream>>>(h0, h1, w2t0, w2t1, m_b2, FFNN_DIM, KP2,
                                   m_w3, partials);
    score_final<<<NUM_CAND / 256, 256, 0, stream>>>(partials, m_b3, width_s, cand_starts,
                                                    cand_ends, out);
    rank_kernel<<<NUM_CAND / 32, 256, 0, stream>>>(out, cand_starts, cand_ends, ord_g, se_g);
    select_nms<<<1, 64, 0, stream>>>(se_g, sel_g, count_g);
    select_post<<<1, 256, 0, stream>>>(out, cand_starts, cand_ends, ord_g, sel_g, count_g,
                                       out, top_idx_ws);
    gather_emb<<<TOP_NUM, 256, 0, stream>>>(mention_doc, span_width_emb, attn_g, cand_starts,
                                            cand_ends, top_idx_ws, out);
}

// Round 8
// 792.869 us; speedup vs baseline: 1.1916x; 1.0345x over previous
//
#include <hip/hip_runtime.h>
#include <cstdio>
#include <cmath>

#define NUM_WORDS 2048
#define NUM_CAND 8192
#define HIDDEN 768
#define FEAT 20
#define FFNN_DIM 1000
#define SPAN_DIM 2324
#define TOP_NUM 819
#define MSW 30
#define KP2 1024   // FFNN padded to x32
#define NP 1024    // padded N
#define PNP 3072   // P matrix padded N (3 segments of 1024)

// d_out layout (floats): [scores 8192][top_idx 819][top_starts 819][top_ends 819]
//                        [top_span_emb 819*2324][top_scores 819]
#define OUT_TOPIDX   (NUM_CAND)
#define OUT_TSTART   (NUM_CAND + TOP_NUM)
#define OUT_TEND     (NUM_CAND + 2*TOP_NUM)
#define OUT_TEMB     (NUM_CAND + 3*TOP_NUM)
#define OUT_TSCORE   (NUM_CAND + 3*TOP_NUM + TOP_NUM*SPAN_DIM)

typedef short short8 __attribute__((ext_vector_type(8)));
typedef float f32x4 __attribute__((ext_vector_type(4)));
typedef unsigned short u16x4 __attribute__((ext_vector_type(4)));

__device__ __forceinline__ unsigned short bf16_rne(float x) {
    unsigned int u = __float_as_uint(x);
    unsigned int r = u + 0x7FFFu + ((u >> 16) & 1u);
    return (unsigned short)(r >> 16);
}
__device__ __forceinline__ float bf16_to_f(unsigned short h) {
    return __uint_as_float(((unsigned int)h) << 16);
}
// 2-way split: v = s0 + s1 + r, |r| <= 2^-16 |v| (r21-verified: absmax unchanged)
__device__ __forceinline__ void store_split2(unsigned short* p0, unsigned short* p1,
                                             size_t off, float v) {
    unsigned short h0 = bf16_rne(v);
    float r1 = v - bf16_to_f(h0);
    p0[off] = h0;
    p1[off] = bf16_rne(r1);
}

// async 16B global->LDS (gfx950 global_load_lds_dwordx4). LDS dest must be
// wave-uniform base + lane*16 -> staging tiles are UNPADDED (128x32 bf16, 64B rows),
// bank conflicts handled by XOR swizzle: kblk stored at kblk^(row&3).
__device__ __forceinline__ void gl_lds16(const unsigned short* g, unsigned short* l) {
    __builtin_amdgcn_global_load_lds(
        (const __attribute__((address_space(1))) unsigned short*)g,
        (__attribute__((address_space(3))) unsigned short*)l, 16, 0, 0);
}

// ---------------- head scores: doc @ head_w + head_b  -> [2048] ----------------
// r22: block 0 also zeroes the start-histogram (consumed by attn_kernel next dispatch).
__global__ void head_kernel(const float* __restrict__ doc, const float* __restrict__ hw,
                            const float* __restrict__ hb, float* __restrict__ out,
                            int* __restrict__ hist) {
    if (blockIdx.x == 0) {
        for (int i = threadIdx.x; i < NUM_WORDS; i += 256) hist[i] = 0;
    }
    int wave = threadIdx.x >> 6, lane = threadIdx.x & 63;
    int row = blockIdx.x * 4 + wave;
    if (row >= NUM_WORDS) return;
    float acc = 0.f;
    for (int h = lane; h < HIDDEN; h += 64) acc += doc[row * HIDDEN + h] * hw[h];
    for (int off = 32; off > 0; off >>= 1) acc += __shfl_down(acc, off);
    if (lane == 0) out[row] = acc + hb[0];
}

// ---------------- width prior ffnn: [30,20] -> [30] ----------------
__global__ void width_kernel(const float* __restrict__ x, const float* __restrict__ w1,
                             const float* __restrict__ b1, const float* __restrict__ w2,
                             const float* __restrict__ b2, const float* __restrict__ w3,
                             const float* __restrict__ b3, float* __restrict__ out) {
    __shared__ float xs[FEAT];
    __shared__ float h1s[FFNN_DIM];
    __shared__ float red[256];
    int r = blockIdx.x, t = threadIdx.x;
    if (t < FEAT) xs[t] = x[r * FEAT + t];
    __syncthreads();
    for (int j = t; j < FFNN_DIM; j += 256) {
        float acc = b1[j];
        for (int k = 0; k < FEAT; ++k) acc += xs[k] * w1[k * FFNN_DIM + j];
        h1s[j] = fmaxf(acc, 0.f);
    }
    __syncthreads();
    float partial = 0.f;
    for (int j = t; j < FFNN_DIM; j += 256) {
        float acc = b2[j];
        for (int k = 0; k < FFNN_DIM; ++k) acc += h1s[k] * w2[k * FFNN_DIM + j];
        partial += fmaxf(acc, 0.f) * w3[j];
    }
    red[t] = partial;
    __syncthreads();
    for (int s = 128; s > 0; s >>= 1) { if (t < s) red[t] += red[t + s]; __syncthreads(); }
    if (t == 0) out[r] = red[0] + b3[0];
}

// ---------------- attention weights per span: attn_g [8192][32] ----------------
// r22: also builds the start-histogram (one atomicAdd per candidate; counts deterministic).
__global__ void attn_kernel(const float* __restrict__ head_s, const int* __restrict__ starts,
                            const int* __restrict__ ends, float* __restrict__ attn_g,
                            int* __restrict__ hist) {
    int wave = threadIdx.x >> 6, w = threadIdx.x & 63;
    int c = blockIdx.x * 4 + wave;
    if (c >= NUM_CAND) return;
    int s = starts[c], e = ends[c];
    if (w == 0) atomicAdd(&hist[s], 1);
    int wid = e - s;
    float hsv = -INFINITY;
    if (w < MSW && w <= wid) hsv = head_s[s + w];
    float m = hsv;
    for (int off = 32; off > 0; off >>= 1) m = fmaxf(m, __shfl_down(m, off));
    m = __shfl(m, 0);
    float ex = (w < MSW && w <= wid) ? expf(hsv - m) : 0.f;
    float ssum = ex;
    for (int off = 32; off > 0; off >>= 1) ssum += __shfl_down(ssum, off);
    ssum = __shfl(ssum, 0);
    if (w < 32) attn_g[c * 32 + w] = (w < MSW) ? (ex / ssum) : 0.f;
}

// ---------------- counting-sort permutation by start (scan + scatter, 1 block) ----------
// Order within a start-bin is atomic-timing-dependent, but ANY permutation is correct:
// combine writes h[c] by original candidate id with identical per-candidate arithmetic.
__global__ __launch_bounds__(256) void perm_kernel(const int* __restrict__ hist,
                                                   const int* __restrict__ starts,
                                                   int* __restrict__ perm) {
    __shared__ int hoff[NUM_WORDS];
    __shared__ int wsum[4];
    int t = threadIdx.x, lane = t & 63, wv = t >> 6;
    int base = t * 8;
    int lh[8];
    int s0 = 0;
#pragma unroll
    for (int i = 0; i < 8; ++i) { lh[i] = hist[base + i]; s0 += lh[i]; }
    int sc = s0;
    for (int o = 1; o < 64; o <<= 1) { int v = __shfl_up(sc, o); if (lane >= o) sc += v; }
    if (lane == 63) wsum[wv] = sc;
    __syncthreads();
    int wbase = 0;
    for (int i = 0; i < wv; ++i) wbase += wsum[i];
    int run = wbase + sc - s0;  // exclusive prefix of this thread's 8 bins
#pragma unroll
    for (int i = 0; i < 8; ++i) { hoff[base + i] = run; run += lh[i]; }
    __syncthreads();
    for (int c = t; c < NUM_CAND; c += 256) {
        int pos = atomicAdd(&hoff[starts[c]], 1);
        perm[pos] = c;
    }
}

// ---------------- doc fp32 -> 2-split bf16 [2048*768] ----------------
__global__ void doc_convert(const float* __restrict__ doc, unsigned short* __restrict__ d0,
                            unsigned short* __restrict__ d1) {
    int i = blockIdx.x * 256 + threadIdx.x;
    if (i < NUM_WORDS * HIDDEN) store_split2(d0, d1, i, doc[i]);
}

// ---------------- Wc convert via LDS tile-transpose: coalesced both sides --------------
// r22: old version read w1 columns at stride 4KB (16x over-fetch). 64x64 tiles.
// seg row bases: 0 -> rows 0..767 (start), 1 -> 768..1535 (end), 2 -> 1556..2323.
__global__ __launch_bounds__(256) void convert_wc(const float* __restrict__ w1,
                                                  unsigned short* __restrict__ q0,
                                                  unsigned short* __restrict__ q1) {
    __shared__ float tile[64][65];
    int kbase = blockIdx.x << 6;            // 0..704 (12 tiles over 768)
    int n2base = blockIdx.y << 6;           // 0..3008 (48 tiles over 3072)
    int seg = n2base >> 10;
    int nbase = n2base & 1023;
    int row0 = (seg == 0) ? 0 : ((seg == 1) ? HIDDEN : 1556);
    int t = threadIdx.x;
    int c = t & 63, r0 = t >> 6;
    for (int rr = 0; rr < 64; rr += 4) {
        int r = rr + r0;
        int n = nbase + c;
        tile[r][c] = (n < FFNN_DIM) ? w1[(size_t)(row0 + kbase + r) * FFNN_DIM + n] : 0.f;
    }
    __syncthreads();
    int kl = t & 63;
    for (int rr = 0; rr < 64; rr += 4) {
        int nl = rr + r0;
        store_split2(q0, q1, (size_t)(n2base + nl) * HIDDEN + kbase + kl, tile[kl][nl]);
    }
}

// ---------------- w2 convert+transpose via LDS tiles: m_w2[1000][1000] -> [1024][1024] ---
__global__ __launch_bounds__(256) void convert_wt(const float* __restrict__ w,
                                                  unsigned short* __restrict__ q0,
                                                  unsigned short* __restrict__ q1) {
    __shared__ float tile[64][65];
    int kbase = blockIdx.x << 6;            // 16 tiles over 1024
    int nbase = blockIdx.y << 6;            // 16 tiles over 1024
    int t = threadIdx.x;
    int c = t & 63, r0 = t >> 6;
    for (int rr = 0; rr < 64; rr += 4) {
        int r = rr + r0;
        int k = kbase + r, n = nbase + c;
        tile[r][c] = (k < FFNN_DIM && n < FFNN_DIM) ? w[(size_t)k * FFNN_DIM + n] : 0.f;
    }
    __syncthreads();
    int kl = t & 63;
    for (int rr = 0; rr < 64; rr += 4) {
        int nl = rr + r0;
        store_split2(q0, q1, (size_t)(nbase + nl) * KP2 + kbase + kl, tile[kl][nl]);
    }
}

// ---------------- T_w[wid][1024] = span_width_emb[wid] @ m_w1[1536:1556] ----------------
__global__ void tw_kernel(const float* __restrict__ swe, const float* __restrict__ w1,
                          float* __restrict__ tw) {
    int wid = blockIdx.x, t = threadIdx.x;
    for (int n = t; n < NP; n += 256) {
        float acc = 0.f;
        if (n < FFNN_DIM) {
            for (int f = 0; f < FEAT; ++f)
                acc += swe[wid * FEAT + f] * w1[(size_t)(1536 + f) * FFNN_DIM + n];
        }
        tw[wid * NP + n] = acc;
    }
}

// Stage one 128x32-bf16 tile (8KB) async into LDS with XOR swizzle.
__device__ __forceinline__ void stage_tile(const unsigned short* __restrict__ src,
                                           unsigned short* lds, int base_row, int Kp, int k0,
                                           int t) {
#pragma unroll
    for (int qi = 0; qi < 2; ++qi) {
        int u = qi * 256 + t;
        int l = u & 63;
        int row = ((u >> 6) << 4) + (l >> 2);
        int cblk = (l & 3) ^ (row & 3);
        const unsigned short* g = src + (size_t)(base_row + row) * Kp + k0 + cblk * 8;
        gl_lds16(g, lds + u * 8);
    }
}

// ---------------- 2-split 3-product MFMA GEMM, fp32 out: P = doc @ [W_s|W_e|W_a] ---------
__global__ __launch_bounds__(256, 2) void gemm3p(
    const unsigned short* __restrict__ A0, const unsigned short* __restrict__ A1,
    const unsigned short* __restrict__ B0, const unsigned short* __restrict__ B1,
    float* __restrict__ C) {
    __shared__ unsigned short As0[128 * 32], As1[128 * 32];
    __shared__ unsigned short Bs0[128 * 32], Bs1[128 * 32];
    int t = threadIdx.x;
    int bid = blockIdx.x;
    int bm = (bid & 15) << 7;
    int bn = (bid >> 4) << 7;
    int lane = t & 63, wv = t >> 6;
    int wm = (wv >> 1) * 64, wn = (wv & 1) * 64;
    int lr = lane & 15, qq = lane >> 4;
    int sw = (qq ^ (lr & 3)) * 8;

    f32x4 acc[4][4] = {};

    for (int k0 = 0; k0 < HIDDEN; k0 += 32) {
        stage_tile(A0, As0, bm, HIDDEN, k0, t);
        stage_tile(A1, As1, bm, HIDDEN, k0, t);
        stage_tile(B0, Bs0, bn, HIDDEN, k0, t);
        stage_tile(B1, Bs1, bn, HIDDEN, k0, t);
        __syncthreads();
        short8 a0[4], a1[4];
#pragma unroll
        for (int i = 0; i < 4; ++i) {
            int ra = (wm + i * 16 + lr) * 32 + sw;
            a0[i] = *(const short8*)&As0[ra];
            a1[i] = *(const short8*)&As1[ra];
        }
#pragma unroll
        for (int j = 0; j < 4; ++j) {
            int rb = (wn + j * 16 + lr) * 32 + sw;
            short8 b0 = *(const short8*)&Bs0[rb];
            short8 b1 = *(const short8*)&Bs1[rb];
#pragma unroll
            for (int i = 0; i < 4; ++i) {
                acc[i][j] = __builtin_amdgcn_mfma_f32_16x16x32_bf16(a1[i], b0, acc[i][j], 0, 0, 0);
                acc[i][j] = __builtin_amdgcn_mfma_f32_16x16x32_bf16(a0[i], b1, acc[i][j], 0, 0, 0);
                acc[i][j] = __builtin_amdgcn_mfma_f32_16x16x32_bf16(a0[i], b0, acc[i][j], 0, 0, 0);
            }
        }
        __syncthreads();
    }
#pragma unroll
    for (int i = 0; i < 4; ++i)
#pragma unroll
        for (int j = 0; j < 4; ++j)
#pragma unroll
            for (int r = 0; r < 4; ++r) {
                int m = bm + wm + i * 16 + qq * 4 + r;
                int n = bn + wn + j * 16 + lr;
                C[(size_t)m * PNP + n] = acc[i][j][r];
            }
}

// ---------------- combine: h1[c] = relu(P_s[s] + P_e[e] + sum attn*P_a[s+w] + Tw + b1) ----
// r22: blocks process candidates in start-sorted order with XCD chunking: block b ->
// perm[(b&7)*1024 + (b>>3)] so each XCD's L2 sees a contiguous ~256-start range of P
// rows (~3.4MB, fits 4MB L2). Per-candidate arithmetic + write location unchanged.
__global__ void combine_kernel(const float* __restrict__ P, const float* __restrict__ tw,
                               const float* __restrict__ attn_g, const float* __restrict__ b1,
                               const int* __restrict__ starts, const int* __restrict__ ends,
                               const int* __restrict__ perm,
                               unsigned short* __restrict__ h0, unsigned short* __restrict__ h1) {
    int pos = ((blockIdx.x & 7) << 10) | (blockIdx.x >> 3);
    int c = perm[pos];
    int t = threadIdx.x;
    int s = starts[c], e = ends[c];
    int wid = e - s;
    __shared__ float at[MSW];
    if (t < MSW) at[t] = attn_g[c * 32 + t];
    __syncthreads();
    int n0 = t * 4;
    size_t ho = (size_t)c * NP + n0;
    if (t < 250) {
        f32x4 acc = *(const f32x4*)&P[(size_t)s * PNP + n0];
        acc += *(const f32x4*)&P[(size_t)e * PNP + 1024 + n0];
        acc += *(const f32x4*)&tw[(size_t)wid * NP + n0];
        acc += *(const f32x4*)&b1[n0];
        const float* Pa = P + (size_t)s * PNP + 2048 + n0;
        for (int w = 0; w <= wid; ++w)
            acc += at[w] * *(const f32x4*)&Pa[(size_t)w * PNP];
        u16x4 q0, q1;
#pragma unroll
        for (int k = 0; k < 4; ++k) {
            float v = fmaxf(acc[k], 0.f);
            unsigned short x0 = bf16_rne(v);
            float r1 = v - bf16_to_f(x0);
            q0[k] = x0; q1[k] = bf16_rne(r1);
        }
        *(u16x4*)&h0[ho] = q0;
        *(u16x4*)&h1[ho] = q1;
    } else {
        u16x4 z = {0, 0, 0, 0};
        *(u16x4*)&h0[ho] = z;
        *(u16x4*)&h1[ho] = z;
    }
}

// ---------------- 2-split 3-product MFMA GEMM (score fusion) ------------
__global__ __launch_bounds__(256, 2) void gemm3(
    const unsigned short* __restrict__ A0, const unsigned short* __restrict__ A1,
    const unsigned short* __restrict__ B0, const unsigned short* __restrict__ B1,
    const float* __restrict__ bias, int nreal, int Kp,
    const float* __restrict__ w3, float* __restrict__ partials) {
    __shared__ unsigned short As0[128 * 32], As1[128 * 32];
    __shared__ unsigned short Bs0[128 * 32], Bs1[128 * 32];
    int t = threadIdx.x;
    int bid = blockIdx.x;
    int sm = bid >> 6, idx = bid & 63;
    int bm = ((sm << 3) + (idx & 7)) << 7;
    int bn = (idx >> 3) << 7;
    int lane = t & 63, wv = t >> 6;
    int wm = (wv >> 1) * 64, wn = (wv & 1) * 64;
    int lr = lane & 15, qq = lane >> 4;
    int sw = (qq ^ (lr & 3)) * 8;

    f32x4 acc[4][4] = {};

    for (int k0 = 0; k0 < Kp; k0 += 32) {
        stage_tile(A0, As0, bm, Kp, k0, t);
        stage_tile(A1, As1, bm, Kp, k0, t);
        stage_tile(B0, Bs0, bn, Kp, k0, t);
        stage_tile(B1, Bs1, bn, Kp, k0, t);
        __syncthreads();
        short8 a0[4], a1[4];
#pragma unroll
        for (int i = 0; i < 4; ++i) {
            int ra = (wm + i * 16 + lr) * 32 + sw;
            a0[i] = *(const short8*)&As0[ra];
            a1[i] = *(const short8*)&As1[ra];
        }
#pragma unroll
        for (int j = 0; j < 4; ++j) {
            int rb = (wn + j * 16 + lr) * 32 + sw;
            short8 b0 = *(const short8*)&Bs0[rb];
            short8 b1 = *(const short8*)&Bs1[rb];
#pragma unroll
            for (int i = 0; i < 4; ++i) {
                acc[i][j] = __builtin_amdgcn_mfma_f32_16x16x32_bf16(a1[i], b0, acc[i][j], 0, 0, 0);
                acc[i][j] = __builtin_amdgcn_mfma_f32_16x16x32_bf16(a0[i], b1, acc[i][j], 0, 0, 0);
                acc[i][j] = __builtin_amdgcn_mfma_f32_16x16x32_bf16(a0[i], b0, acc[i][j], 0, 0, 0);
            }
        }
        __syncthreads();
    }

    int pid = ((bn >> 7) << 1) | (wn >> 6);  // 0..15
#pragma unroll
    for (int i = 0; i < 4; ++i)
#pragma unroll
        for (int r = 0; r < 4; ++r) {
            float p = 0.f;
#pragma unroll
            for (int j = 0; j < 4; ++j) {
                int n = bn + wn + j * 16 + lr;
                float v = acc[i][j][r] + (n < nreal ? bias[n] : 0.f);
                v = fmaxf(v, 0.f);
                p += v * (n < nreal ? w3[n] : 0.f);
            }
            p += __shfl_xor(p, 1);
            p += __shfl_xor(p, 2);
            p += __shfl_xor(p, 4);
            p += __shfl_xor(p, 8);
            if (lr == 0) {
                int m = bm + wm + i * 16 + qq * 4 + r;
                partials[(size_t)m * 16 + pid] = p;
            }
        }
}

// ---------------- deterministic score finalize ----------------
__global__ void score_final(const float* __restrict__ partials, const float* __restrict__ b3,
                            const float* __restrict__ width_s, const int* __restrict__ starts,
                            const int* __restrict__ ends, float* __restrict__ out) {
    int c = blockIdx.x * 256 + threadIdx.x;
    if (c >= NUM_CAND) return;
    float s = b3[0] + width_s[ends[c] - starts[c]];
#pragma unroll
    for (int p = 0; p < 16; ++p) s += partials[(size_t)c * 16 + p];
    out[c] = s;
}

// ---------------- exact counting rank-sort: 256 blocks ----------------
__global__ __launch_bounds__(256) void rank_kernel(const float* __restrict__ scores,
                                                   const int* __restrict__ starts,
                                                   const int* __restrict__ ends,
                                                   unsigned short* __restrict__ ord_g,
                                                   unsigned int* __restrict__ se_g) {
    __shared__ unsigned long long kk[NUM_CAND];  // 64 KB
    int t = threadIdx.x;
    for (int i = t; i < NUM_CAND; i += 256) {
        unsigned int b = __float_as_uint(scores[i]);
        unsigned int u = b ^ ((b & 0x80000000u) ? 0xFFFFFFFFu : 0x80000000u);
        unsigned int hi = ~u;
        kk[i] = ((unsigned long long)hi << 32) | (unsigned int)i;
    }
    __syncthreads();
    int c = blockIdx.x * 32 + (t >> 3);
    int seg = (t & 7) * 1024;
    unsigned long long mykey = kk[c];
    int cnt = 0;
    for (int i = seg; i < seg + 1024; ++i) cnt += (kk[i] < mykey) ? 1 : 0;
    cnt += __shfl_xor(cnt, 1);
    cnt += __shfl_xor(cnt, 2);
    cnt += __shfl_xor(cnt, 4);
    if ((t & 7) == 0) {
        int idx = (int)(mykey & 0xFFFFFFFFull);
        int rank = cnt;
        ord_g[rank] = (unsigned short)idx;
        se_g[rank] = ((unsigned int)starts[idx] << 16) | (unsigned int)ends[idx];
    }
}

// ---------------- single-wave greedy crossing-NMS ----------------
// LOCKED at the r17-verified form (292us). Evidence: r13 8-wave=313, r15 flag=401,
// r18 pipelined=374, r19 fixpoint=356, r20 clock-hold spinners=350 (DVFS falsified —
// busy CUs didn't speed the wave; the cost is dependent-chain latency, structural).
// Every added instruction costs ~8 cycles wall; only LESS work helps, and this is the
// least-work form found. Do not restructure further.
__global__ __launch_bounds__(64, 1)
void select_nms(const unsigned int* __restrict__ se_g,
                unsigned short* __restrict__ sel_g,
                int* __restrict__ count_g) {
    __shared__ unsigned int se_arr[NUM_CAND];   // 32 KB
    __shared__ unsigned int st[2 * NUM_WORDS];  // 16 KB
    int lane = threadIdx.x;

    {
        const uint4* src4 = (const uint4*)se_g;
        uint4* dst4 = (uint4*)se_arr;
        for (int i = lane; i < NUM_CAND / 4; i += 64) dst4[i] = src4[i];
    }
    for (int i = lane; i < 2 * NUM_WORDS; i += 64)
        st[i] = (i & 1) ? (unsigned int)NUM_WORDS : 0u;  // max_end+1=0, min_start=2048
    __syncthreads();

    const unsigned long long* stp = (const unsigned long long*)st;
    int count = 0;
    for (int c = 0; c < NUM_CAND / 64; ++c) {
        int ib = c * 64;
        unsigned int sev = se_arr[ib + lane];
        int s = (int)(sev >> 16), e = (int)(sev & 0xFFFFu);
        // snapshot: by program order this wave's own st atomics from all previous chunks
        // are visible (per-wave DS ops are in-order).
        const unsigned long long* bp = stp + s;
        unsigned long long v[MSW];
#pragma unroll
        for (int w = 0; w < MSW; ++w) v[w] = bp[w];
        int me = (int)(unsigned int)v[0] - 1;
        bool crossedA = (s < e) && ((int)(unsigned int)(v[0] >> 32) < s);
        bool crossedB = false;
#pragma unroll
        for (int w = 1; w < MSW; ++w) {
            int j = s + w;
            bool in = (j <= e);
            int mej = (int)(unsigned int)v[w] - 1;
            int msj = (int)(unsigned int)(v[w] >> 32);
            bool hit = in && ((mej > e) || ((j < e) && (msj < s)));
            if (w & 1) crossedA = crossedA || hit;
            else       crossedB = crossedB || hit;
        }
        bool crossed = crossedA || crossedB;
        bool spec = !crossed && (me != e);

        // serial resolve — decision loop identical to the r2..r17-verified form
        int cbefore = count;
        unsigned long long window = ~0ull;
        unsigned int pend = 0u;
        int rk = 0, lcnt = 0;
        while (true) {
            unsigned long long b = __ballot(spec) & window;
            if (b == 0ull) break;
            int f = __ffsll((unsigned long long)b) - 1;
            unsigned int sef = __builtin_amdgcn_readlane(sev, (unsigned int)f);
            int sf = (int)(sef >> 16), ef = (int)(sef & 0xFFFFu);
            bool mine = (lane == lcnt);
            pend = mine ? sef : pend;
            rk = mine ? (ib + f) : rk;
            lcnt++;
            count++;
            if (count >= TOP_NUM) break;
            window &= (f >= 63) ? 0ull : (~0ull << (f + 1));
            if (lane > f) {
                if (s == sf) me = max(me, ef);
                crossed = crossed || ((s < sf) && (sf <= e) && (ef > e))
                                  || ((sf < s) && (s <= ef) && (ef < e));
                spec = !crossed && (me != e);
            }
        }
        if (lane < lcnt) {
            int sf = (int)(pend >> 16), ef = (int)(pend & 0xFFFFu);
            sel_g[cbefore + lane] = (unsigned short)rk;
            atomicMax(&st[2 * sf], (unsigned int)(ef + 1));
            atomicMin(&st[2 * ef + 1], (unsigned int)sf);
        }
        if (count >= TOP_NUM) break;
    }
    if (lane == 0) *count_g = count;
}

// ---------------- post: final span-order sort + emit ----------------
__global__ __launch_bounds__(256) void select_post(const float* __restrict__ scores,
                                                   const int* __restrict__ starts,
                                                   const int* __restrict__ ends,
                                                   const unsigned short* __restrict__ ord_g,
                                                   const unsigned short* __restrict__ sel_g,
                                                   const int* __restrict__ count_g,
                                                   float* out, int* top_idx_ws) {
    __shared__ unsigned long long fkeys[1024];
    int t = threadIdx.x;
    int count = *count_g;
    for (int i = t; i < 1024; i += 256) {
        unsigned long long k = 0xFFFFFFFFFFFFFFFFull;
        if (i < count) {
            int idx = (int)ord_g[sel_g[i]];
            unsigned int key32 = (unsigned int)(starts[idx] * NUM_WORDS + ends[idx]);
            k = ((unsigned long long)key32 << 32) | (unsigned int)idx;
        }
        fkeys[i] = k;
    }
    __syncthreads();
    for (int size = 2; size <= 1024; size <<= 1) {
        for (int stride = size >> 1; stride > 0; stride >>= 1) {
            for (int i = t; i < 1024; i += 256) {
                int ixj = i ^ stride;
                if (ixj > i) {
                    bool up = ((i & size) == 0);
                    unsigned long long a = fkeys[i], b = fkeys[ixj];
                    if ((a > b) == up) { fkeys[i] = b; fkeys[ixj] = a; }
                }
            }
            __syncthreads();
        }
    }
    for (int i = t; i < TOP_NUM; i += 256) {
        int fi = (i < count) ? (int)(fkeys[i] & 0xFFFFFFFFull)
                             : (int)(fkeys[0] & 0xFFFFFFFFull);
        out[OUT_TOPIDX + i] = (float)fi;
        out[OUT_TSTART + i] = (float)starts[fi];
        out[OUT_TEND + i] = (float)ends[fi];
        out[OUT_TSCORE + i] = scores[fi];
        top_idx_ws[i] = fi;
    }
}

// ---------------- gather top_span_emb rows directly from doc (exact fp32) ----------------
__global__ void gather_emb(const float* __restrict__ doc, const float* __restrict__ swe,
                           const float* __restrict__ attn_g, const int* __restrict__ starts,
                           const int* __restrict__ ends, const int* __restrict__ top_idx_ws,
                           float* __restrict__ out) {
    int r = blockIdx.x, t = threadIdx.x;
    int idx = top_idx_ws[r];
    int s = starts[idx], e = ends[idx];
    int wid = e - s;
    __shared__ float at[MSW];
    if (t < MSW) at[t] = attn_g[(size_t)idx * 32 + t];
    __syncthreads();
    float* dst = out + OUT_TEMB + (size_t)r * SPAN_DIM;
    if (t < 192) {
        int h4 = t * 4;
        f32x4 vs = *(const f32x4*)&doc[(size_t)s * HIDDEN + h4];
        f32x4 ve = *(const f32x4*)&doc[(size_t)e * HIDDEN + h4];
        f32x4 acc = {0.f, 0.f, 0.f, 0.f};
        for (int w = 0; w <= wid; ++w)
            acc += at[w] * *(const f32x4*)&doc[(size_t)(s + w) * HIDDEN + h4];
#pragma unroll
        for (int k = 0; k < 4; ++k) {
            dst[h4 + k] = vs[k];
            dst[HIDDEN + h4 + k] = ve[k];
            dst[2 * HIDDEN + FEAT + h4 + k] = acc[k];
        }
    }
    if (t < FEAT) dst[2 * HIDDEN + t] = swe[wid * FEAT + t];
}

extern "C" void kernel_launch(void* const* d_in, const int* in_sizes, int n_in,
                              void* d_out, int out_size, void* d_ws, size_t ws_size,
                              hipStream_t stream) {
    const float* mention_doc = (const float*)d_in[0];
    const float* span_width_emb = (const float*)d_in[1];
    const float* head_w = (const float*)d_in[2];
    const float* head_b = (const float*)d_in[3];
    const float* m_w1 = (const float*)d_in[4];
    const float* m_b1 = (const float*)d_in[5];
    const float* m_w2 = (const float*)d_in[6];
    const float* m_b2 = (const float*)d_in[7];
    const float* m_w3 = (const float*)d_in[8];
    const float* m_b3 = (const float*)d_in[9];
    const float* width_prior_emb = (const float*)d_in[10];
    const float* w_w1 = (const float*)d_in[11];
    const float* w_b1 = (const float*)d_in[12];
    const float* w_w2 = (const float*)d_in[13];
    const float* w_b2 = (const float*)d_in[14];
    const float* w_w3 = (const float*)d_in[15];
    const float* w_b3 = (const float*)d_in[16];
    const int* cand_starts = (const int*)d_in[17];
    const int* cand_ends = (const int*)d_in[18];

    char* w = (char*)d_ws;
    const size_t szH = (size_t)NUM_CAND * NP * 2;
    const size_t szW2 = (size_t)NP * KP2 * 2;
    const size_t szWc = (size_t)PNP * HIDDEN * 2;
    const size_t szD = (size_t)NUM_WORDS * HIDDEN * 2;
    char* p = w;
    unsigned short* h0 = (unsigned short*)p; p += szH;
    unsigned short* h1 = (unsigned short*)p; p += szH;
    unsigned short* w2t0 = (unsigned short*)p; p += szW2;
    unsigned short* w2t1 = (unsigned short*)p; p += szW2;
    unsigned short* Wc0 = (unsigned short*)p; p += szWc;
    unsigned short* Wc1 = (unsigned short*)p; p += szWc;
    unsigned short* d0 = (unsigned short*)p; p += szD;
    unsigned short* d1 = (unsigned short*)p; p += szD;
    float* P = (float*)p; p += (size_t)NUM_WORDS * PNP * 4;
    float* tw = (float*)p; p += (size_t)MSW * NP * 4;
    float* attn_g = (float*)p; p += (size_t)NUM_CAND * 32 * 4;
    float* partials = (float*)p; p += (size_t)NUM_CAND * 16 * 4;
    unsigned short* ord_g = (unsigned short*)p; p += (size_t)NUM_CAND * 2;
    unsigned int* se_g = (unsigned int*)p; p += (size_t)NUM_CAND * 4;
    unsigned short* sel_g = (unsigned short*)p; p += 2048;
    int* count_g = (int*)p; p += 128;
    float* head_s = (float*)p; p += NUM_WORDS * 4;
    float* width_s = (float*)p; p += 128;
    int* top_idx_ws = (int*)p; p += 4096;
    int* hist_g = (int*)p; p += NUM_WORDS * 4;
    int* perm_g = (int*)p; p += (size_t)NUM_CAND * 4;

    size_t need = (size_t)(p - w);
    if (ws_size < need) {
        fprintf(stderr, "kernel_launch: ws too small (%zu < %zu)\n", ws_size, need);
    }

    float* out = (float*)d_out;

    head_kernel<<<NUM_WORDS / 4, 256, 0, stream>>>(mention_doc, head_w, head_b, head_s,
                                                   hist_g);
    width_kernel<<<MSW, 256, 0, stream>>>(width_prior_emb, w_w1, w_b1, w_w2, w_b2, w_w3, w_b3,
                                          width_s);
    attn_kernel<<<NUM_CAND / 4, 256, 0, stream>>>(head_s, cand_starts, cand_ends, attn_g,
                                                  hist_g);
    doc_convert<<<(NUM_WORDS * HIDDEN + 255) / 256, 256, 0, stream>>>(mention_doc, d0, d1);
    convert_wc<<<dim3(12, 48), 256, 0, stream>>>(m_w1, Wc0, Wc1);
    convert_wt<<<dim3(16, 16), 256, 0, stream>>>(m_w2, w2t0, w2t1);
    tw_kernel<<<MSW, 256, 0, stream>>>(span_width_emb, m_w1, tw);
    perm_kernel<<<1, 256, 0, stream>>>(hist_g, cand_starts, perm_g);
    gemm3p<<<16 * 24, 256, 0, stream>>>(d0, d1, Wc0, Wc1, P);
    combine_kernel<<<NUM_CAND, 256, 0, stream>>>(P, tw, attn_g, m_b1, cand_starts, cand_ends,
                                                 perm_g, h0, h1);
    gemm3<<<512, 256, 0, stream>>>(h0, h1, w2t0, w2t1, m_b2, FFNN_DIM, KP2,
                                   m_w3, partials);
    score_final<<<NUM_CAND / 256, 256, 0, stream>>>(partials, m_b3, width_s, cand_starts,
                                                    cand_ends, out);
    rank_kernel<<<NUM_CAND / 32, 256, 0, stream>>>(out, cand_starts, cand_ends, ord_g, se_g);
    select_nms<<<1, 64, 0, stream>>>(se_g, sel_g, count_g);
    select_post<<<1, 256, 0, stream>>>(out, cand_starts, cand_ends, ord_g, sel_g, count_g,
                                       out, top_idx_ws);
    gather_emb<<<TOP_NUM, 256, 0, stream>>>(mention_doc, span_width_emb, attn_g, cand_starts,
                                            cand_ends, top_idx_ws, out);
}

// Round 9
// 766.650 us; speedup vs baseline: 1.2323x; 1.0342x over previous
//
#include <hip/hip_runtime.h>
#include <cstdio>
#include <cmath>

#define NUM_WORDS 2048
#define NUM_CAND 8192
#define HIDDEN 768
#define FEAT 20
#define FFNN_DIM 1000
#define SPAN_DIM 2324
#define TOP_NUM 819
#define MSW 30
#define KP2 1024   // FFNN padded to x32
#define NP 1024    // padded N
#define PNP 3072   // P matrix padded N (3 segments of 1024)

// d_out layout (floats): [scores 8192][top_idx 819][top_starts 819][top_ends 819]
//                        [top_span_emb 819*2324][top_scores 819]
#define OUT_TOPIDX   (NUM_CAND)
#define OUT_TSTART   (NUM_CAND + TOP_NUM)
#define OUT_TEND     (NUM_CAND + 2*TOP_NUM)
#define OUT_TEMB     (NUM_CAND + 3*TOP_NUM)
#define OUT_TSCORE   (NUM_CAND + 3*TOP_NUM + TOP_NUM*SPAN_DIM)

typedef short short8 __attribute__((ext_vector_type(8)));
typedef float f32x4 __attribute__((ext_vector_type(4)));
typedef unsigned short u16x4 __attribute__((ext_vector_type(4)));

__device__ __forceinline__ unsigned short bf16_rne(float x) {
    unsigned int u = __float_as_uint(x);
    unsigned int r = u + 0x7FFFu + ((u >> 16) & 1u);
    return (unsigned short)(r >> 16);
}
__device__ __forceinline__ float bf16_to_f(unsigned short h) {
    return __uint_as_float(((unsigned int)h) << 16);
}
// 2-way split: v = s0 + s1 + r, |r| <= 2^-16 |v| (r21-verified: absmax unchanged)
__device__ __forceinline__ void store_split2(unsigned short* p0, unsigned short* p1,
                                             size_t off, float v) {
    unsigned short h0 = bf16_rne(v);
    float r1 = v - bf16_to_f(h0);
    p0[off] = h0;
    p1[off] = bf16_rne(r1);
}

// async 16B global->LDS (gfx950 global_load_lds_dwordx4). LDS dest must be
// wave-uniform base + lane*16 -> staging tiles are UNPADDED (128x32 bf16, 64B rows),
// bank conflicts handled by XOR swizzle: kblk stored at kblk^(row&3).
__device__ __forceinline__ void gl_lds16(const unsigned short* g, unsigned short* l) {
    __builtin_amdgcn_global_load_lds(
        (const __attribute__((address_space(1))) unsigned short*)g,
        (__attribute__((address_space(3))) unsigned short*)l, 16, 0, 0);
}

// ---------------- head scores + doc 2-split convert (r23 fusion) ----------------
// Block handles 4 doc rows: head reduction per wave + split-convert of the same rows
// (values L1/L2-hot). Block 0 also zeroes the start-histogram for attn_kernel.
__global__ void head_kernel(const float* __restrict__ doc, const float* __restrict__ hw,
                            const float* __restrict__ hb, float* __restrict__ out,
                            int* __restrict__ hist,
                            unsigned short* __restrict__ d0, unsigned short* __restrict__ d1) {
    int t = threadIdx.x;
    if (blockIdx.x == 0) {
        for (int i = t; i < NUM_WORDS; i += 256) hist[i] = 0;
    }
    int base = blockIdx.x * 4 * HIDDEN;
    for (int i = t; i < 4 * HIDDEN; i += 256)
        store_split2(d0, d1, (size_t)base + i, doc[base + i]);
    int wave = t >> 6, lane = t & 63;
    int row = blockIdx.x * 4 + wave;
    if (row >= NUM_WORDS) return;
    float acc = 0.f;
    for (int h = lane; h < HIDDEN; h += 64) acc += doc[row * HIDDEN + h] * hw[h];
    for (int off = 32; off > 0; off >>= 1) acc += __shfl_down(acc, off);
    if (lane == 0) out[row] = acc + hb[0];
}

// ---------------- width prior ffnn [30,20]->[30] + T_w rows (r23 fusion) ----------------
__global__ void width_kernel(const float* __restrict__ x, const float* __restrict__ w1,
                             const float* __restrict__ b1, const float* __restrict__ w2,
                             const float* __restrict__ b2, const float* __restrict__ w3,
                             const float* __restrict__ b3, float* __restrict__ out,
                             const float* __restrict__ swe, const float* __restrict__ mw1,
                             float* __restrict__ tw) {
    __shared__ float xs[FEAT];
    __shared__ float h1s[FFNN_DIM];
    __shared__ float red[256];
    int r = blockIdx.x, t = threadIdx.x;
    if (t < FEAT) xs[t] = x[r * FEAT + t];
    __syncthreads();
    for (int j = t; j < FFNN_DIM; j += 256) {
        float acc = b1[j];
        for (int k = 0; k < FEAT; ++k) acc += xs[k] * w1[k * FFNN_DIM + j];
        h1s[j] = fmaxf(acc, 0.f);
    }
    __syncthreads();
    float partial = 0.f;
    for (int j = t; j < FFNN_DIM; j += 256) {
        float acc = b2[j];
        for (int k = 0; k < FFNN_DIM; ++k) acc += h1s[k] * w2[k * FFNN_DIM + j];
        partial += fmaxf(acc, 0.f) * w3[j];
    }
    red[t] = partial;
    __syncthreads();
    for (int s = 128; s > 0; s >>= 1) { if (t < s) red[t] += red[t + s]; __syncthreads(); }
    if (t == 0) out[r] = red[0] + b3[0];
    // T_w[r][1024] = span_width_emb[r] @ m_w1[1536:1556] (bit-identical to old tw_kernel)
    for (int n = t; n < NP; n += 256) {
        float acc = 0.f;
        if (n < FFNN_DIM) {
            for (int f = 0; f < FEAT; ++f)
                acc += swe[r * FEAT + f] * mw1[(size_t)(1536 + f) * FFNN_DIM + n];
        }
        tw[r * NP + n] = acc;
    }
}

// ---------------- attention weights per span: attn_g [8192][32] ----------------
// r22: also builds the start-histogram (one atomicAdd per candidate; counts deterministic).
__global__ void attn_kernel(const float* __restrict__ head_s, const int* __restrict__ starts,
                            const int* __restrict__ ends, float* __restrict__ attn_g,
                            int* __restrict__ hist) {
    int wave = threadIdx.x >> 6, w = threadIdx.x & 63;
    int c = blockIdx.x * 4 + wave;
    if (c >= NUM_CAND) return;
    int s = starts[c], e = ends[c];
    if (w == 0) atomicAdd(&hist[s], 1);
    int wid = e - s;
    float hsv = -INFINITY;
    if (w < MSW && w <= wid) hsv = head_s[s + w];
    float m = hsv;
    for (int off = 32; off > 0; off >>= 1) m = fmaxf(m, __shfl_down(m, off));
    m = __shfl(m, 0);
    float ex = (w < MSW && w <= wid) ? expf(hsv - m) : 0.f;
    float ssum = ex;
    for (int off = 32; off > 0; off >>= 1) ssum += __shfl_down(ssum, off);
    ssum = __shfl(ssum, 0);
    if (w < 32) attn_g[c * 32 + w] = (w < MSW) ? (ex / ssum) : 0.f;
}

// ---------------- counting-sort permutation by start (scan + scatter, 1 block) ----------
// Order within a start-bin is atomic-timing-dependent, but ANY permutation is correct:
// combine writes h[c] by original candidate id with identical per-candidate arithmetic.
__global__ __launch_bounds__(256) void perm_kernel(const int* __restrict__ hist,
                                                   const int* __restrict__ starts,
                                                   int* __restrict__ perm) {
    __shared__ int hoff[NUM_WORDS];
    __shared__ int wsum[4];
    int t = threadIdx.x, lane = t & 63, wv = t >> 6;
    int base = t * 8;
    int lh[8];
    int s0 = 0;
#pragma unroll
    for (int i = 0; i < 8; ++i) { lh[i] = hist[base + i]; s0 += lh[i]; }
    int sc = s0;
    for (int o = 1; o < 64; o <<= 1) { int v = __shfl_up(sc, o); if (lane >= o) sc += v; }
    if (lane == 63) wsum[wv] = sc;
    __syncthreads();
    int wbase = 0;
    for (int i = 0; i < wv; ++i) wbase += wsum[i];
    int run = wbase + sc - s0;  // exclusive prefix of this thread's 8 bins
#pragma unroll
    for (int i = 0; i < 8; ++i) { hoff[base + i] = run; run += lh[i]; }
    __syncthreads();
    for (int c = t; c < NUM_CAND; c += 256) {
        int pos = atomicAdd(&hoff[starts[c]], 1);
        perm[pos] = c;
    }
}

// ---------------- Wc convert via LDS tile-transpose: coalesced both sides --------------
// seg row bases: 0 -> rows 0..767 (start), 1 -> 768..1535 (end), 2 -> 1556..2323.
__global__ __launch_bounds__(256) void convert_wc(const float* __restrict__ w1,
                                                  unsigned short* __restrict__ q0,
                                                  unsigned short* __restrict__ q1) {
    __shared__ float tile[64][65];
    int kbase = blockIdx.x << 6;            // 0..704 (12 tiles over 768)
    int n2base = blockIdx.y << 6;           // 0..3008 (48 tiles over 3072)
    int seg = n2base >> 10;
    int nbase = n2base & 1023;
    int row0 = (seg == 0) ? 0 : ((seg == 1) ? HIDDEN : 1556);
    int t = threadIdx.x;
    int c = t & 63, r0 = t >> 6;
    for (int rr = 0; rr < 64; rr += 4) {
        int r = rr + r0;
        int n = nbase + c;
        tile[r][c] = (n < FFNN_DIM) ? w1[(size_t)(row0 + kbase + r) * FFNN_DIM + n] : 0.f;
    }
    __syncthreads();
    int kl = t & 63;
    for (int rr = 0; rr < 64; rr += 4) {
        int nl = rr + r0;
        store_split2(q0, q1, (size_t)(n2base + nl) * HIDDEN + kbase + kl, tile[kl][nl]);
    }
}

// ---------------- w2 convert+transpose via LDS tiles: m_w2[1000][1000] -> [1024][1024] ---
__global__ __launch_bounds__(256) void convert_wt(const float* __restrict__ w,
                                                  unsigned short* __restrict__ q0,
                                                  unsigned short* __restrict__ q1) {
    __shared__ float tile[64][65];
    int kbase = blockIdx.x << 6;            // 16 tiles over 1024
    int nbase = blockIdx.y << 6;            // 16 tiles over 1024
    int t = threadIdx.x;
    int c = t & 63, r0 = t >> 6;
    for (int rr = 0; rr < 64; rr += 4) {
        int r = rr + r0;
        int k = kbase + r, n = nbase + c;
        tile[r][c] = (k < FFNN_DIM && n < FFNN_DIM) ? w[(size_t)k * FFNN_DIM + n] : 0.f;
    }
    __syncthreads();
    int kl = t & 63;
    for (int rr = 0; rr < 64; rr += 4) {
        int nl = rr + r0;
        store_split2(q0, q1, (size_t)(nbase + nl) * KP2 + kbase + kl, tile[kl][nl]);
    }
}

// Stage one 128x32-bf16 tile (8KB) async into LDS with XOR swizzle.
__device__ __forceinline__ void stage_tile(const unsigned short* __restrict__ src,
                                           unsigned short* lds, int base_row, int Kp, int k0,
                                           int t) {
#pragma unroll
    for (int qi = 0; qi < 2; ++qi) {
        int u = qi * 256 + t;
        int l = u & 63;
        int row = ((u >> 6) << 4) + (l >> 2);
        int cblk = (l & 3) ^ (row & 3);
        const unsigned short* g = src + (size_t)(base_row + row) * Kp + k0 + cblk * 8;
        gl_lds16(g, lds + u * 8);
    }
}

// ---------------- 2-split 3-product MFMA GEMM, fp32 out: P = doc @ [W_s|W_e|W_a] ---------
__global__ __launch_bounds__(256, 2) void gemm3p(
    const unsigned short* __restrict__ A0, const unsigned short* __restrict__ A1,
    const unsigned short* __restrict__ B0, const unsigned short* __restrict__ B1,
    float* __restrict__ C) {
    __shared__ unsigned short As0[128 * 32], As1[128 * 32];
    __shared__ unsigned short Bs0[128 * 32], Bs1[128 * 32];
    int t = threadIdx.x;
    int bid = blockIdx.x;
    int bm = (bid & 15) << 7;
    int bn = (bid >> 4) << 7;
    int lane = t & 63, wv = t >> 6;
    int wm = (wv >> 1) * 64, wn = (wv & 1) * 64;
    int lr = lane & 15, qq = lane >> 4;
    int sw = (qq ^ (lr & 3)) * 8;

    f32x4 acc[4][4] = {};

    for (int k0 = 0; k0 < HIDDEN; k0 += 32) {
        stage_tile(A0, As0, bm, HIDDEN, k0, t);
        stage_tile(A1, As1, bm, HIDDEN, k0, t);
        stage_tile(B0, Bs0, bn, HIDDEN, k0, t);
        stage_tile(B1, Bs1, bn, HIDDEN, k0, t);
        __syncthreads();
        short8 a0[4], a1[4];
#pragma unroll
        for (int i = 0; i < 4; ++i) {
            int ra = (wm + i * 16 + lr) * 32 + sw;
            a0[i] = *(const short8*)&As0[ra];
            a1[i] = *(const short8*)&As1[ra];
        }
#pragma unroll
        for (int j = 0; j < 4; ++j) {
            int rb = (wn + j * 16 + lr) * 32 + sw;
            short8 b0 = *(const short8*)&Bs0[rb];
            short8 b1 = *(const short8*)&Bs1[rb];
#pragma unroll
            for (int i = 0; i < 4; ++i) {
                acc[i][j] = __builtin_amdgcn_mfma_f32_16x16x32_bf16(a1[i], b0, acc[i][j], 0, 0, 0);
                acc[i][j] = __builtin_amdgcn_mfma_f32_16x16x32_bf16(a0[i], b1, acc[i][j], 0, 0, 0);
                acc[i][j] = __builtin_amdgcn_mfma_f32_16x16x32_bf16(a0[i], b0, acc[i][j], 0, 0, 0);
            }
        }
        __syncthreads();
    }
#pragma unroll
    for (int i = 0; i < 4; ++i)
#pragma unroll
        for (int j = 0; j < 4; ++j)
#pragma unroll
            for (int r = 0; r < 4; ++r) {
                int m = bm + wm + i * 16 + qq * 4 + r;
                int n = bn + wn + j * 16 + lr;
                C[(size_t)m * PNP + n] = acc[i][j][r];
            }
}

// ---------------- combine: h1[c] = relu(P_s[s] + P_e[e] + sum attn*P_a[s+w] + Tw + b1) ----
// r22: blocks process candidates in start-sorted order with XCD chunking: block b ->
// perm[(b&7)*1024 + (b>>3)] so each XCD's L2 sees a contiguous ~256-start range of P
// rows (~3.4MB, fits 4MB L2). Per-candidate arithmetic + write location unchanged.
__global__ void combine_kernel(const float* __restrict__ P, const float* __restrict__ tw,
                               const float* __restrict__ attn_g, const float* __restrict__ b1,
                               const int* __restrict__ starts, const int* __restrict__ ends,
                               const int* __restrict__ perm,
                               unsigned short* __restrict__ h0, unsigned short* __restrict__ h1) {
    int pos = ((blockIdx.x & 7) << 10) | (blockIdx.x >> 3);
    int c = perm[pos];
    int t = threadIdx.x;
    int s = starts[c], e = ends[c];
    int wid = e - s;
    __shared__ float at[MSW];
    if (t < MSW) at[t] = attn_g[c * 32 + t];
    __syncthreads();
    int n0 = t * 4;
    size_t ho = (size_t)c * NP + n0;
    if (t < 250) {
        f32x4 acc = *(const f32x4*)&P[(size_t)s * PNP + n0];
        acc += *(const f32x4*)&P[(size_t)e * PNP + 1024 + n0];
        acc += *(const f32x4*)&tw[(size_t)wid * NP + n0];
        acc += *(const f32x4*)&b1[n0];
        const float* Pa = P + (size_t)s * PNP + 2048 + n0;
        for (int w = 0; w <= wid; ++w)
            acc += at[w] * *(const f32x4*)&Pa[(size_t)w * PNP];
        u16x4 q0, q1;
#pragma unroll
        for (int k = 0; k < 4; ++k) {
            float v = fmaxf(acc[k], 0.f);
            unsigned short x0 = bf16_rne(v);
            float r1 = v - bf16_to_f(x0);
            q0[k] = x0; q1[k] = bf16_rne(r1);
        }
        *(u16x4*)&h0[ho] = q0;
        *(u16x4*)&h1[ho] = q1;
    } else {
        u16x4 z = {0, 0, 0, 0};
        *(u16x4*)&h0[ho] = z;
        *(u16x4*)&h1[ho] = z;
    }
}

// ---------------- 2-split 3-product MFMA GEMM (score fusion) ------------
__global__ __launch_bounds__(256, 2) void gemm3(
    const unsigned short* __restrict__ A0, const unsigned short* __restrict__ A1,
    const unsigned short* __restrict__ B0, const unsigned short* __restrict__ B1,
    const float* __restrict__ bias, int nreal, int Kp,
    const float* __restrict__ w3, float* __restrict__ partials) {
    __shared__ unsigned short As0[128 * 32], As1[128 * 32];
    __shared__ unsigned short Bs0[128 * 32], Bs1[128 * 32];
    int t = threadIdx.x;
    int bid = blockIdx.x;
    int sm = bid >> 6, idx = bid & 63;
    int bm = ((sm << 3) + (idx & 7)) << 7;
    int bn = (idx >> 3) << 7;
    int lane = t & 63, wv = t >> 6;
    int wm = (wv >> 1) * 64, wn = (wv & 1) * 64;
    int lr = lane & 15, qq = lane >> 4;
    int sw = (qq ^ (lr & 3)) * 8;

    f32x4 acc[4][4] = {};

    for (int k0 = 0; k0 < Kp; k0 += 32) {
        stage_tile(A0, As0, bm, Kp, k0, t);
        stage_tile(A1, As1, bm, Kp, k0, t);
        stage_tile(B0, Bs0, bn, Kp, k0, t);
        stage_tile(B1, Bs1, bn, Kp, k0, t);
        __syncthreads();
        short8 a0[4], a1[4];
#pragma unroll
        for (int i = 0; i < 4; ++i) {
            int ra = (wm + i * 16 + lr) * 32 + sw;
            a0[i] = *(const short8*)&As0[ra];
            a1[i] = *(const short8*)&As1[ra];
        }
#pragma unroll
        for (int j = 0; j < 4; ++j) {
            int rb = (wn + j * 16 + lr) * 32 + sw;
            short8 b0 = *(const short8*)&Bs0[rb];
            short8 b1 = *(const short8*)&Bs1[rb];
#pragma unroll
            for (int i = 0; i < 4; ++i) {
                acc[i][j] = __builtin_amdgcn_mfma_f32_16x16x32_bf16(a1[i], b0, acc[i][j], 0, 0, 0);
                acc[i][j] = __builtin_amdgcn_mfma_f32_16x16x32_bf16(a0[i], b1, acc[i][j], 0, 0, 0);
                acc[i][j] = __builtin_amdgcn_mfma_f32_16x16x32_bf16(a0[i], b0, acc[i][j], 0, 0, 0);
            }
        }
        __syncthreads();
    }

    int pid = ((bn >> 7) << 1) | (wn >> 6);  // 0..15
#pragma unroll
    for (int i = 0; i < 4; ++i)
#pragma unroll
        for (int r = 0; r < 4; ++r) {
            float p = 0.f;
#pragma unroll
            for (int j = 0; j < 4; ++j) {
                int n = bn + wn + j * 16 + lr;
                float v = acc[i][j][r] + (n < nreal ? bias[n] : 0.f);
                v = fmaxf(v, 0.f);
                p += v * (n < nreal ? w3[n] : 0.f);
            }
            p += __shfl_xor(p, 1);
            p += __shfl_xor(p, 2);
            p += __shfl_xor(p, 4);
            p += __shfl_xor(p, 8);
            if (lr == 0) {
                int m = bm + wm + i * 16 + qq * 4 + r;
                partials[(size_t)m * 16 + pid] = p;
            }
        }
}

// ---------------- deterministic score finalize ----------------
__global__ void score_final(const float* __restrict__ partials, const float* __restrict__ b3,
                            const float* __restrict__ width_s, const int* __restrict__ starts,
                            const int* __restrict__ ends, float* __restrict__ out) {
    int c = blockIdx.x * 256 + threadIdx.x;
    if (c >= NUM_CAND) return;
    float s = b3[0] + width_s[ends[c] - starts[c]];
#pragma unroll
    for (int p = 0; p < 16; ++p) s += partials[(size_t)c * 16 + p];
    out[c] = s;
}

// ---------------- exact counting rank-sort: 256 blocks ----------------
__global__ __launch_bounds__(256) void rank_kernel(const float* __restrict__ scores,
                                                   const int* __restrict__ starts,
                                                   const int* __restrict__ ends,
                                                   unsigned short* __restrict__ ord_g,
                                                   unsigned int* __restrict__ se_g) {
    __shared__ unsigned long long kk[NUM_CAND];  // 64 KB
    int t = threadIdx.x;
    for (int i = t; i < NUM_CAND; i += 256) {
        unsigned int b = __float_as_uint(scores[i]);
        unsigned int u = b ^ ((b & 0x80000000u) ? 0xFFFFFFFFu : 0x80000000u);
        unsigned int hi = ~u;
        kk[i] = ((unsigned long long)hi << 32) | (unsigned int)i;
    }
    __syncthreads();
    int c = blockIdx.x * 32 + (t >> 3);
    int seg = (t & 7) * 1024;
    unsigned long long mykey = kk[c];
    int cnt = 0;
    for (int i = seg; i < seg + 1024; ++i) cnt += (kk[i] < mykey) ? 1 : 0;
    cnt += __shfl_xor(cnt, 1);
    cnt += __shfl_xor(cnt, 2);
    cnt += __shfl_xor(cnt, 4);
    if ((t & 7) == 0) {
        int idx = (int)(mykey & 0xFFFFFFFFull);
        int rank = cnt;
        ord_g[rank] = (unsigned short)idx;
        se_g[rank] = ((unsigned int)starts[idx] << 16) | (unsigned int)ends[idx];
    }
}

// ---------------- single-wave greedy crossing-NMS ----------------
// LOCKED at the r17-verified form (292us). Evidence: r13 8-wave=313, r15 flag=401,
// r18 pipelined=374, r19 fixpoint=356, r20 clock-hold spinners=350 (DVFS falsified —
// busy CUs didn't speed the wave; the cost is dependent-chain latency, structural).
// Every added instruction costs ~8 cycles wall; only LESS work helps, and this is the
// least-work form found. Do not restructure further.
__global__ __launch_bounds__(64, 1)
void select_nms(const unsigned int* __restrict__ se_g,
                unsigned short* __restrict__ sel_g,
                int* __restrict__ count_g) {
    __shared__ unsigned int se_arr[NUM_CAND];   // 32 KB
    __shared__ unsigned int st[2 * NUM_WORDS];  // 16 KB
    int lane = threadIdx.x;

    {
        const uint4* src4 = (const uint4*)se_g;
        uint4* dst4 = (uint4*)se_arr;
        for (int i = lane; i < NUM_CAND / 4; i += 64) dst4[i] = src4[i];
    }
    for (int i = lane; i < 2 * NUM_WORDS; i += 64)
        st[i] = (i & 1) ? (unsigned int)NUM_WORDS : 0u;  // max_end+1=0, min_start=2048
    __syncthreads();

    const unsigned long long* stp = (const unsigned long long*)st;
    int count = 0;
    for (int c = 0; c < NUM_CAND / 64; ++c) {
        int ib = c * 64;
        unsigned int sev = se_arr[ib + lane];
        int s = (int)(sev >> 16), e = (int)(sev & 0xFFFFu);
        // snapshot: by program order this wave's own st atomics from all previous chunks
        // are visible (per-wave DS ops are in-order).
        const unsigned long long* bp = stp + s;
        unsigned long long v[MSW];
#pragma unroll
        for (int w = 0; w < MSW; ++w) v[w] = bp[w];
        int me = (int)(unsigned int)v[0] - 1;
        bool crossedA = (s < e) && ((int)(unsigned int)(v[0] >> 32) < s);
        bool crossedB = false;
#pragma unroll
        for (int w = 1; w < MSW; ++w) {
            int j = s + w;
            bool in = (j <= e);
            int mej = (int)(unsigned int)v[w] - 1;
            int msj = (int)(unsigned int)(v[w] >> 32);
            bool hit = in && ((mej > e) || ((j < e) && (msj < s)));
            if (w & 1) crossedA = crossedA || hit;
            else       crossedB = crossedB || hit;
        }
        bool crossed = crossedA || crossedB;
        bool spec = !crossed && (me != e);

        // serial resolve — decision loop identical to the r2..r17-verified form
        int cbefore = count;
        unsigned long long window = ~0ull;
        unsigned int pend = 0u;
        int rk = 0, lcnt = 0;
        while (true) {
            unsigned long long b = __ballot(spec) & window;
            if (b == 0ull) break;
            int f = __ffsll((unsigned long long)b) - 1;
            unsigned int sef = __builtin_amdgcn_readlane(sev, (unsigned int)f);
            int sf = (int)(sef >> 16), ef = (int)(sef & 0xFFFFu);
            bool mine = (lane == lcnt);
            pend = mine ? sef : pend;
            rk = mine ? (ib + f) : rk;
            lcnt++;
            count++;
            if (count >= TOP_NUM) break;
            window &= (f >= 63) ? 0ull : (~0ull << (f + 1));
            if (lane > f) {
                if (s == sf) me = max(me, ef);
                crossed = crossed || ((s < sf) && (sf <= e) && (ef > e))
                                  || ((sf < s) && (s <= ef) && (ef < e));
                spec = !crossed && (me != e);
            }
        }
        if (lane < lcnt) {
            int sf = (int)(pend >> 16), ef = (int)(pend & 0xFFFFu);
            sel_g[cbefore + lane] = (unsigned short)rk;
            atomicMax(&st[2 * sf], (unsigned int)(ef + 1));
            atomicMin(&st[2 * ef + 1], (unsigned int)sf);
        }
        if (count >= TOP_NUM) break;
    }
    if (lane == 0) *count_g = count;
}

// ---------------- post: final span-order sort + emit (r23: 1024 threads) ----------------
// One thread per element: 4x fewer per-phase iterations on the same 55-barrier network.
// Identical compare-exchange network => bit-identical result.
__global__ __launch_bounds__(1024) void select_post(const float* __restrict__ scores,
                                                    const int* __restrict__ starts,
                                                    const int* __restrict__ ends,
                                                    const unsigned short* __restrict__ ord_g,
                                                    const unsigned short* __restrict__ sel_g,
                                                    const int* __restrict__ count_g,
                                                    float* out, int* top_idx_ws) {
    __shared__ unsigned long long fkeys[1024];
    int t = threadIdx.x;
    int count = *count_g;
    {
        unsigned long long k = 0xFFFFFFFFFFFFFFFFull;
        if (t < count) {
            int idx = (int)ord_g[sel_g[t]];
            unsigned int key32 = (unsigned int)(starts[idx] * NUM_WORDS + ends[idx]);
            k = ((unsigned long long)key32 << 32) | (unsigned int)idx;
        }
        fkeys[t] = k;
    }
    __syncthreads();
    for (int size = 2; size <= 1024; size <<= 1) {
        for (int stride = size >> 1; stride > 0; stride >>= 1) {
            int ixj = t ^ stride;
            if (ixj > t) {
                bool up = ((t & size) == 0);
                unsigned long long a = fkeys[t], b = fkeys[ixj];
                if ((a > b) == up) { fkeys[t] = b; fkeys[ixj] = a; }
            }
            __syncthreads();
        }
    }
    if (t < TOP_NUM) {
        int fi = (t < count) ? (int)(fkeys[t] & 0xFFFFFFFFull)
                             : (int)(fkeys[0] & 0xFFFFFFFFull);
        out[OUT_TOPIDX + t] = (float)fi;
        out[OUT_TSTART + t] = (float)starts[fi];
        out[OUT_TEND + t] = (float)ends[fi];
        out[OUT_TSCORE + t] = scores[fi];
        top_idx_ws[t] = fi;
    }
}

// ---------------- gather top_span_emb rows directly from doc (exact fp32) ----------------
__global__ void gather_emb(const float* __restrict__ doc, const float* __restrict__ swe,
                           const float* __restrict__ attn_g, const int* __restrict__ starts,
                           const int* __restrict__ ends, const int* __restrict__ top_idx_ws,
                           float* __restrict__ out) {
    int r = blockIdx.x, t = threadIdx.x;
    int idx = top_idx_ws[r];
    int s = starts[idx], e = ends[idx];
    int wid = e - s;
    __shared__ float at[MSW];
    if (t < MSW) at[t] = attn_g[(size_t)idx * 32 + t];
    __syncthreads();
    float* dst = out + OUT_TEMB + (size_t)r * SPAN_DIM;
    if (t < 192) {
        int h4 = t * 4;
        f32x4 vs = *(const f32x4*)&doc[(size_t)s * HIDDEN + h4];
        f32x4 ve = *(const f32x4*)&doc[(size_t)e * HIDDEN + h4];
        f32x4 acc = {0.f, 0.f, 0.f, 0.f};
        for (int w = 0; w <= wid; ++w)
            acc += at[w] * *(const f32x4*)&doc[(size_t)(s + w) * HIDDEN + h4];
#pragma unroll
        for (int k = 0; k < 4; ++k) {
            dst[h4 + k] = vs[k];
            dst[HIDDEN + h4 + k] = ve[k];
            dst[2 * HIDDEN + FEAT + h4 + k] = acc[k];
        }
    }
    if (t < FEAT) dst[2 * HIDDEN + t] = swe[wid * FEAT + t];
}

extern "C" void kernel_launch(void* const* d_in, const int* in_sizes, int n_in,
                              void* d_out, int out_size, void* d_ws, size_t ws_size,
                              hipStream_t stream) {
    const float* mention_doc = (const float*)d_in[0];
    const float* span_width_emb = (const float*)d_in[1];
    const float* head_w = (const float*)d_in[2];
    const float* head_b = (const float*)d_in[3];
    const float* m_w1 = (const float*)d_in[4];
    const float* m_b1 = (const float*)d_in[5];
    const float* m_w2 = (const float*)d_in[6];
    const float* m_b2 = (const float*)d_in[7];
    const float* m_w3 = (const float*)d_in[8];
    const float* m_b3 = (const float*)d_in[9];
    const float* width_prior_emb = (const float*)d_in[10];
    const float* w_w1 = (const float*)d_in[11];
    const float* w_b1 = (const float*)d_in[12];
    const float* w_w2 = (const float*)d_in[13];
    const float* w_b2 = (const float*)d_in[14];
    const float* w_w3 = (const float*)d_in[15];
    const float* w_b3 = (const float*)d_in[16];
    const int* cand_starts = (const int*)d_in[17];
    const int* cand_ends = (const int*)d_in[18];

    char* w = (char*)d_ws;
    const size_t szH = (size_t)NUM_CAND * NP * 2;
    const size_t szW2 = (size_t)NP * KP2 * 2;
    const size_t szWc = (size_t)PNP * HIDDEN * 2;
    const size_t szD = (size_t)NUM_WORDS * HIDDEN * 2;
    char* p = w;
    unsigned short* h0 = (unsigned short*)p; p += szH;
    unsigned short* h1 = (unsigned short*)p; p += szH;
    unsigned short* w2t0 = (unsigned short*)p; p += szW2;
    unsigned short* w2t1 = (unsigned short*)p; p += szW2;
    unsigned short* Wc0 = (unsigned short*)p; p += szWc;
    unsigned short* Wc1 = (unsigned short*)p; p += szWc;
    unsigned short* d0 = (unsigned short*)p; p += szD;
    unsigned short* d1 = (unsigned short*)p; p += szD;
    float* P = (float*)p; p += (size_t)NUM_WORDS * PNP * 4;
    float* tw = (float*)p; p += (size_t)MSW * NP * 4;
    float* attn_g = (float*)p; p += (size_t)NUM_CAND * 32 * 4;
    float* partials = (float*)p; p += (size_t)NUM_CAND * 16 * 4;
    unsigned short* ord_g = (unsigned short*)p; p += (size_t)NUM_CAND * 2;
    unsigned int* se_g = (unsigned int*)p; p += (size_t)NUM_CAND * 4;
    unsigned short* sel_g = (unsigned short*)p; p += 2048;
    int* count_g = (int*)p; p += 128;
    float* head_s = (float*)p; p += NUM_WORDS * 4;
    float* width_s = (float*)p; p += 128;
    int* top_idx_ws = (int*)p; p += 4096;
    int* hist_g = (int*)p; p += NUM_WORDS * 4;
    int* perm_g = (int*)p; p += (size_t)NUM_CAND * 4;

    size_t need = (size_t)(p - w);
    if (ws_size < need) {
        fprintf(stderr, "kernel_launch: ws too small (%zu < %zu)\n", ws_size, need);
    }

    float* out = (float*)d_out;

    head_kernel<<<NUM_WORDS / 4, 256, 0, stream>>>(mention_doc, head_w, head_b, head_s,
                                                   hist_g, d0, d1);
    width_kernel<<<MSW, 256, 0, stream>>>(width_prior_emb, w_w1, w_b1, w_w2, w_b2, w_w3, w_b3,
                                          width_s, span_width_emb, m_w1, tw);
    attn_kernel<<<NUM_CAND / 4, 256, 0, stream>>>(head_s, cand_starts, cand_ends, attn_g,
                                                  hist_g);
    convert_wc<<<dim3(12, 48), 256, 0, stream>>>(m_w1, Wc0, Wc1);
    convert_wt<<<dim3(16, 16), 256, 0, stream>>>(m_w2, w2t0, w2t1);
    perm_kernel<<<1, 256, 0, stream>>>(hist_g, cand_starts, perm_g);
    gemm3p<<<16 * 24, 256, 0, stream>>>(d0, d1, Wc0, Wc1, P);
    combine_kernel<<<NUM_CAND, 256, 0, stream>>>(P, tw, attn_g, m_b1, cand_starts, cand_ends,
                                                 perm_g, h0, h1);
    gemm3<<<512, 256, 0, stream>>>(h0, h1, w2t0, w2t1, m_b2, FFNN_DIM, KP2,
                                   m_w3, partials);
    score_final<<<NUM_CAND / 256, 256, 0, stream>>>(partials, m_b3, width_s, cand_starts,
                                                    cand_ends, out);
    rank_kernel<<<NUM_CAND / 32, 256, 0, stream>>>(out, cand_starts, cand_ends, ord_g, se_g);
    select_nms<<<1, 64, 0, stream>>>(se_g, sel_g, count_g);
    select_post<<<1, 1024, 0, stream>>>(out, cand_starts, cand_ends, ord_g, sel_g, count_g,
                                        out, top_idx_ws);
    gather_emb<<<TOP_NUM, 256, 0, stream>>>(mention_doc, span_width_emb, attn_g, cand_starts,
                                            cand_ends, top_idx_ws, out);
}

// Round 10
// 746.840 us; speedup vs baseline: 1.2650x; 1.0265x over previous
//
#include <hip/hip_runtime.h>
#include <cstdio>
#include <cmath>

#define NUM_WORDS 2048
#define NUM_CAND 8192
#define HIDDEN 768
#define FEAT 20
#define FFNN_DIM 1000
#define SPAN_DIM 2324
#define TOP_NUM 819
#define MSW 30
#define KP2 1024   // FFNN padded to x32
#define NP 1024    // padded N
#define PNP 3072   // P matrix padded N (3 segments of 1024)

// d_out layout (floats): [scores 8192][top_idx 819][top_starts 819][top_ends 819]
//                        [top_span_emb 819*2324][top_scores 819]
#define OUT_TOPIDX   (NUM_CAND)
#define OUT_TSTART   (NUM_CAND + TOP_NUM)
#define OUT_TEND     (NUM_CAND + 2*TOP_NUM)
#define OUT_TEMB     (NUM_CAND + 3*TOP_NUM)
#define OUT_TSCORE   (NUM_CAND + 3*TOP_NUM + TOP_NUM*SPAN_DIM)

typedef short short8 __attribute__((ext_vector_type(8)));
typedef float f32x4 __attribute__((ext_vector_type(4)));
typedef unsigned short u16x4 __attribute__((ext_vector_type(4)));

__device__ __forceinline__ unsigned short bf16_rne(float x) {
    unsigned int u = __float_as_uint(x);
    unsigned int r = u + 0x7FFFu + ((u >> 16) & 1u);
    return (unsigned short)(r >> 16);
}
__device__ __forceinline__ float bf16_to_f(unsigned short h) {
    return __uint_as_float(((unsigned int)h) << 16);
}
// 2-way split: v = s0 + s1 + r, |r| <= 2^-16 |v| (r21-verified: absmax unchanged)
__device__ __forceinline__ void store_split2(unsigned short* p0, unsigned short* p1,
                                             size_t off, float v) {
    unsigned short h0 = bf16_rne(v);
    float r1 = v - bf16_to_f(h0);
    p0[off] = h0;
    p1[off] = bf16_rne(r1);
}

// async 16B global->LDS (gfx950 global_load_lds_dwordx4). LDS dest must be
// wave-uniform base + lane*16 -> linear LDS; swizzle applied to the GLOBAL source.
__device__ __forceinline__ void gl_lds16(const unsigned short* g, unsigned short* l) {
    __builtin_amdgcn_global_load_lds(
        (const __attribute__((address_space(1))) unsigned short*)g,
        (__attribute__((address_space(3))) unsigned short*)l, 16, 0, 0);
}

// ---------------- head scores + doc 2-split convert (r23 fusion) ----------------
__global__ void head_kernel(const float* __restrict__ doc, const float* __restrict__ hw,
                            const float* __restrict__ hb, float* __restrict__ out,
                            int* __restrict__ hist,
                            unsigned short* __restrict__ d0, unsigned short* __restrict__ d1) {
    int t = threadIdx.x;
    if (blockIdx.x == 0) {
        for (int i = t; i < NUM_WORDS; i += 256) hist[i] = 0;
    }
    int base = blockIdx.x * 4 * HIDDEN;
    for (int i = t; i < 4 * HIDDEN; i += 256)
        store_split2(d0, d1, (size_t)base + i, doc[base + i]);
    int wave = t >> 6, lane = t & 63;
    int row = blockIdx.x * 4 + wave;
    if (row >= NUM_WORDS) return;
    float acc = 0.f;
    for (int h = lane; h < HIDDEN; h += 64) acc += doc[row * HIDDEN + h] * hw[h];
    for (int off = 32; off > 0; off >>= 1) acc += __shfl_down(acc, off);
    if (lane == 0) out[row] = acc + hb[0];
}

// ---------------- width prior ffnn [30,20]->[30] + T_w rows (r23 fusion) ----------------
__global__ void width_kernel(const float* __restrict__ x, const float* __restrict__ w1,
                             const float* __restrict__ b1, const float* __restrict__ w2,
                             const float* __restrict__ b2, const float* __restrict__ w3,
                             const float* __restrict__ b3, float* __restrict__ out,
                             const float* __restrict__ swe, const float* __restrict__ mw1,
                             float* __restrict__ tw) {
    __shared__ float xs[FEAT];
    __shared__ float h1s[FFNN_DIM];
    __shared__ float red[256];
    int r = blockIdx.x, t = threadIdx.x;
    if (t < FEAT) xs[t] = x[r * FEAT + t];
    __syncthreads();
    for (int j = t; j < FFNN_DIM; j += 256) {
        float acc = b1[j];
        for (int k = 0; k < FEAT; ++k) acc += xs[k] * w1[k * FFNN_DIM + j];
        h1s[j] = fmaxf(acc, 0.f);
    }
    __syncthreads();
    float partial = 0.f;
    for (int j = t; j < FFNN_DIM; j += 256) {
        float acc = b2[j];
        for (int k = 0; k < FFNN_DIM; ++k) acc += h1s[k] * w2[k * FFNN_DIM + j];
        partial += fmaxf(acc, 0.f) * w3[j];
    }
    red[t] = partial;
    __syncthreads();
    for (int s = 128; s > 0; s >>= 1) { if (t < s) red[t] += red[t + s]; __syncthreads(); }
    if (t == 0) out[r] = red[0] + b3[0];
    // T_w[r][1024] = span_width_emb[r] @ m_w1[1536:1556] (bit-identical to old tw_kernel)
    for (int n = t; n < NP; n += 256) {
        float acc = 0.f;
        if (n < FFNN_DIM) {
            for (int f = 0; f < FEAT; ++f)
                acc += swe[r * FEAT + f] * mw1[(size_t)(1536 + f) * FFNN_DIM + n];
        }
        tw[r * NP + n] = acc;
    }
}

// ---------------- attention weights per span: attn_g [8192][32] ----------------
__global__ void attn_kernel(const float* __restrict__ head_s, const int* __restrict__ starts,
                            const int* __restrict__ ends, float* __restrict__ attn_g,
                            int* __restrict__ hist) {
    int wave = threadIdx.x >> 6, w = threadIdx.x & 63;
    int c = blockIdx.x * 4 + wave;
    if (c >= NUM_CAND) return;
    int s = starts[c], e = ends[c];
    if (w == 0) atomicAdd(&hist[s], 1);
    int wid = e - s;
    float hsv = -INFINITY;
    if (w < MSW && w <= wid) hsv = head_s[s + w];
    float m = hsv;
    for (int off = 32; off > 0; off >>= 1) m = fmaxf(m, __shfl_down(m, off));
    m = __shfl(m, 0);
    float ex = (w < MSW && w <= wid) ? expf(hsv - m) : 0.f;
    float ssum = ex;
    for (int off = 32; off > 0; off >>= 1) ssum += __shfl_down(ssum, off);
    ssum = __shfl(ssum, 0);
    if (w < 32) attn_g[c * 32 + w] = (w < MSW) ? (ex / ssum) : 0.f;
}

// ---------------- counting-sort permutation by start (scan + scatter, 1 block) ----------
__global__ __launch_bounds__(256) void perm_kernel(const int* __restrict__ hist,
                                                   const int* __restrict__ starts,
                                                   int* __restrict__ perm) {
    __shared__ int hoff[NUM_WORDS];
    __shared__ int wsum[4];
    int t = threadIdx.x, lane = t & 63, wv = t >> 6;
    int base = t * 8;
    int lh[8];
    int s0 = 0;
#pragma unroll
    for (int i = 0; i < 8; ++i) { lh[i] = hist[base + i]; s0 += lh[i]; }
    int sc = s0;
    for (int o = 1; o < 64; o <<= 1) { int v = __shfl_up(sc, o); if (lane >= o) sc += v; }
    if (lane == 63) wsum[wv] = sc;
    __syncthreads();
    int wbase = 0;
    for (int i = 0; i < wv; ++i) wbase += wsum[i];
    int run = wbase + sc - s0;  // exclusive prefix of this thread's 8 bins
#pragma unroll
    for (int i = 0; i < 8; ++i) { hoff[base + i] = run; run += lh[i]; }
    __syncthreads();
    for (int c = t; c < NUM_CAND; c += 256) {
        int pos = atomicAdd(&hoff[starts[c]], 1);
        perm[pos] = c;
    }
}

// ---------------- Wc convert via LDS tile-transpose: coalesced both sides --------------
__global__ __launch_bounds__(256) void convert_wc(const float* __restrict__ w1,
                                                  unsigned short* __restrict__ q0,
                                                  unsigned short* __restrict__ q1) {
    __shared__ float tile[64][65];
    int kbase = blockIdx.x << 6;            // 0..704 (12 tiles over 768)
    int n2base = blockIdx.y << 6;           // 0..3008 (48 tiles over 3072)
    int seg = n2base >> 10;
    int nbase = n2base & 1023;
    int row0 = (seg == 0) ? 0 : ((seg == 1) ? HIDDEN : 1556);
    int t = threadIdx.x;
    int c = t & 63, r0 = t >> 6;
    for (int rr = 0; rr < 64; rr += 4) {
        int r = rr + r0;
        int n = nbase + c;
        tile[r][c] = (n < FFNN_DIM) ? w1[(size_t)(row0 + kbase + r) * FFNN_DIM + n] : 0.f;
    }
    __syncthreads();
    int kl = t & 63;
    for (int rr = 0; rr < 64; rr += 4) {
        int nl = rr + r0;
        store_split2(q0, q1, (size_t)(n2base + nl) * HIDDEN + kbase + kl, tile[kl][nl]);
    }
}

// ---------------- w2 convert+transpose via LDS tiles: m_w2[1000][1000] -> [1024][1024] ---
__global__ __launch_bounds__(256) void convert_wt(const float* __restrict__ w,
                                                  unsigned short* __restrict__ q0,
                                                  unsigned short* __restrict__ q1) {
    __shared__ float tile[64][65];
    int kbase = blockIdx.x << 6;            // 16 tiles over 1024
    int nbase = blockIdx.y << 6;            // 16 tiles over 1024
    int t = threadIdx.x;
    int c = t & 63, r0 = t >> 6;
    for (int rr = 0; rr < 64; rr += 4) {
        int r = rr + r0;
        int k = kbase + r, n = nbase + c;
        tile[r][c] = (k < FFNN_DIM && n < FFNN_DIM) ? w[(size_t)k * FFNN_DIM + n] : 0.f;
    }
    __syncthreads();
    int kl = t & 63;
    for (int rr = 0; rr < 64; rr += 4) {
        int nl = rr + r0;
        store_split2(q0, q1, (size_t)(nbase + nl) * KP2 + kbase + kl, tile[kl][nl]);
    }
}

// Stage one 128x64-bf16 tile (16KB) async into LDS. r24: BK=64. LDS layout row-major
// [128][64]; LDS slot s (8 bf16) of row r holds global kblk s^(r&7) (both-sides
// involution: linear LDS dest, pre-swizzled global source; read undoes it).
__device__ __forceinline__ void stage_tile64(const unsigned short* __restrict__ src,
                                             unsigned short* lds, int base_row, int Kp,
                                             int k0, int t) {
#pragma unroll
    for (int qi = 0; qi < 4; ++qi) {
        int u = qi * 256 + t;           // 0..1023
        int row = u >> 3;
        int slot = u & 7;
        int kblk = slot ^ (row & 7);
        const unsigned short* g = src + (size_t)(base_row + row) * Kp + k0 + kblk * 8;
        gl_lds16(g, lds + u * 8);
    }
}

// ---------------- 2-split 3-product MFMA GEMM (BK=64), fp32 out: P = doc @ Wc ---------
// r24: BK 32->64 halves barrier count (24 k-steps -> 12); XCD-aware mapping gives each
// XCD 3 B-panels (L2-hot). Per-accumulator MFMA issue order identical to BK=32 version
// (h=0's 3 products then h=1's per k-step) -> bit-identical accumulation.
__global__ __launch_bounds__(256, 2) void gemm3p(
    const unsigned short* __restrict__ A0, const unsigned short* __restrict__ A1,
    const unsigned short* __restrict__ B0, const unsigned short* __restrict__ B1,
    float* __restrict__ C) {
    __shared__ unsigned short As0[128 * 64], As1[128 * 64];
    __shared__ unsigned short Bs0[128 * 64], Bs1[128 * 64];
    int t = threadIdx.x;
    int bid = blockIdx.x;
    int g = bid & 7, rr = bid >> 3;         // xcd-chunk g: n_tiles {g, g+8, g+16}
    int bm = (rr & 15) << 7;
    int bn = (g + 8 * (rr >> 4)) << 7;
    int lane = t & 63, wv = t >> 6;
    int wm = (wv >> 1) * 64, wn = (wv & 1) * 64;
    int lr = lane & 15, qq = lane >> 4;

    f32x4 acc[4][4] = {};

    for (int k0 = 0; k0 < HIDDEN; k0 += 64) {
        stage_tile64(A0, As0, bm, HIDDEN, k0, t);
        stage_tile64(A1, As1, bm, HIDDEN, k0, t);
        stage_tile64(B0, Bs0, bn, HIDDEN, k0, t);
        stage_tile64(B1, Bs1, bn, HIDDEN, k0, t);
        __syncthreads();
        short8 a0[2][4], a1[2][4];
#pragma unroll
        for (int i = 0; i < 4; ++i) {
            int ra = (wm + i * 16 + lr) * 64;
#pragma unroll
            for (int h = 0; h < 2; ++h) {
                int sl = ((h * 4 + qq) ^ (lr & 7)) * 8;
                a0[h][i] = *(const short8*)&As0[ra + sl];
                a1[h][i] = *(const short8*)&As1[ra + sl];
            }
        }
#pragma unroll
        for (int j = 0; j < 4; ++j) {
            int rb = (wn + j * 16 + lr) * 64;
            short8 b0[2], b1[2];
#pragma unroll
            for (int h = 0; h < 2; ++h) {
                int sl = ((h * 4 + qq) ^ (lr & 7)) * 8;
                b0[h] = *(const short8*)&Bs0[rb + sl];
                b1[h] = *(const short8*)&Bs1[rb + sl];
            }
#pragma unroll
            for (int i = 0; i < 4; ++i) {
#pragma unroll
                for (int h = 0; h < 2; ++h) {
                    acc[i][j] = __builtin_amdgcn_mfma_f32_16x16x32_bf16(a1[h][i], b0[h], acc[i][j], 0, 0, 0);
                    acc[i][j] = __builtin_amdgcn_mfma_f32_16x16x32_bf16(a0[h][i], b1[h], acc[i][j], 0, 0, 0);
                    acc[i][j] = __builtin_amdgcn_mfma_f32_16x16x32_bf16(a0[h][i], b0[h], acc[i][j], 0, 0, 0);
                }
            }
        }
        __syncthreads();
    }
#pragma unroll
    for (int i = 0; i < 4; ++i)
#pragma unroll
        for (int j = 0; j < 4; ++j)
#pragma unroll
            for (int r = 0; r < 4; ++r) {
                int m = bm + wm + i * 16 + qq * 4 + r;
                int n = bn + wn + j * 16 + lr;
                C[(size_t)m * PNP + n] = acc[i][j][r];
            }
}

// ---------------- combine: h1[c] = relu(P_s[s] + P_e[e] + sum attn*P_a[s+w] + Tw + b1) ----
__global__ void combine_kernel(const float* __restrict__ P, const float* __restrict__ tw,
                               const float* __restrict__ attn_g, const float* __restrict__ b1,
                               const int* __restrict__ starts, const int* __restrict__ ends,
                               const int* __restrict__ perm,
                               unsigned short* __restrict__ h0, unsigned short* __restrict__ h1) {
    int pos = ((blockIdx.x & 7) << 10) | (blockIdx.x >> 3);
    int c = perm[pos];
    int t = threadIdx.x;
    int s = starts[c], e = ends[c];
    int wid = e - s;
    __shared__ float at[MSW];
    if (t < MSW) at[t] = attn_g[c * 32 + t];
    __syncthreads();
    int n0 = t * 4;
    size_t ho = (size_t)c * NP + n0;
    if (t < 250) {
        f32x4 acc = *(const f32x4*)&P[(size_t)s * PNP + n0];
        acc += *(const f32x4*)&P[(size_t)e * PNP + 1024 + n0];
        acc += *(const f32x4*)&tw[(size_t)wid * NP + n0];
        acc += *(const f32x4*)&b1[n0];
        const float* Pa = P + (size_t)s * PNP + 2048 + n0;
        for (int w = 0; w <= wid; ++w)
            acc += at[w] * *(const f32x4*)&Pa[(size_t)w * PNP];
        u16x4 q0, q1;
#pragma unroll
        for (int k = 0; k < 4; ++k) {
            float v = fmaxf(acc[k], 0.f);
            unsigned short x0 = bf16_rne(v);
            float r1 = v - bf16_to_f(x0);
            q0[k] = x0; q1[k] = bf16_rne(r1);
        }
        *(u16x4*)&h0[ho] = q0;
        *(u16x4*)&h1[ho] = q1;
    } else {
        u16x4 z = {0, 0, 0, 0};
        *(u16x4*)&h0[ho] = z;
        *(u16x4*)&h1[ho] = z;
    }
}

// ---------------- 2-split 3-product MFMA GEMM (BK=64, score fusion) ------------
// r24: BK 32->64 (32 k-steps -> 16); XCD-aware mapping: n_tile = bid&7 -> each XCD
// keeps one 0.5MB B-panel L2-hot while A streams. MFMA order preserved (bit-identical).
__global__ __launch_bounds__(256, 2) void gemm3(
    const unsigned short* __restrict__ A0, const unsigned short* __restrict__ A1,
    const unsigned short* __restrict__ B0, const unsigned short* __restrict__ B1,
    const float* __restrict__ bias, int nreal, int Kp,
    const float* __restrict__ w3, float* __restrict__ partials) {
    __shared__ unsigned short As0[128 * 64], As1[128 * 64];
    __shared__ unsigned short Bs0[128 * 64], Bs1[128 * 64];
    int t = threadIdx.x;
    int bid = blockIdx.x;
    int bm = (bid >> 3) << 7;               // 64 M-tiles
    int bn = (bid & 7) << 7;                // 8 N-tiles; n ≡ bid (mod 8) -> per-XCD panel
    int lane = t & 63, wv = t >> 6;
    int wm = (wv >> 1) * 64, wn = (wv & 1) * 64;
    int lr = lane & 15, qq = lane >> 4;

    f32x4 acc[4][4] = {};

    for (int k0 = 0; k0 < Kp; k0 += 64) {
        stage_tile64(A0, As0, bm, Kp, k0, t);
        stage_tile64(A1, As1, bm, Kp, k0, t);
        stage_tile64(B0, Bs0, bn, Kp, k0, t);
        stage_tile64(B1, Bs1, bn, Kp, k0, t);
        __syncthreads();
        short8 a0[2][4], a1[2][4];
#pragma unroll
        for (int i = 0; i < 4; ++i) {
            int ra = (wm + i * 16 + lr) * 64;
#pragma unroll
            for (int h = 0; h < 2; ++h) {
                int sl = ((h * 4 + qq) ^ (lr & 7)) * 8;
                a0[h][i] = *(const short8*)&As0[ra + sl];
                a1[h][i] = *(const short8*)&As1[ra + sl];
            }
        }
#pragma unroll
        for (int j = 0; j < 4; ++j) {
            int rb = (wn + j * 16 + lr) * 64;
            short8 b0[2], b1[2];
#pragma unroll
            for (int h = 0; h < 2; ++h) {
                int sl = ((h * 4 + qq) ^ (lr & 7)) * 8;
                b0[h] = *(const short8*)&Bs0[rb + sl];
                b1[h] = *(const short8*)&Bs1[rb + sl];
            }
#pragma unroll
            for (int i = 0; i < 4; ++i) {
#pragma unroll
                for (int h = 0; h < 2; ++h) {
                    acc[i][j] = __builtin_amdgcn_mfma_f32_16x16x32_bf16(a1[h][i], b0[h], acc[i][j], 0, 0, 0);
                    acc[i][j] = __builtin_amdgcn_mfma_f32_16x16x32_bf16(a0[h][i], b1[h], acc[i][j], 0, 0, 0);
                    acc[i][j] = __builtin_amdgcn_mfma_f32_16x16x32_bf16(a0[h][i], b0[h], acc[i][j], 0, 0, 0);
                }
            }
        }
        __syncthreads();
    }

    int pid = ((bn >> 7) << 1) | (wn >> 6);  // 0..15
#pragma unroll
    for (int i = 0; i < 4; ++i)
#pragma unroll
        for (int r = 0; r < 4; ++r) {
            float p = 0.f;
#pragma unroll
            for (int j = 0; j < 4; ++j) {
                int n = bn + wn + j * 16 + lr;
                float v = acc[i][j][r] + (n < nreal ? bias[n] : 0.f);
                v = fmaxf(v, 0.f);
                p += v * (n < nreal ? w3[n] : 0.f);
            }
            p += __shfl_xor(p, 1);
            p += __shfl_xor(p, 2);
            p += __shfl_xor(p, 4);
            p += __shfl_xor(p, 8);
            if (lr == 0) {
                int m = bm + wm + i * 16 + qq * 4 + r;
                partials[(size_t)m * 16 + pid] = p;
            }
        }
}

// ---------------- deterministic score finalize ----------------
__global__ void score_final(const float* __restrict__ partials, const float* __restrict__ b3,
                            const float* __restrict__ width_s, const int* __restrict__ starts,
                            const int* __restrict__ ends, float* __restrict__ out) {
    int c = blockIdx.x * 256 + threadIdx.x;
    if (c >= NUM_CAND) return;
    float s = b3[0] + width_s[ends[c] - starts[c]];
#pragma unroll
    for (int p = 0; p < 16; ++p) s += partials[(size_t)c * 16 + p];
    out[c] = s;
}

// ---------------- exact counting rank-sort: 256 blocks ----------------
// r24: per-lane rotation (t&7)*2 spreads the 8 broadcast segment reads across 8 distinct
// bank pairs (previously all aliased one pair -> 8-beat serialize). Sum order-independent.
__global__ __launch_bounds__(256) void rank_kernel(const float* __restrict__ scores,
                                                   const int* __restrict__ starts,
                                                   const int* __restrict__ ends,
                                                   unsigned short* __restrict__ ord_g,
                                                   unsigned int* __restrict__ se_g) {
    __shared__ unsigned long long kk[NUM_CAND];  // 64 KB
    int t = threadIdx.x;
    for (int i = t; i < NUM_CAND; i += 256) {
        unsigned int b = __float_as_uint(scores[i]);
        unsigned int u = b ^ ((b & 0x80000000u) ? 0xFFFFFFFFu : 0x80000000u);
        unsigned int hi = ~u;
        kk[i] = ((unsigned long long)hi << 32) | (unsigned int)i;
    }
    __syncthreads();
    int c = blockIdx.x * 32 + (t >> 3);
    int seg = (t & 7) * 1024;
    int rot = (t & 7) * 2;
    unsigned long long mykey = kk[c];
    int cnt = 0;
    for (int ii = 0; ii < 1024; ++ii) {
        int i = seg + ((ii + rot) & 1023);
        cnt += (kk[i] < mykey) ? 1 : 0;
    }
    cnt += __shfl_xor(cnt, 1);
    cnt += __shfl_xor(cnt, 2);
    cnt += __shfl_xor(cnt, 4);
    if ((t & 7) == 0) {
        int idx = (int)(mykey & 0xFFFFFFFFull);
        int rank = cnt;
        ord_g[rank] = (unsigned short)idx;
        se_g[rank] = ((unsigned int)starts[idx] << 16) | (unsigned int)ends[idx];
    }
}

// ---------------- single-wave greedy crossing-NMS ----------------
// LOCKED at the r17-verified form (292us). Evidence: r13 8-wave=313, r15 flag=401,
// r18 pipelined=374, r19 fixpoint=356, r20 clock-hold spinners=350 (DVFS falsified).
// The cost is dependent-chain latency, structural. Do not restructure further.
__global__ __launch_bounds__(64, 1)
void select_nms(const unsigned int* __restrict__ se_g,
                unsigned short* __restrict__ sel_g,
                int* __restrict__ count_g) {
    __shared__ unsigned int se_arr[NUM_CAND];   // 32 KB
    __shared__ unsigned int st[2 * NUM_WORDS];  // 16 KB
    int lane = threadIdx.x;

    {
        const uint4* src4 = (const uint4*)se_g;
        uint4* dst4 = (uint4*)se_arr;
        for (int i = lane; i < NUM_CAND / 4; i += 64) dst4[i] = src4[i];
    }
    for (int i = lane; i < 2 * NUM_WORDS; i += 64)
        st[i] = (i & 1) ? (unsigned int)NUM_WORDS : 0u;  // max_end+1=0, min_start=2048
    __syncthreads();

    const unsigned long long* stp = (const unsigned long long*)st;
    int count = 0;
    for (int c = 0; c < NUM_CAND / 64; ++c) {
        int ib = c * 64;
        unsigned int sev = se_arr[ib + lane];
        int s = (int)(sev >> 16), e = (int)(sev & 0xFFFFu);
        const unsigned long long* bp = stp + s;
        unsigned long long v[MSW];
#pragma unroll
        for (int w = 0; w < MSW; ++w) v[w] = bp[w];
        int me = (int)(unsigned int)v[0] - 1;
        bool crossedA = (s < e) && ((int)(unsigned int)(v[0] >> 32) < s);
        bool crossedB = false;
#pragma unroll
        for (int w = 1; w < MSW; ++w) {
            int j = s + w;
            bool in = (j <= e);
            int mej = (int)(unsigned int)v[w] - 1;
            int msj = (int)(unsigned int)(v[w] >> 32);
            bool hit = in && ((mej > e) || ((j < e) && (msj < s)));
            if (w & 1) crossedA = crossedA || hit;
            else       crossedB = crossedB || hit;
        }
        bool crossed = crossedA || crossedB;
        bool spec = !crossed && (me != e);

        int cbefore = count;
        unsigned long long window = ~0ull;
        unsigned int pend = 0u;
        int rk = 0, lcnt = 0;
        while (true) {
            unsigned long long b = __ballot(spec) & window;
            if (b == 0ull) break;
            int f = __ffsll((unsigned long long)b) - 1;
            unsigned int sef = __builtin_amdgcn_readlane(sev, (unsigned int)f);
            int sf = (int)(sef >> 16), ef = (int)(sef & 0xFFFFu);
            bool mine = (lane == lcnt);
            pend = mine ? sef : pend;
            rk = mine ? (ib + f) : rk;
            lcnt++;
            count++;
            if (count >= TOP_NUM) break;
            window &= (f >= 63) ? 0ull : (~0ull << (f + 1));
            if (lane > f) {
                if (s == sf) me = max(me, ef);
                crossed = crossed || ((s < sf) && (sf <= e) && (ef > e))
                                  || ((sf < s) && (s <= ef) && (ef < e));
                spec = !crossed && (me != e);
            }
        }
        if (lane < lcnt) {
            int sf = (int)(pend >> 16), ef = (int)(pend & 0xFFFFu);
            sel_g[cbefore + lane] = (unsigned short)rk;
            atomicMax(&st[2 * sf], (unsigned int)(ef + 1));
            atomicMin(&st[2 * ef + 1], (unsigned int)sf);
        }
        if (count >= TOP_NUM) break;
    }
    if (lane == 0) *count_g = count;
}

// ---------------- post: final span-order sort + emit (r23: 1024 threads) ----------------
__global__ __launch_bounds__(1024) void select_post(const float* __restrict__ scores,
                                                    const int* __restrict__ starts,
                                                    const int* __restrict__ ends,
                                                    const unsigned short* __restrict__ ord_g,
                                                    const unsigned short* __restrict__ sel_g,
                                                    const int* __restrict__ count_g,
                                                    float* out, int* top_idx_ws) {
    __shared__ unsigned long long fkeys[1024];
    int t = threadIdx.x;
    int count = *count_g;
    {
        unsigned long long k = 0xFFFFFFFFFFFFFFFFull;
        if (t < count) {
            int idx = (int)ord_g[sel_g[t]];
            unsigned int key32 = (unsigned int)(starts[idx] * NUM_WORDS + ends[idx]);
            k = ((unsigned long long)key32 << 32) | (unsigned int)idx;
        }
        fkeys[t] = k;
    }
    __syncthreads();
    for (int size = 2; size <= 1024; size <<= 1) {
        for (int stride = size >> 1; stride > 0; stride >>= 1) {
            int ixj = t ^ stride;
            if (ixj > t) {
                bool up = ((t & size) == 0);
                unsigned long long a = fkeys[t], b = fkeys[ixj];
                if ((a > b) == up) { fkeys[t] = b; fkeys[ixj] = a; }
            }
            __syncthreads();
        }
    }
    if (t < TOP_NUM) {
        int fi = (t < count) ? (int)(fkeys[t] & 0xFFFFFFFFull)
                             : (int)(fkeys[0] & 0xFFFFFFFFull);
        out[OUT_TOPIDX + t] = (float)fi;
        out[OUT_TSTART + t] = (float)starts[fi];
        out[OUT_TEND + t] = (float)ends[fi];
        out[OUT_TSCORE + t] = scores[fi];
        top_idx_ws[t] = fi;
    }
}

// ---------------- gather top_span_emb rows directly from doc (exact fp32) ----------------
__global__ void gather_emb(const float* __restrict__ doc, const float* __restrict__ swe,
                           const float* __restrict__ attn_g, const int* __restrict__ starts,
                           const int* __restrict__ ends, const int* __restrict__ top_idx_ws,
                           float* __restrict__ out) {
    int r = blockIdx.x, t = threadIdx.x;
    int idx = top_idx_ws[r];
    int s = starts[idx], e = ends[idx];
    int wid = e - s;
    __shared__ float at[MSW];
    if (t < MSW) at[t] = attn_g[(size_t)idx * 32 + t];
    __syncthreads();
    float* dst = out + OUT_TEMB + (size_t)r * SPAN_DIM;
    if (t < 192) {
        int h4 = t * 4;
        f32x4 vs = *(const f32x4*)&doc[(size_t)s * HIDDEN + h4];
        f32x4 ve = *(const f32x4*)&doc[(size_t)e * HIDDEN + h4];
        f32x4 acc = {0.f, 0.f, 0.f, 0.f};
        for (int w = 0; w <= wid; ++w)
            acc += at[w] * *(const f32x4*)&doc[(size_t)(s + w) * HIDDEN + h4];
#pragma unroll
        for (int k = 0; k < 4; ++k) {
            dst[h4 + k] = vs[k];
            dst[HIDDEN + h4 + k] = ve[k];
            dst[2 * HIDDEN + FEAT + h4 + k] = acc[k];
        }
    }
    if (t < FEAT) dst[2 * HIDDEN + t] = swe[wid * FEAT + t];
}

extern "C" void kernel_launch(void* const* d_in, const int* in_sizes, int n_in,
                              void* d_out, int out_size, void* d_ws, size_t ws_size,
                              hipStream_t stream) {
    const float* mention_doc = (const float*)d_in[0];
    const float* span_width_emb = (const float*)d_in[1];
    const float* head_w = (const float*)d_in[2];
    const float* head_b = (const float*)d_in[3];
    const float* m_w1 = (const float*)d_in[4];
    const float* m_b1 = (const float*)d_in[5];
    const float* m_w2 = (const float*)d_in[6];
    const float* m_b2 = (const float*)d_in[7];
    const float* m_w3 = (const float*)d_in[8];
    const float* m_b3 = (const float*)d_in[9];
    const float* width_prior_emb = (const float*)d_in[10];
    const float* w_w1 = (const float*)d_in[11];
    const float* w_b1 = (const float*)d_in[12];
    const float* w_w2 = (const float*)d_in[13];
    const float* w_b2 = (const float*)d_in[14];
    const float* w_w3 = (const float*)d_in[15];
    const float* w_b3 = (const float*)d_in[16];
    const int* cand_starts = (const int*)d_in[17];
    const int* cand_ends = (const int*)d_in[18];

    char* w = (char*)d_ws;
    const size_t szH = (size_t)NUM_CAND * NP * 2;
    const size_t szW2 = (size_t)NP * KP2 * 2;
    const size_t szWc = (size_t)PNP * HIDDEN * 2;
    const size_t szD = (size_t)NUM_WORDS * HIDDEN * 2;
    char* p = w;
    unsigned short* h0 = (unsigned short*)p; p += szH;
    unsigned short* h1 = (unsigned short*)p; p += szH;
    unsigned short* w2t0 = (unsigned short*)p; p += szW2;
    unsigned short* w2t1 = (unsigned short*)p; p += szW2;
    unsigned short* Wc0 = (unsigned short*)p; p += szWc;
    unsigned short* Wc1 = (unsigned short*)p; p += szWc;
    unsigned short* d0 = (unsigned short*)p; p += szD;
    unsigned short* d1 = (unsigned short*)p; p += szD;
    float* P = (float*)p; p += (size_t)NUM_WORDS * PNP * 4;
    float* tw = (float*)p; p += (size_t)MSW * NP * 4;
    float* attn_g = (float*)p; p += (size_t)NUM_CAND * 32 * 4;
    float* partials = (float*)p; p += (size_t)NUM_CAND * 16 * 4;
    unsigned short* ord_g = (unsigned short*)p; p += (size_t)NUM_CAND * 2;
    unsigned int* se_g = (unsigned int*)p; p += (size_t)NUM_CAND * 4;
    unsigned short* sel_g = (unsigned short*)p; p += 2048;
    int* count_g = (int*)p; p += 128;
    float* head_s = (float*)p; p += NUM_WORDS * 4;
    float* width_s = (float*)p; p += 128;
    int* top_idx_ws = (int*)p; p += 4096;
    int* hist_g = (int*)p; p += NUM_WORDS * 4;
    int* perm_g = (int*)p; p += (size_t)NUM_CAND * 4;

    size_t need = (size_t)(p - w);
    if (ws_size < need) {
        fprintf(stderr, "kernel_launch: ws too small (%zu < %zu)\n", ws_size, need);
    }

    float* out = (float*)d_out;

    head_kernel<<<NUM_WORDS / 4, 256, 0, stream>>>(mention_doc, head_w, head_b, head_s,
                                                   hist_g, d0, d1);
    width_kernel<<<MSW, 256, 0, stream>>>(width_prior_emb, w_w1, w_b1, w_w2, w_b2, w_w3, w_b3,
                                          width_s, span_width_emb, m_w1, tw);
    attn_kernel<<<NUM_CAND / 4, 256, 0, stream>>>(head_s, cand_starts, cand_ends, attn_g,
                                                  hist_g);
    convert_wc<<<dim3(12, 48), 256, 0, stream>>>(m_w1, Wc0, Wc1);
    convert_wt<<<dim3(16, 16), 256, 0, stream>>>(m_w2, w2t0, w2t1);
    perm_kernel<<<1, 256, 0, stream>>>(hist_g, cand_starts, perm_g);
    gemm3p<<<16 * 24, 256, 0, stream>>>(d0, d1, Wc0, Wc1, P);
    combine_kernel<<<NUM_CAND, 256, 0, stream>>>(P, tw, attn_g, m_b1, cand_starts, cand_ends,
                                                 perm_g, h0, h1);
    gemm3<<<512, 256, 0, stream>>>(h0, h1, w2t0, w2t1, m_b2, FFNN_DIM, KP2,
                                   m_w3, partials);
    score_final<<<NUM_CAND / 256, 256, 0, stream>>>(partials, m_b3, width_s, cand_starts,
                                                    cand_ends, out);
    rank_kernel<<<NUM_CAND / 32, 256, 0, stream>>>(out, cand_starts, cand_ends, ord_g, se_g);
    select_nms<<<1, 64, 0, stream>>>(se_g, sel_g, count_g);
    select_post<<<1, 1024, 0, stream>>>(out, cand_starts, cand_ends, ord_g, sel_g, count_g,
                                        out, top_idx_ws);
    gather_emb<<<TOP_NUM, 256, 0, stream>>>(mention_doc, span_width_emb, attn_g, cand_starts,
                                            cand_ends, top_idx_ws, out);
}

// Round 11
// 741.235 us; speedup vs baseline: 1.2746x; 1.0076x over previous
//
#include <hip/hip_runtime.h>
#include <cstdio>
#include <cmath>

#define NUM_WORDS 2048
#define NUM_CAND 8192
#define HIDDEN 768
#define FEAT 20
#define FFNN_DIM 1000
#define SPAN_DIM 2324
#define TOP_NUM 819
#define MSW 30
#define KP2 1024   // FFNN padded to x32
#define NP 1024    // padded N
#define PNP 3072   // P matrix padded N (3 segments of 1024)

// d_out layout (floats): [scores 8192][top_idx 819][top_starts 819][top_ends 819]
//                        [top_span_emb 819*2324][top_scores 819]
#define OUT_TOPIDX   (NUM_CAND)
#define OUT_TSTART   (NUM_CAND + TOP_NUM)
#define OUT_TEND     (NUM_CAND + 2*TOP_NUM)
#define OUT_TEMB     (NUM_CAND + 3*TOP_NUM)
#define OUT_TSCORE   (NUM_CAND + 3*TOP_NUM + TOP_NUM*SPAN_DIM)

typedef short short8 __attribute__((ext_vector_type(8)));
typedef float f32x4 __attribute__((ext_vector_type(4)));
typedef unsigned short u16x4 __attribute__((ext_vector_type(4)));

__device__ __forceinline__ unsigned short bf16_rne(float x) {
    unsigned int u = __float_as_uint(x);
    unsigned int r = u + 0x7FFFu + ((u >> 16) & 1u);
    return (unsigned short)(r >> 16);
}
__device__ __forceinline__ float bf16_to_f(unsigned short h) {
    return __uint_as_float(((unsigned int)h) << 16);
}
// 2-way split: v = s0 + s1 + r, |r| <= 2^-16 |v| (r21-verified: absmax unchanged)
__device__ __forceinline__ void store_split2(unsigned short* p0, unsigned short* p1,
                                             size_t off, float v) {
    unsigned short h0 = bf16_rne(v);
    float r1 = v - bf16_to_f(h0);
    p0[off] = h0;
    p1[off] = bf16_rne(r1);
}

// async 16B global->LDS (gfx950 global_load_lds_dwordx4). LDS dest must be
// wave-uniform base + lane*16 -> linear LDS; swizzle applied to the GLOBAL source.
__device__ __forceinline__ void gl_lds16(const unsigned short* g, unsigned short* l) {
    __builtin_amdgcn_global_load_lds(
        (const __attribute__((address_space(1))) unsigned short*)g,
        (__attribute__((address_space(3))) unsigned short*)l, 16, 0, 0);
}

// ---------------- head scores + doc 2-split convert (r23 fusion) ----------------
__global__ void head_kernel(const float* __restrict__ doc, const float* __restrict__ hw,
                            const float* __restrict__ hb, float* __restrict__ out,
                            int* __restrict__ hist,
                            unsigned short* __restrict__ d0, unsigned short* __restrict__ d1) {
    int t = threadIdx.x;
    if (blockIdx.x == 0) {
        for (int i = t; i < NUM_WORDS; i += 256) hist[i] = 0;
    }
    int base = blockIdx.x * 4 * HIDDEN;
    for (int i = t; i < 4 * HIDDEN; i += 256)
        store_split2(d0, d1, (size_t)base + i, doc[base + i]);
    int wave = t >> 6, lane = t & 63;
    int row = blockIdx.x * 4 + wave;
    if (row >= NUM_WORDS) return;
    float acc = 0.f;
    for (int h = lane; h < HIDDEN; h += 64) acc += doc[row * HIDDEN + h] * hw[h];
    for (int off = 32; off > 0; off >>= 1) acc += __shfl_down(acc, off);
    if (lane == 0) out[row] = acc + hb[0];
}

// ---------------- width prior ffnn [30,20]->[30] + T_w rows (r23 fusion) ----------------
__global__ void width_kernel(const float* __restrict__ x, const float* __restrict__ w1,
                             const float* __restrict__ b1, const float* __restrict__ w2,
                             const float* __restrict__ b2, const float* __restrict__ w3,
                             const float* __restrict__ b3, float* __restrict__ out,
                             const float* __restrict__ swe, const float* __restrict__ mw1,
                             float* __restrict__ tw) {
    __shared__ float xs[FEAT];
    __shared__ float h1s[FFNN_DIM];
    __shared__ float red[256];
    int r = blockIdx.x, t = threadIdx.x;
    if (t < FEAT) xs[t] = x[r * FEAT + t];
    __syncthreads();
    for (int j = t; j < FFNN_DIM; j += 256) {
        float acc = b1[j];
        for (int k = 0; k < FEAT; ++k) acc += xs[k] * w1[k * FFNN_DIM + j];
        h1s[j] = fmaxf(acc, 0.f);
    }
    __syncthreads();
    float partial = 0.f;
    for (int j = t; j < FFNN_DIM; j += 256) {
        float acc = b2[j];
        for (int k = 0; k < FFNN_DIM; ++k) acc += h1s[k] * w2[k * FFNN_DIM + j];
        partial += fmaxf(acc, 0.f) * w3[j];
    }
    red[t] = partial;
    __syncthreads();
    for (int s = 128; s > 0; s >>= 1) { if (t < s) red[t] += red[t + s]; __syncthreads(); }
    if (t == 0) out[r] = red[0] + b3[0];
    // T_w[r][1024] = span_width_emb[r] @ m_w1[1536:1556] (bit-identical to old tw_kernel)
    for (int n = t; n < NP; n += 256) {
        float acc = 0.f;
        if (n < FFNN_DIM) {
            for (int f = 0; f < FEAT; ++f)
                acc += swe[r * FEAT + f] * mw1[(size_t)(1536 + f) * FFNN_DIM + n];
        }
        tw[r * NP + n] = acc;
    }
}

// ---------------- attention weights per span: attn_g [8192][32] ----------------
// r25: 2 candidates per wave (32-lane segments). Bit-exact vs the 64-wide form: the old
// tree's off=32 step only added -inf/0 padding (fmax(x,-inf)=x, x+0=x); remaining steps
// are exactly this 32-wide tree.
__global__ void attn_kernel(const float* __restrict__ head_s, const int* __restrict__ starts,
                            const int* __restrict__ ends, float* __restrict__ attn_g,
                            int* __restrict__ hist) {
    int c = blockIdx.x * 8 + (threadIdx.x >> 5);
    int w = threadIdx.x & 31;
    if (c >= NUM_CAND) return;
    int s = starts[c], e = ends[c];
    if (w == 0) atomicAdd(&hist[s], 1);
    int wid = e - s;
    float hsv = (w < MSW && w <= wid) ? head_s[s + w] : -INFINITY;
    float m = hsv;
    for (int off = 16; off > 0; off >>= 1) m = fmaxf(m, __shfl_down(m, off, 32));
    m = __shfl(m, 0, 32);
    float ex = (w < MSW && w <= wid) ? expf(hsv - m) : 0.f;
    float ssum = ex;
    for (int off = 16; off > 0; off >>= 1) ssum += __shfl_down(ssum, off, 32);
    ssum = __shfl(ssum, 0, 32);
    attn_g[c * 32 + w] = (w < MSW) ? (ex / ssum) : 0.f;
}

// ---------------- counting-sort permutation by start (scan + scatter, 1 block) ----------
__global__ __launch_bounds__(256) void perm_kernel(const int* __restrict__ hist,
                                                   const int* __restrict__ starts,
                                                   int* __restrict__ perm) {
    __shared__ int hoff[NUM_WORDS];
    __shared__ int wsum[4];
    int t = threadIdx.x, lane = t & 63, wv = t >> 6;
    int base = t * 8;
    int lh[8];
    int s0 = 0;
#pragma unroll
    for (int i = 0; i < 8; ++i) { lh[i] = hist[base + i]; s0 += lh[i]; }
    int sc = s0;
    for (int o = 1; o < 64; o <<= 1) { int v = __shfl_up(sc, o); if (lane >= o) sc += v; }
    if (lane == 63) wsum[wv] = sc;
    __syncthreads();
    int wbase = 0;
    for (int i = 0; i < wv; ++i) wbase += wsum[i];
    int run = wbase + sc - s0;  // exclusive prefix of this thread's 8 bins
#pragma unroll
    for (int i = 0; i < 8; ++i) { hoff[base + i] = run; run += lh[i]; }
    __syncthreads();
    for (int c = t; c < NUM_CAND; c += 256) {
        int pos = atomicAdd(&hoff[starts[c]], 1);
        perm[pos] = c;
    }
}

// ---------------- Wc convert via LDS tile-transpose: coalesced both sides --------------
__global__ __launch_bounds__(256) void convert_wc(const float* __restrict__ w1,
                                                  unsigned short* __restrict__ q0,
                                                  unsigned short* __restrict__ q1) {
    __shared__ float tile[64][65];
    int kbase = blockIdx.x << 6;            // 0..704 (12 tiles over 768)
    int n2base = blockIdx.y << 6;           // 0..3008 (48 tiles over 3072)
    int seg = n2base >> 10;
    int nbase = n2base & 1023;
    int row0 = (seg == 0) ? 0 : ((seg == 1) ? HIDDEN : 1556);
    int t = threadIdx.x;
    int c = t & 63, r0 = t >> 6;
    for (int rr = 0; rr < 64; rr += 4) {
        int r = rr + r0;
        int n = nbase + c;
        tile[r][c] = (n < FFNN_DIM) ? w1[(size_t)(row0 + kbase + r) * FFNN_DIM + n] : 0.f;
    }
    __syncthreads();
    int kl = t & 63;
    for (int rr = 0; rr < 64; rr += 4) {
        int nl = rr + r0;
        store_split2(q0, q1, (size_t)(n2base + nl) * HIDDEN + kbase + kl, tile[kl][nl]);
    }
}

// ---------------- w2 convert+transpose via LDS tiles: m_w2[1000][1000] -> [1024][1024] ---
__global__ __launch_bounds__(256) void convert_wt(const float* __restrict__ w,
                                                  unsigned short* __restrict__ q0,
                                                  unsigned short* __restrict__ q1) {
    __shared__ float tile[64][65];
    int kbase = blockIdx.x << 6;            // 16 tiles over 1024
    int nbase = blockIdx.y << 6;            // 16 tiles over 1024
    int t = threadIdx.x;
    int c = t & 63, r0 = t >> 6;
    for (int rr = 0; rr < 64; rr += 4) {
        int r = rr + r0;
        int k = kbase + r, n = nbase + c;
        tile[r][c] = (k < FFNN_DIM && n < FFNN_DIM) ? w[(size_t)k * FFNN_DIM + n] : 0.f;
    }
    __syncthreads();
    int kl = t & 63;
    for (int rr = 0; rr < 64; rr += 4) {
        int nl = rr + r0;
        store_split2(q0, q1, (size_t)(nbase + nl) * KP2 + kbase + kl, tile[kl][nl]);
    }
}

// Stage one 128x64-bf16 tile (16KB) async into LDS. r24: BK=64. LDS layout row-major
// [128][64]; LDS slot s (8 bf16) of row r holds global kblk s^(r&7).
__device__ __forceinline__ void stage_tile64(const unsigned short* __restrict__ src,
                                             unsigned short* lds, int base_row, int Kp,
                                             int k0, int t) {
#pragma unroll
    for (int qi = 0; qi < 4; ++qi) {
        int u = qi * 256 + t;           // 0..1023
        int row = u >> 3;
        int slot = u & 7;
        int kblk = slot ^ (row & 7);
        const unsigned short* g = src + (size_t)(base_row + row) * Kp + k0 + kblk * 8;
        gl_lds16(g, lds + u * 8);
    }
}

// ---------------- 2-split 3-product MFMA GEMM (BK=64), fp32 out: P = doc @ Wc ---------
__global__ __launch_bounds__(256, 2) void gemm3p(
    const unsigned short* __restrict__ A0, const unsigned short* __restrict__ A1,
    const unsigned short* __restrict__ B0, const unsigned short* __restrict__ B1,
    float* __restrict__ C) {
    __shared__ unsigned short As0[128 * 64], As1[128 * 64];
    __shared__ unsigned short Bs0[128 * 64], Bs1[128 * 64];
    int t = threadIdx.x;
    int bid = blockIdx.x;
    int g = bid & 7, rr = bid >> 3;         // xcd-chunk g: n_tiles {g, g+8, g+16}
    int bm = (rr & 15) << 7;
    int bn = (g + 8 * (rr >> 4)) << 7;
    int lane = t & 63, wv = t >> 6;
    int wm = (wv >> 1) * 64, wn = (wv & 1) * 64;
    int lr = lane & 15, qq = lane >> 4;

    f32x4 acc[4][4] = {};

    for (int k0 = 0; k0 < HIDDEN; k0 += 64) {
        stage_tile64(A0, As0, bm, HIDDEN, k0, t);
        stage_tile64(A1, As1, bm, HIDDEN, k0, t);
        stage_tile64(B0, Bs0, bn, HIDDEN, k0, t);
        stage_tile64(B1, Bs1, bn, HIDDEN, k0, t);
        __syncthreads();
        short8 a0[2][4], a1[2][4];
#pragma unroll
        for (int i = 0; i < 4; ++i) {
            int ra = (wm + i * 16 + lr) * 64;
#pragma unroll
            for (int h = 0; h < 2; ++h) {
                int sl = ((h * 4 + qq) ^ (lr & 7)) * 8;
                a0[h][i] = *(const short8*)&As0[ra + sl];
                a1[h][i] = *(const short8*)&As1[ra + sl];
            }
        }
#pragma unroll
        for (int j = 0; j < 4; ++j) {
            int rb = (wn + j * 16 + lr) * 64;
            short8 b0[2], b1[2];
#pragma unroll
            for (int h = 0; h < 2; ++h) {
                int sl = ((h * 4 + qq) ^ (lr & 7)) * 8;
                b0[h] = *(const short8*)&Bs0[rb + sl];
                b1[h] = *(const short8*)&Bs1[rb + sl];
            }
#pragma unroll
            for (int i = 0; i < 4; ++i) {
#pragma unroll
                for (int h = 0; h < 2; ++h) {
                    acc[i][j] = __builtin_amdgcn_mfma_f32_16x16x32_bf16(a1[h][i], b0[h], acc[i][j], 0, 0, 0);
                    acc[i][j] = __builtin_amdgcn_mfma_f32_16x16x32_bf16(a0[h][i], b1[h], acc[i][j], 0, 0, 0);
                    acc[i][j] = __builtin_amdgcn_mfma_f32_16x16x32_bf16(a0[h][i], b0[h], acc[i][j], 0, 0, 0);
                }
            }
        }
        __syncthreads();
    }
#pragma unroll
    for (int i = 0; i < 4; ++i)
#pragma unroll
        for (int j = 0; j < 4; ++j)
#pragma unroll
            for (int r = 0; r < 4; ++r) {
                int m = bm + wm + i * 16 + qq * 4 + r;
                int n = bn + wn + j * 16 + lr;
                C[(size_t)m * PNP + n] = acc[i][j][r];
            }
}

// ---------------- combine: h1[c] = relu(P_s[s] + P_e[e] + sum attn*P_a[s+w] + Tw + b1) ----
__global__ void combine_kernel(const float* __restrict__ P, const float* __restrict__ tw,
                               const float* __restrict__ attn_g, const float* __restrict__ b1,
                               const int* __restrict__ starts, const int* __restrict__ ends,
                               const int* __restrict__ perm,
                               unsigned short* __restrict__ h0, unsigned short* __restrict__ h1) {
    int pos = ((blockIdx.x & 7) << 10) | (blockIdx.x >> 3);
    int c = perm[pos];
    int t = threadIdx.x;
    int s = starts[c], e = ends[c];
    int wid = e - s;
    __shared__ float at[MSW];
    if (t < MSW) at[t] = attn_g[c * 32 + t];
    __syncthreads();
    int n0 = t * 4;
    size_t ho = (size_t)c * NP + n0;
    if (t < 250) {
        f32x4 acc = *(const f32x4*)&P[(size_t)s * PNP + n0];
        acc += *(const f32x4*)&P[(size_t)e * PNP + 1024 + n0];
        acc += *(const f32x4*)&tw[(size_t)wid * NP + n0];
        acc += *(const f32x4*)&b1[n0];
        const float* Pa = P + (size_t)s * PNP + 2048 + n0;
        for (int w = 0; w <= wid; ++w)
            acc += at[w] * *(const f32x4*)&Pa[(size_t)w * PNP];
        u16x4 q0, q1;
#pragma unroll
        for (int k = 0; k < 4; ++k) {
            float v = fmaxf(acc[k], 0.f);
            unsigned short x0 = bf16_rne(v);
            float r1 = v - bf16_to_f(x0);
            q0[k] = x0; q1[k] = bf16_rne(r1);
        }
        *(u16x4*)&h0[ho] = q0;
        *(u16x4*)&h1[ho] = q1;
    } else {
        u16x4 z = {0, 0, 0, 0};
        *(u16x4*)&h0[ho] = z;
        *(u16x4*)&h1[ho] = z;
    }
}

// ---------------- 2-split 3-product MFMA GEMM (BK=64, score fusion) ------------
__global__ __launch_bounds__(256, 2) void gemm3(
    const unsigned short* __restrict__ A0, const unsigned short* __restrict__ A1,
    const unsigned short* __restrict__ B0, const unsigned short* __restrict__ B1,
    const float* __restrict__ bias, int nreal, int Kp,
    const float* __restrict__ w3, float* __restrict__ partials) {
    __shared__ unsigned short As0[128 * 64], As1[128 * 64];
    __shared__ unsigned short Bs0[128 * 64], Bs1[128 * 64];
    int t = threadIdx.x;
    int bid = blockIdx.x;
    int bm = (bid >> 3) << 7;               // 64 M-tiles
    int bn = (bid & 7) << 7;                // 8 N-tiles; n ≡ bid (mod 8) -> per-XCD panel
    int lane = t & 63, wv = t >> 6;
    int wm = (wv >> 1) * 64, wn = (wv & 1) * 64;
    int lr = lane & 15, qq = lane >> 4;

    f32x4 acc[4][4] = {};

    for (int k0 = 0; k0 < Kp; k0 += 64) {
        stage_tile64(A0, As0, bm, Kp, k0, t);
        stage_tile64(A1, As1, bm, Kp, k0, t);
        stage_tile64(B0, Bs0, bn, Kp, k0, t);
        stage_tile64(B1, Bs1, bn, Kp, k0, t);
        __syncthreads();
        short8 a0[2][4], a1[2][4];
#pragma unroll
        for (int i = 0; i < 4; ++i) {
            int ra = (wm + i * 16 + lr) * 64;
#pragma unroll
            for (int h = 0; h < 2; ++h) {
                int sl = ((h * 4 + qq) ^ (lr & 7)) * 8;
                a0[h][i] = *(const short8*)&As0[ra + sl];
                a1[h][i] = *(const short8*)&As1[ra + sl];
            }
        }
#pragma unroll
        for (int j = 0; j < 4; ++j) {
            int rb = (wn + j * 16 + lr) * 64;
            short8 b0[2], b1[2];
#pragma unroll
            for (int h = 0; h < 2; ++h) {
                int sl = ((h * 4 + qq) ^ (lr & 7)) * 8;
                b0[h] = *(const short8*)&Bs0[rb + sl];
                b1[h] = *(const short8*)&Bs1[rb + sl];
            }
#pragma unroll
            for (int i = 0; i < 4; ++i) {
#pragma unroll
                for (int h = 0; h < 2; ++h) {
                    acc[i][j] = __builtin_amdgcn_mfma_f32_16x16x32_bf16(a1[h][i], b0[h], acc[i][j], 0, 0, 0);
                    acc[i][j] = __builtin_amdgcn_mfma_f32_16x16x32_bf16(a0[h][i], b1[h], acc[i][j], 0, 0, 0);
                    acc[i][j] = __builtin_amdgcn_mfma_f32_16x16x32_bf16(a0[h][i], b0[h], acc[i][j], 0, 0, 0);
                }
            }
        }
        __syncthreads();
    }

    int pid = ((bn >> 7) << 1) | (wn >> 6);  // 0..15
#pragma unroll
    for (int i = 0; i < 4; ++i)
#pragma unroll
        for (int r = 0; r < 4; ++r) {
            float p = 0.f;
#pragma unroll
            for (int j = 0; j < 4; ++j) {
                int n = bn + wn + j * 16 + lr;
                float v = acc[i][j][r] + (n < nreal ? bias[n] : 0.f);
                v = fmaxf(v, 0.f);
                p += v * (n < nreal ? w3[n] : 0.f);
            }
            p += __shfl_xor(p, 1);
            p += __shfl_xor(p, 2);
            p += __shfl_xor(p, 4);
            p += __shfl_xor(p, 8);
            if (lr == 0) {
                int m = bm + wm + i * 16 + qq * 4 + r;
                partials[(size_t)m * 16 + pid] = p;
            }
        }
}

// ---------------- deterministic score finalize ----------------
__global__ void score_final(const float* __restrict__ partials, const float* __restrict__ b3,
                            const float* __restrict__ width_s, const int* __restrict__ starts,
                            const int* __restrict__ ends, float* __restrict__ out) {
    int c = blockIdx.x * 256 + threadIdx.x;
    if (c >= NUM_CAND) return;
    float s = b3[0] + width_s[ends[c] - starts[c]];
#pragma unroll
    for (int p = 0; p < 16; ++p) s += partials[(size_t)c * 16 + p];
    out[c] = s;
}

// ---------------- exact counting rank-sort: 256 blocks ----------------
__global__ __launch_bounds__(256) void rank_kernel(const float* __restrict__ scores,
                                                   const int* __restrict__ starts,
                                                   const int* __restrict__ ends,
                                                   unsigned short* __restrict__ ord_g,
                                                   unsigned int* __restrict__ se_g) {
    __shared__ unsigned long long kk[NUM_CAND];  // 64 KB
    int t = threadIdx.x;
    for (int i = t; i < NUM_CAND; i += 256) {
        unsigned int b = __float_as_uint(scores[i]);
        unsigned int u = b ^ ((b & 0x80000000u) ? 0xFFFFFFFFu : 0x80000000u);
        unsigned int hi = ~u;
        kk[i] = ((unsigned long long)hi << 32) | (unsigned int)i;
    }
    __syncthreads();
    int c = blockIdx.x * 32 + (t >> 3);
    int seg = (t & 7) * 1024;
    int rot = (t & 7) * 2;
    unsigned long long mykey = kk[c];
    int cnt = 0;
    for (int ii = 0; ii < 1024; ++ii) {
        int i = seg + ((ii + rot) & 1023);
        cnt += (kk[i] < mykey) ? 1 : 0;
    }
    cnt += __shfl_xor(cnt, 1);
    cnt += __shfl_xor(cnt, 2);
    cnt += __shfl_xor(cnt, 4);
    if ((t & 7) == 0) {
        int idx = (int)(mykey & 0xFFFFFFFFull);
        int rank = cnt;
        ord_g[rank] = (unsigned short)idx;
        se_g[rank] = ((unsigned int)starts[idx] << 16) | (unsigned int)ends[idx];
    }
}

// ---------------- merged NMS + span-order sort + emit (r25) ----------------
// NMS decision path LOCKED at the r17-verified form (~292us; r13/r15/r18/r19/r20 all
// worse — cost is dependent-chain latency, structural). r25 merges select_post into the
// same launch: 512 threads init se_arr/st (8x faster), wave 0 runs the NMS loop (no
// internal barriers), sel stays in LDS (no global round-trip), then all 512 threads run
// the identical bitonic network (2 elems/thread). amdgpu_waves_per_eu(1,2) keeps the
// 132-VGPR allocation (r14-verified; spill marker would be VGPR_Count~40).
__global__ __launch_bounds__(512, 1)
__attribute__((amdgpu_waves_per_eu(1, 2)))
void select_nms_post(const unsigned int* __restrict__ se_g,
                     const unsigned short* __restrict__ ord_g,
                     const float* __restrict__ scores,
                     const int* __restrict__ starts,
                     const int* __restrict__ ends,
                     float* __restrict__ out, int* __restrict__ top_idx_ws) {
    __shared__ unsigned int se_arr[NUM_CAND];    // 32 KB
    __shared__ unsigned int st[2 * NUM_WORDS];   // 16 KB
    __shared__ unsigned short sel_sh[1024];      //  2 KB
    __shared__ unsigned long long fkeys[1024];   //  8 KB
    __shared__ int count_sh;
    int t = threadIdx.x;

    {
        const uint4* src4 = (const uint4*)se_g;
        uint4* dst4 = (uint4*)se_arr;
        for (int i = t; i < NUM_CAND / 4; i += 512) dst4[i] = src4[i];
    }
    for (int i = t; i < 2 * NUM_WORDS; i += 512)
        st[i] = (i & 1) ? (unsigned int)NUM_WORDS : 0u;  // max_end+1=0, min_start=2048
    __syncthreads();

    if (t < 64) {
        int lane = t;
        const unsigned long long* stp = (const unsigned long long*)st;
        int count = 0;
        for (int c = 0; c < NUM_CAND / 64; ++c) {
            int ib = c * 64;
            unsigned int sev = se_arr[ib + lane];
            int s = (int)(sev >> 16), e = (int)(sev & 0xFFFFu);
            const unsigned long long* bp = stp + s;
            unsigned long long v[MSW];
#pragma unroll
            for (int w = 0; w < MSW; ++w) v[w] = bp[w];
            int me = (int)(unsigned int)v[0] - 1;
            bool crossedA = (s < e) && ((int)(unsigned int)(v[0] >> 32) < s);
            bool crossedB = false;
#pragma unroll
            for (int w = 1; w < MSW; ++w) {
                int j = s + w;
                bool in = (j <= e);
                int mej = (int)(unsigned int)v[w] - 1;
                int msj = (int)(unsigned int)(v[w] >> 32);
                bool hit = in && ((mej > e) || ((j < e) && (msj < s)));
                if (w & 1) crossedA = crossedA || hit;
                else       crossedB = crossedB || hit;
            }
            bool crossed = crossedA || crossedB;
            bool spec = !crossed && (me != e);

            // serial resolve — decision loop identical to the r2..r17-verified form
            int cbefore = count;
            unsigned long long window = ~0ull;
            unsigned int pend = 0u;
            int rk = 0, lcnt = 0;
            while (true) {
                unsigned long long b = __ballot(spec) & window;
                if (b == 0ull) break;
                int f = __ffsll((unsigned long long)b) - 1;
                unsigned int sef = __builtin_amdgcn_readlane(sev, (unsigned int)f);
                int sf = (int)(sef >> 16), ef = (int)(sef & 0xFFFFu);
                bool mine = (lane == lcnt);
                pend = mine ? sef : pend;
                rk = mine ? (ib + f) : rk;
                lcnt++;
                count++;
                if (count >= TOP_NUM) break;
                window &= (f >= 63) ? 0ull : (~0ull << (f + 1));
                if (lane > f) {
                    if (s == sf) me = max(me, ef);
                    crossed = crossed || ((s < sf) && (sf <= e) && (ef > e))
                                      || ((sf < s) && (s <= ef) && (ef < e));
                    spec = !crossed && (me != e);
                }
            }
            if (lane < lcnt) {
                int sf = (int)(pend >> 16), ef = (int)(pend & 0xFFFFu);
                sel_sh[cbefore + lane] = (unsigned short)rk;
                atomicMax(&st[2 * sf], (unsigned int)(ef + 1));
                atomicMin(&st[2 * ef + 1], (unsigned int)sf);
            }
            if (count >= TOP_NUM) break;
        }
        if (lane == 0) count_sh = count;
    }
    __syncthreads();
    int count = count_sh;

    // ---- span-order bitonic sort (identical network; 2 elems/thread) ----
#pragma unroll
    for (int ii = 0; ii < 2; ++ii) {
        int i = t + ii * 512;
        unsigned long long k = 0xFFFFFFFFFFFFFFFFull;
        if (i < count) {
            int idx = (int)ord_g[sel_sh[i]];
            unsigned int key32 = (unsigned int)(starts[idx] * NUM_WORDS + ends[idx]);
            k = ((unsigned long long)key32 << 32) | (unsigned int)idx;
        }
        fkeys[i] = k;
    }
    __syncthreads();
    for (int size = 2; size <= 1024; size <<= 1) {
        for (int stride = size >> 1; stride > 0; stride >>= 1) {
#pragma unroll
            for (int ii = 0; ii < 2; ++ii) {
                int i = t + ii * 512;
                int ixj = i ^ stride;
                if (ixj > i) {
                    bool up = ((i & size) == 0);
                    unsigned long long a = fkeys[i], b = fkeys[ixj];
                    if ((a > b) == up) { fkeys[i] = b; fkeys[ixj] = a; }
                }
            }
            __syncthreads();
        }
    }
#pragma unroll
    for (int ii = 0; ii < 2; ++ii) {
        int i = t + ii * 512;
        if (i < TOP_NUM) {
            int fi = (i < count) ? (int)(fkeys[i] & 0xFFFFFFFFull)
                                 : (int)(fkeys[0] & 0xFFFFFFFFull);
            out[OUT_TOPIDX + i] = (float)fi;
            out[OUT_TSTART + i] = (float)starts[fi];
            out[OUT_TEND + i] = (float)ends[fi];
            out[OUT_TSCORE + i] = scores[fi];
            top_idx_ws[i] = fi;
        }
    }
}

// ---------------- gather top_span_emb rows directly from doc (exact fp32) ----------------
__global__ void gather_emb(const float* __restrict__ doc, const float* __restrict__ swe,
                           const float* __restrict__ attn_g, const int* __restrict__ starts,
                           const int* __restrict__ ends, const int* __restrict__ top_idx_ws,
                           float* __restrict__ out) {
    int r = blockIdx.x, t = threadIdx.x;
    int idx = top_idx_ws[r];
    int s = starts[idx], e = ends[idx];
    int wid = e - s;
    __shared__ float at[MSW];
    if (t < MSW) at[t] = attn_g[(size_t)idx * 32 + t];
    __syncthreads();
    float* dst = out + OUT_TEMB + (size_t)r * SPAN_DIM;
    if (t < 192) {
        int h4 = t * 4;
        f32x4 vs = *(const f32x4*)&doc[(size_t)s * HIDDEN + h4];
        f32x4 ve = *(const f32x4*)&doc[(size_t)e * HIDDEN + h4];
        f32x4 acc = {0.f, 0.f, 0.f, 0.f};
        for (int w = 0; w <= wid; ++w)
            acc += at[w] * *(const f32x4*)&doc[(size_t)(s + w) * HIDDEN + h4];
#pragma unroll
        for (int k = 0; k < 4; ++k) {
            dst[h4 + k] = vs[k];
            dst[HIDDEN + h4 + k] = ve[k];
            dst[2 * HIDDEN + FEAT + h4 + k] = acc[k];
        }
    }
    if (t < FEAT) dst[2 * HIDDEN + t] = swe[wid * FEAT + t];
}

extern "C" void kernel_launch(void* const* d_in, const int* in_sizes, int n_in,
                              void* d_out, int out_size, void* d_ws, size_t ws_size,
                              hipStream_t stream) {
    const float* mention_doc = (const float*)d_in[0];
    const float* span_width_emb = (const float*)d_in[1];
    const float* head_w = (const float*)d_in[2];
    const float* head_b = (const float*)d_in[3];
    const float* m_w1 = (const float*)d_in[4];
    const float* m_b1 = (const float*)d_in[5];
    const float* m_w2 = (const float*)d_in[6];
    const float* m_b2 = (const float*)d_in[7];
    const float* m_w3 = (const float*)d_in[8];
    const float* m_b3 = (const float*)d_in[9];
    const float* width_prior_emb = (const float*)d_in[10];
    const float* w_w1 = (const float*)d_in[11];
    const float* w_b1 = (const float*)d_in[12];
    const float* w_w2 = (const float*)d_in[13];
    const float* w_b2 = (const float*)d_in[14];
    const float* w_w3 = (const float*)d_in[15];
    const float* w_b3 = (const float*)d_in[16];
    const int* cand_starts = (const int*)d_in[17];
    const int* cand_ends = (const int*)d_in[18];

    char* w = (char*)d_ws;
    const size_t szH = (size_t)NUM_CAND * NP * 2;
    const size_t szW2 = (size_t)NP * KP2 * 2;
    const size_t szWc = (size_t)PNP * HIDDEN * 2;
    const size_t szD = (size_t)NUM_WORDS * HIDDEN * 2;
    char* p = w;
    unsigned short* h0 = (unsigned short*)p; p += szH;
    unsigned short* h1 = (unsigned short*)p; p += szH;
    unsigned short* w2t0 = (unsigned short*)p; p += szW2;
    unsigned short* w2t1 = (unsigned short*)p; p += szW2;
    unsigned short* Wc0 = (unsigned short*)p; p += szWc;
    unsigned short* Wc1 = (unsigned short*)p; p += szWc;
    unsigned short* d0 = (unsigned short*)p; p += szD;
    unsigned short* d1 = (unsigned short*)p; p += szD;
    float* P = (float*)p; p += (size_t)NUM_WORDS * PNP * 4;
    float* tw = (float*)p; p += (size_t)MSW * NP * 4;
    float* attn_g = (float*)p; p += (size_t)NUM_CAND * 32 * 4;
    float* partials = (float*)p; p += (size_t)NUM_CAND * 16 * 4;
    unsigned short* ord_g = (unsigned short*)p; p += (size_t)NUM_CAND * 2;
    unsigned int* se_g = (unsigned int*)p; p += (size_t)NUM_CAND * 4;
    unsigned short* sel_g = (unsigned short*)p; p += 2048;
    int* count_g = (int*)p; p += 128;
    float* head_s = (float*)p; p += NUM_WORDS * 4;
    float* width_s = (float*)p; p += 128;
    int* top_idx_ws = (int*)p; p += 4096;
    int* hist_g = (int*)p; p += NUM_WORDS * 4;
    int* perm_g = (int*)p; p += (size_t)NUM_CAND * 4;

    size_t need = (size_t)(p - w);
    if (ws_size < need) {
        fprintf(stderr, "kernel_launch: ws too small (%zu < %zu)\n", ws_size, need);
    }
    (void)sel_g; (void)count_g;

    float* out = (float*)d_out;

    head_kernel<<<NUM_WORDS / 4, 256, 0, stream>>>(mention_doc, head_w, head_b, head_s,
                                                   hist_g, d0, d1);
    width_kernel<<<MSW, 256, 0, stream>>>(width_prior_emb, w_w1, w_b1, w_w2, w_b2, w_w3, w_b3,
                                          width_s, span_width_emb, m_w1, tw);
    attn_kernel<<<NUM_CAND / 8, 256, 0, stream>>>(head_s, cand_starts, cand_ends, attn_g,
                                                  hist_g);
    convert_wc<<<dim3(12, 48), 256, 0, stream>>>(m_w1, Wc0, Wc1);
    convert_wt<<<dim3(16, 16), 256, 0, stream>>>(m_w2, w2t0, w2t1);
    perm_kernel<<<1, 256, 0, stream>>>(hist_g, cand_starts, perm_g);
    gemm3p<<<16 * 24, 256, 0, stream>>>(d0, d1, Wc0, Wc1, P);
    combine_kernel<<<NUM_CAND, 256, 0, stream>>>(P, tw, attn_g, m_b1, cand_starts, cand_ends,
                                                 perm_g, h0, h1);
    gemm3<<<512, 256, 0, stream>>>(h0, h1, w2t0, w2t1, m_b2, FFNN_DIM, KP2,
                                   m_w3, partials);
    score_final<<<NUM_CAND / 256, 256, 0, stream>>>(partials, m_b3, width_s, cand_starts,
                                                    cand_ends, out);
    rank_kernel<<<NUM_CAND / 32, 256, 0, stream>>>(out, cand_starts, cand_ends, ord_g, se_g);
    select_nms_post<<<1, 512, 0, stream>>>(se_g, ord_g, out, cand_starts, cand_ends,
                                           out, top_idx_ws);
    gather_emb<<<TOP_NUM, 256, 0, stream>>>(mention_doc, span_width_emb, attn_g, cand_starts,
                                            cand_ends, top_idx_ws, out);
}